// Round 1
// baseline (366.803 us; speedup 1.0000x reference)
//
#include <hip/hip_runtime.h>
#include <math.h>

#define N_NODES 8192
#define D 256
#define HID 128
#define S_SEG 256
#define MAXC 112

// ---------------- segment offsets from sorted batch ----------------
__global__ void seg_offsets(const int* __restrict__ batch,
                            int* __restrict__ sstart, int* __restrict__ scount,
                            int n) {
  int i = blockIdx.x * blockDim.x + threadIdx.x;
  if (i < n) {
    int b = batch[i];
    atomicAdd(&scount[b], 1);
    if (i == 0 || batch[i - 1] != b) sstart[b] = i;
  }
}

// ---------- GEMM: C[N,M] = act(A[N,K] @ W[M,K]^T + bias[M]) ----------
// ACT: 0 = none, 1 = leaky_relu(0.01)
template <int ACT>
__global__ __launch_bounds__(256) void gemm_bias_act(
    const float* __restrict__ A, const float* __restrict__ W,
    const float* __restrict__ bias, float* __restrict__ C,
    int M, int K) {
  __shared__ float As[16][65];
  __shared__ float Ws[16][65];
  const int tid = threadIdx.x;
  const int tx = tid & 15, ty = tid >> 4;
  const int row0 = blockIdx.x * 64, col0 = blockIdx.y * 64;
  const int lr = tid >> 2;        // 0..63
  const int lc4 = (tid & 3) * 4;  // 0,4,8,12

  float acc[4][4] = {};

  for (int k0 = 0; k0 < K; k0 += 16) {
    float4 av = *(const float4*)&A[(size_t)(row0 + lr) * K + k0 + lc4];
    float4 wv = *(const float4*)&W[(size_t)(col0 + lr) * K + k0 + lc4];
    As[lc4 + 0][lr] = av.x; As[lc4 + 1][lr] = av.y;
    As[lc4 + 2][lr] = av.z; As[lc4 + 3][lr] = av.w;
    Ws[lc4 + 0][lr] = wv.x; Ws[lc4 + 1][lr] = wv.y;
    Ws[lc4 + 2][lr] = wv.z; Ws[lc4 + 3][lr] = wv.w;
    __syncthreads();
#pragma unroll
    for (int k = 0; k < 16; ++k) {
      float a[4], b[4];
#pragma unroll
      for (int i = 0; i < 4; ++i) a[i] = As[k][ty * 4 + i];
#pragma unroll
      for (int j = 0; j < 4; ++j) b[j] = Ws[k][tx * 4 + j];
#pragma unroll
      for (int i = 0; i < 4; ++i)
#pragma unroll
        for (int j = 0; j < 4; ++j) acc[i][j] += a[i] * b[j];
    }
    __syncthreads();
  }

#pragma unroll
  for (int i = 0; i < 4; ++i) {
#pragma unroll
    for (int j = 0; j < 4; ++j) {
      float v = acc[i][j] + bias[col0 + tx * 4 + j];
      if (ACT == 1) v = (v >= 0.0f) ? v : 0.01f * v;
      C[(size_t)(row0 + ty * 4 + i) * M + col0 + tx * 4 + j] = v;
    }
  }
}

// ---------------- per-segment masked softmax attention ----------------
// Hm[i,:] = sum_j softmax_j(att_i . att_j) * Hf[j,:]   (i,j within segment)
__global__ __launch_bounds__(256) void seg_attention(
    const float* __restrict__ att, const float* __restrict__ Hf,
    float* __restrict__ Hm, const int* __restrict__ sstart,
    const int* __restrict__ scount) {
  __shared__ float dotm[MAXC * MAXC];
  __shared__ float red[256];
  const int s = blockIdx.x, t = threadIdx.x;
  const int cnt = scount[s];
  if (cnt == 0) return;
  const int r0 = sstart[s];

  if (cnt <= MAXC) {
    const int total = cnt * cnt;
    for (int p = t; p < total; p += 256) {
      int i = p / cnt, j = p - i * cnt;
      const float4* a = (const float4*)&att[(size_t)(r0 + i) * D];
      const float4* b = (const float4*)&att[(size_t)(r0 + j) * D];
      float acc = 0.0f;
#pragma unroll 8
      for (int k = 0; k < D / 4; ++k) {
        float4 x = a[k], y = b[k];
        acc += x.x * y.x + x.y * y.y + x.z * y.z + x.w * y.w;
      }
      dotm[p] = acc;
    }
    __syncthreads();
    if (t < cnt) {
      float* row = &dotm[t * cnt];
      float m = -INFINITY;
      for (int j = 0; j < cnt; ++j) m = fmaxf(m, row[j]);
      float sum = 0.0f;
      for (int j = 0; j < cnt; ++j) {
        float e = __expf(row[j] - m);
        row[j] = e;
        sum += e;
      }
      float inv = 1.0f / sum;
      for (int j = 0; j < cnt; ++j) row[j] *= inv;
    }
    __syncthreads();
    // t indexes the output column d (D == 256 == blockDim)
    for (int i = 0; i < cnt; ++i) {
      const float* w = &dotm[i * cnt];
      float acc = 0.0f;
      for (int j = 0; j < cnt; ++j) acc += w[j] * Hf[(size_t)(r0 + j) * D + t];
      Hm[(size_t)(r0 + i) * D + t] = acc;
    }
  } else {
    // robust fallback (practically never taken): row-serial two-pass
    for (int i = 0; i < cnt; ++i) {
      const float4* a = (const float4*)&att[(size_t)(r0 + i) * D];
      for (int j = t; j < cnt; j += 256) {
        const float4* b = (const float4*)&att[(size_t)(r0 + j) * D];
        float acc = 0.0f;
        for (int k = 0; k < D / 4; ++k) {
          float4 x = a[k], y = b[k];
          acc += x.x * y.x + x.y * y.y + x.z * y.z + x.w * y.w;
        }
        dotm[j] = acc;
      }
      __syncthreads();
      float pm = -INFINITY;
      for (int j = t; j < cnt; j += 256) pm = fmaxf(pm, dotm[j]);
      red[t] = pm;
      __syncthreads();
      for (int o = 128; o > 0; o >>= 1) {
        if (t < o) red[t] = fmaxf(red[t], red[t + o]);
        __syncthreads();
      }
      float m = red[0];
      __syncthreads();
      float ps = 0.0f;
      for (int j = t; j < cnt; j += 256) {
        float e = __expf(dotm[j] - m);
        dotm[j] = e;
        ps += e;
      }
      red[t] = ps;
      __syncthreads();
      for (int o = 128; o > 0; o >>= 1) {
        if (t < o) red[t] += red[t + o];
        __syncthreads();
      }
      float inv = 1.0f / red[0];
      float acc = 0.0f;
      for (int j = 0; j < cnt; ++j) acc += dotm[j] * Hf[(size_t)(r0 + j) * D + t];
      Hm[(size_t)(r0 + i) * D + t] = acc * inv;
      __syncthreads();
    }
  }
}

// ---------------- final gate layer: hgate[n] = g2[n,:] . w3 + b3 ----------------
__global__ void gate3(const float* __restrict__ g2, const float* __restrict__ w3,
                      const float* __restrict__ b3, float* __restrict__ hgate,
                      int n) {
  int i = blockIdx.x * blockDim.x + threadIdx.x;
  if (i < n) {
    const float4* a = (const float4*)&g2[(size_t)i * HID];
    const float4* w = (const float4*)w3;
    float acc = b3[0];
#pragma unroll 8
    for (int k = 0; k < HID / 4; ++k) {
      float4 x = a[k], y = w[k];
      acc += x.x * y.x + x.y * y.y + x.z * y.z + x.w * y.w;
    }
    hgate[i] = acc;
  }
}

// ------------- per-segment scatter softmax + weighted pooling -------------
__global__ __launch_bounds__(256) void seg_pool(
    const float* __restrict__ Hm2, const float* __restrict__ hg,
    const int* __restrict__ sstart, const int* __restrict__ scount,
    float* __restrict__ hpool, float* __restrict__ scores) {
  __shared__ float red[256];
  const int s = blockIdx.x, t = threadIdx.x;
  const int cnt = scount[s];
  if (cnt == 0) {
    hpool[(size_t)s * D + t] = 0.0f;
    return;
  }
  const int r0 = sstart[s];

  float pm = -INFINITY;
  for (int i = t; i < cnt; i += 256) pm = fmaxf(pm, hg[r0 + i]);
  red[t] = pm;
  __syncthreads();
  for (int o = 128; o > 0; o >>= 1) {
    if (t < o) red[t] = fmaxf(red[t], red[t + o]);
    __syncthreads();
  }
  float m = red[0];
  __syncthreads();
  float ps = 0.0f;
  for (int i = t; i < cnt; i += 256) ps += __expf(hg[r0 + i] - m);
  red[t] = ps;
  __syncthreads();
  for (int o = 128; o > 0; o >>= 1) {
    if (t < o) red[t] += red[t + o];
    __syncthreads();
  }
  float den = red[0];
  float invden = 1.0f / den;

  for (int i = t; i < cnt; i += 256)
    scores[r0 + i] = __expf(hg[r0 + i] - m) * invden;

  // pooling: t = output column d
  float acc = 0.0f;
  for (int i = 0; i < cnt; ++i) {
    float w = __expf(hg[r0 + i] - m) * invden;
    acc += w * Hm2[(size_t)(r0 + i) * D + t];
  }
  hpool[(size_t)s * D + t] = acc;
}

// ---------------------------------------------------------------------
extern "C" void kernel_launch(void* const* d_in, const int* in_sizes, int n_in,
                              void* d_out, int out_size, void* d_ws, size_t ws_size,
                              hipStream_t stream) {
  const float* H      = (const float*)d_in[0];
  const int*   batch  = (const int*)d_in[1];
  const float* phi_w1 = (const float*)d_in[2];
  const float* phi_b1 = (const float*)d_in[3];
  const float* phi_w2 = (const float*)d_in[4];
  const float* phi_b2 = (const float*)d_in[5];
  const float* att_w  = (const float*)d_in[6];
  const float* att_b  = (const float*)d_in[7];
  const float* rho_w1 = (const float*)d_in[8];
  const float* rho_b1 = (const float*)d_in[9];
  const float* rho_w2 = (const float*)d_in[10];
  const float* rho_b2 = (const float*)d_in[11];
  const float* g_w1   = (const float*)d_in[12];
  const float* g_b1   = (const float*)d_in[13];
  const float* g_w2   = (const float*)d_in[14];
  const float* g_b2   = (const float*)d_in[15];
  const float* g_w3   = (const float*)d_in[16];
  const float* g_b3   = (const float*)d_in[17];

  float* out_hpool  = (float*)d_out;                       // [S, D]
  float* out_scores = (float*)d_out + (size_t)S_SEG * D;   // [N]

  const size_t ND = (size_t)N_NODES * D;
  float* bufA  = (float*)d_ws;        // t1 / att / rho-hidden / g1,g2
  float* bufB  = bufA + ND;           // Hf / Hm2
  float* bufC  = bufB + ND;           // Hm
  float* hgate = bufC + ND;           // [N]
  int* sstart  = (int*)(hgate + N_NODES);
  int* scount  = sstart + S_SEG;

  hipMemsetAsync(scount, 0, S_SEG * sizeof(int), stream);
  seg_offsets<<<(N_NODES + 255) / 256, 256, 0, stream>>>(batch, sstart, scount, N_NODES);

  dim3 blk(256);
  dim3 gD(N_NODES / 64, D / 64);    // M=256
  dim3 gH(N_NODES / 64, HID / 64);  // M=128

  // phi MLP
  gemm_bias_act<1><<<gD, blk, 0, stream>>>(H,    phi_w1, phi_b1, bufA, D, D);
  gemm_bias_act<1><<<gD, blk, 0, stream>>>(bufA, phi_w2, phi_b2, bufB, D, D);
  // att projection (no activation)
  gemm_bias_act<0><<<gD, blk, 0, stream>>>(bufB, att_w, att_b, bufA, D, D);
  // per-segment attention: Hm = softmax(att att^T | segment) @ Hf
  seg_attention<<<S_SEG, blk, 0, stream>>>(bufA, bufB, bufC, sstart, scount);
  // rho MLP
  gemm_bias_act<1><<<gD, blk, 0, stream>>>(bufC, rho_w1, rho_b1, bufA, D, D);
  gemm_bias_act<1><<<gD, blk, 0, stream>>>(bufA, rho_w2, rho_b2, bufB, D, D);  // Hm2 = bufB
  // gate MLP
  float* g1 = bufA;
  float* g2 = bufA + (size_t)N_NODES * HID;
  gemm_bias_act<1><<<gH, blk, 0, stream>>>(bufB, g_w1, g_b1, g1, HID, D);
  gemm_bias_act<1><<<gH, blk, 0, stream>>>(g1,   g_w2, g_b2, g2, HID, HID);
  gate3<<<(N_NODES + 255) / 256, 256, 0, stream>>>(g2, g_w3, g_b3, hgate, N_NODES);
  // scatter softmax + pooling
  seg_pool<<<S_SEG, blk, 0, stream>>>(bufB, hgate, sstart, scount, out_hpool, out_scores);
}

// Round 2
// 193.257 us; speedup vs baseline: 1.8980x; 1.8980x over previous
//
#include <hip/hip_runtime.h>
#include <math.h>

#define N_NODES 8192
#define D 256
#define HID 128
#define S_SEG 256
#define MAXC 112

typedef __attribute__((ext_vector_type(8))) short short8;
typedef __attribute__((ext_vector_type(4))) float f32x4;
typedef unsigned short u16;
typedef unsigned int u32;

__device__ __forceinline__ u16 f2bf(float f) {
  u32 u = __float_as_uint(f);
  u32 r = (u + 0x7fffu + ((u >> 16) & 1u)) >> 16;
  return (u16)r;
}
__device__ __forceinline__ float bf2f(u16 b) {
  return __uint_as_float(((u32)b) << 16);
}

// ---------------- segment offsets from sorted batch ----------------
__global__ void seg_offsets(const int* __restrict__ batch,
                            int* __restrict__ sstart, int* __restrict__ scount,
                            int n) {
  int i = blockIdx.x * blockDim.x + threadIdx.x;
  if (i < n) {
    int b = batch[i];
    atomicAdd(&scount[b], 1);
    if (i == 0 || batch[i - 1] != b) sstart[b] = i;
  }
}

// ---------------- f32 -> bf16 converter (multi-buffer) ----------------
struct CvtJobs {
  const float* src[8];
  u16* dst[8];
  int n4[8];
};
__global__ void cvt_bf16(CvtJobs jb) {
  int e = blockIdx.y;
  const float* s = jb.src[e];
  u16* d = jb.dst[e];
  int n4 = jb.n4[e];
  for (int i = blockIdx.x * blockDim.x + threadIdx.x; i < n4;
       i += gridDim.x * blockDim.x) {
    float4 v = ((const float4*)s)[i];
    ushort4 o;
    o.x = f2bf(v.x); o.y = f2bf(v.y); o.z = f2bf(v.z); o.w = f2bf(v.w);
    ((ushort4*)d)[i] = o;
  }
}

// ---------- MFMA GEMM: C[N,M] = act(A[N,K] @ W[M,K]^T + bias[M]) ----------
// A,W bf16; accum f32; OUT_BF16 selects bf16 or f32 C.
// Block: 256 thr = 4 waves; tile BM=64 x BN=128 x BK=64; wave = 64x32.
template <int ACT, int OUT_BF16>
__global__ __launch_bounds__(256) void gemm_mfma(
    const u16* __restrict__ A, const u16* __restrict__ W,
    const float* __restrict__ bias, void* __restrict__ Cv, int M, int K) {
  __shared__ __align__(16) u16 Asb[64 * 64];    // [row][64] bf16, swizzled
  __shared__ __align__(16) u16 Bsb[128 * 64];
  const int tid = threadIdx.x;
  const int wave = tid >> 6;
  const int lane = tid & 63;
  const size_t row0 = (size_t)blockIdx.x * 64;
  const int col0 = blockIdx.y * 128;

  f32x4 acc[4][2];
#pragma unroll
  for (int m = 0; m < 4; ++m)
#pragma unroll
    for (int n = 0; n < 2; ++n) acc[m][n] = (f32x4){0.f, 0.f, 0.f, 0.f};

  for (int k0 = 0; k0 < K; k0 += 64) {
    __syncthreads();  // protect LDS from previous iteration's readers
    // stage A: 8KB = 512 x 16B chunks; chunk c: row=c>>3, slot=c&7
#pragma unroll
    for (int q = 0; q < 2; ++q) {
      int c = tid + q * 256;
      int r = c >> 3, sl = c & 7;
      int4 v = *(const int4*)&A[(row0 + r) * K + k0 + sl * 8];
      *(int4*)((char*)Asb + r * 128 + ((sl ^ (r & 7)) * 16)) = v;
    }
    // stage B: 16KB = 1024 chunks
#pragma unroll
    for (int q = 0; q < 4; ++q) {
      int c = tid + q * 256;
      int r = c >> 3, sl = c & 7;
      int4 v = *(const int4*)&W[(size_t)(col0 + r) * K + k0 + sl * 8];
      *(int4*)((char*)Bsb + r * 128 + ((sl ^ (r & 7)) * 16)) = v;
    }
    __syncthreads();
#pragma unroll
    for (int kh = 0; kh < 2; ++kh) {
      short8 af[4], bfr[2];
#pragma unroll
      for (int m = 0; m < 4; ++m) {
        int r = m * 16 + (lane & 15);
        int sg = kh * 4 + (lane >> 4);
        af[m] = *(const short8*)((const char*)Asb + r * 128 + ((sg ^ (r & 7)) * 16));
      }
#pragma unroll
      for (int n = 0; n < 2; ++n) {
        int r = wave * 32 + n * 16 + (lane & 15);
        int sg = kh * 4 + (lane >> 4);
        bfr[n] = *(const short8*)((const char*)Bsb + r * 128 + ((sg ^ (r & 7)) * 16));
      }
#pragma unroll
      for (int m = 0; m < 4; ++m)
#pragma unroll
        for (int n = 0; n < 2; ++n)
          acc[m][n] = __builtin_amdgcn_mfma_f32_16x16x32_bf16(af[m], bfr[n],
                                                              acc[m][n], 0, 0, 0);
    }
  }

  // epilogue: C/D layout col=lane&15, row=(lane>>4)*4+reg
  const int rb = (lane >> 4) * 4;
  const int ccol = lane & 15;
#pragma unroll
  for (int n = 0; n < 2; ++n) {
    int col = col0 + wave * 32 + n * 16 + ccol;
    float b = bias[col];
#pragma unroll
    for (int m = 0; m < 4; ++m) {
#pragma unroll
      for (int r = 0; r < 4; ++r) {
        float v = acc[m][n][r] + b;
        if (ACT) v = (v >= 0.f) ? v : 0.01f * v;
        size_t row = row0 + m * 16 + rb + r;
        if (OUT_BF16)
          ((u16*)Cv)[row * M + col] = f2bf(v);
        else
          ((float*)Cv)[row * M + col] = v;
      }
    }
  }
}

// ---------------- per-segment masked softmax attention ----------------
// Hm[i,:] = sum_j softmax_j(att_i . att_j) * Hf[j,:], within segment.
__global__ __launch_bounds__(512) void seg_attention2(
    const float* __restrict__ att, const u16* __restrict__ Hf,
    u16* __restrict__ Hm, const int* __restrict__ sstart,
    const int* __restrict__ scount) {
  __shared__ float P[MAXC][MAXC + 1];
  __shared__ float red[512];
  const int s = blockIdx.x, t = threadIdx.x;
  const int cnt = scount[s];
  if (cnt == 0) return;
  const int r0 = sstart[s];

  if (cnt <= MAXC) {
    // phase 1: all pairwise dots (f32)
    const int total = cnt * cnt;
    for (int p = t; p < total; p += 512) {
      int i = p / cnt, j = p - i * cnt;
      const float4* a = (const float4*)&att[(size_t)(r0 + i) * D];
      const float4* b = (const float4*)&att[(size_t)(r0 + j) * D];
      float acc = 0.f;
#pragma unroll 8
      for (int k = 0; k < D / 4; ++k) {
        float4 x = a[k], y = b[k];
        acc += x.x * y.x + x.y * y.y + x.z * y.z + x.w * y.w;
      }
      P[i][j] = acc;
    }
    __syncthreads();
    // phase 2: row softmax (thread = row); diag >= 0 so masked-zero max is safe
    if (t < cnt) {
      float* row = P[t];
      float m = -INFINITY;
      for (int j = 0; j < cnt; ++j) m = fmaxf(m, row[j]);
      float sum = 0.f;
      for (int j = 0; j < cnt; ++j) {
        float e = __expf(row[j] - m);
        row[j] = e;
        sum += e;
      }
      float inv = 1.f / sum;
      for (int j = 0; j < cnt; ++j) row[j] *= inv;
    }
    __syncthreads();
    // phase 3: PV, wave-parallel over rows; lane owns 4 columns
    const int w = t >> 6, lane = t & 63;
    for (int i = w; i < cnt; i += 8) {
      const float* Pi = P[i];
      float a0 = 0.f, a1 = 0.f, a2 = 0.f, a3 = 0.f;
      for (int j = 0; j < cnt; ++j) {
        float wj = Pi[j];
        uint2 hv = *(const uint2*)&Hf[(size_t)(r0 + j) * D + lane * 4];
        a0 += wj * __uint_as_float(hv.x << 16);
        a1 += wj * __uint_as_float(hv.x & 0xffff0000u);
        a2 += wj * __uint_as_float(hv.y << 16);
        a3 += wj * __uint_as_float(hv.y & 0xffff0000u);
      }
      ushort4 o;
      o.x = f2bf(a0); o.y = f2bf(a1); o.z = f2bf(a2); o.w = f2bf(a3);
      *(ushort4*)&Hm[(size_t)(r0 + i) * D + lane * 4] = o;
    }
  } else {
    // fallback (cnt > MAXC): row-serial two-pass, P used as flat buffer
    float* Pf = &P[0][0];  // capacity 12656 >= any cnt
    for (int i = 0; i < cnt; ++i) {
      const float4* a = (const float4*)&att[(size_t)(r0 + i) * D];
      for (int j = t; j < cnt; j += 512) {
        const float4* b = (const float4*)&att[(size_t)(r0 + j) * D];
        float acc = 0.f;
        for (int k = 0; k < D / 4; ++k) {
          float4 x = a[k], y = b[k];
          acc += x.x * y.x + x.y * y.y + x.z * y.z + x.w * y.w;
        }
        Pf[j] = acc;
      }
      __syncthreads();
      float pm = -INFINITY;
      for (int j = t; j < cnt; j += 512) pm = fmaxf(pm, Pf[j]);
      red[t] = pm;
      __syncthreads();
      for (int o = 256; o > 0; o >>= 1) {
        if (t < o) red[t] = fmaxf(red[t], red[t + o]);
        __syncthreads();
      }
      float m = red[0];
      __syncthreads();
      float ps = 0.f;
      for (int j = t; j < cnt; j += 512) {
        float e = __expf(Pf[j] - m);
        Pf[j] = e;
        ps += e;
      }
      red[t] = ps;
      __syncthreads();
      for (int o = 256; o > 0; o >>= 1) {
        if (t < o) red[t] += red[t + o];
        __syncthreads();
      }
      float inv = 1.f / red[0];
      if (t < D) {
        float acc = 0.f;
        for (int j = 0; j < cnt; ++j)
          acc += Pf[j] * bf2f(Hf[(size_t)(r0 + j) * D + t]);
        Hm[(size_t)(r0 + i) * D + t] = f2bf(acc * inv);
      }
      __syncthreads();
    }
  }
}

// ---------------- final gate layer: hgate[n] = g2[n,:] . w3 + b3 ----------------
__global__ void gate3(const u16* __restrict__ g2, const float* __restrict__ w3,
                      const float* __restrict__ b3, float* __restrict__ hgate,
                      int n) {
  int i = blockIdx.x * blockDim.x + threadIdx.x;
  if (i >= n) return;
  const uint4* a = (const uint4*)&g2[(size_t)i * HID];
  float acc = b3[0];
#pragma unroll 4
  for (int k = 0; k < HID / 8; ++k) {
    uint4 v = a[k];
    const float* wp = &w3[k * 8];
    acc += __uint_as_float(v.x << 16) * wp[0];
    acc += __uint_as_float(v.x & 0xffff0000u) * wp[1];
    acc += __uint_as_float(v.y << 16) * wp[2];
    acc += __uint_as_float(v.y & 0xffff0000u) * wp[3];
    acc += __uint_as_float(v.z << 16) * wp[4];
    acc += __uint_as_float(v.z & 0xffff0000u) * wp[5];
    acc += __uint_as_float(v.w << 16) * wp[6];
    acc += __uint_as_float(v.w & 0xffff0000u) * wp[7];
  }
  hgate[i] = acc;
}

// ------------- per-segment scatter softmax + weighted pooling -------------
__global__ __launch_bounds__(256) void seg_pool(
    const u16* __restrict__ Hm2, const float* __restrict__ hg,
    const int* __restrict__ sstart, const int* __restrict__ scount,
    float* __restrict__ hpool, float* __restrict__ scores) {
  __shared__ float red[256];
  const int s = blockIdx.x, t = threadIdx.x;
  const int cnt = scount[s];
  if (cnt == 0) {
    hpool[(size_t)s * D + t] = 0.0f;
    return;
  }
  const int r0 = sstart[s];

  float pm = -INFINITY;
  for (int i = t; i < cnt; i += 256) pm = fmaxf(pm, hg[r0 + i]);
  red[t] = pm;
  __syncthreads();
  for (int o = 128; o > 0; o >>= 1) {
    if (t < o) red[t] = fmaxf(red[t], red[t + o]);
    __syncthreads();
  }
  float m = red[0];
  __syncthreads();
  float ps = 0.f;
  for (int i = t; i < cnt; i += 256) ps += __expf(hg[r0 + i] - m);
  red[t] = ps;
  __syncthreads();
  for (int o = 128; o > 0; o >>= 1) {
    if (t < o) red[t] += red[t + o];
    __syncthreads();
  }
  float invden = 1.f / red[0];

  for (int i = t; i < cnt; i += 256)
    scores[r0 + i] = __expf(hg[r0 + i] - m) * invden;

  float acc = 0.f;
  for (int i = 0; i < cnt; ++i) {
    float w = __expf(hg[r0 + i] - m) * invden;
    acc += w * bf2f(Hm2[(size_t)(r0 + i) * D + t]);
  }
  hpool[(size_t)s * D + t] = acc;
}

// ---------------------------------------------------------------------
extern "C" void kernel_launch(void* const* d_in, const int* in_sizes, int n_in,
                              void* d_out, int out_size, void* d_ws, size_t ws_size,
                              hipStream_t stream) {
  const float* H      = (const float*)d_in[0];
  const int*   batch  = (const int*)d_in[1];
  const float* phi_w1 = (const float*)d_in[2];
  const float* phi_b1 = (const float*)d_in[3];
  const float* phi_w2 = (const float*)d_in[4];
  const float* phi_b2 = (const float*)d_in[5];
  const float* att_w  = (const float*)d_in[6];
  const float* att_b  = (const float*)d_in[7];
  const float* rho_w1 = (const float*)d_in[8];
  const float* rho_b1 = (const float*)d_in[9];
  const float* rho_w2 = (const float*)d_in[10];
  const float* rho_b2 = (const float*)d_in[11];
  const float* g_w1   = (const float*)d_in[12];
  const float* g_b1   = (const float*)d_in[13];
  const float* g_w2   = (const float*)d_in[14];
  const float* g_b2   = (const float*)d_in[15];
  const float* g_w3   = (const float*)d_in[16];
  const float* g_b3   = (const float*)d_in[17];

  float* out_hpool  = (float*)d_out;                      // [S, D]
  float* out_scores = (float*)d_out + (size_t)S_SEG * D;  // [N]

  char* w = (char*)d_ws;
  u16*   Hb    = (u16*)(w);                   // [N,256] bf16, 4MB
  u16*   Hfb   = (u16*)(w + (4u << 20));      // 4MB
  float* attF  = (float*)(w + (8u << 20));    // [N,256] f32, 8MB
  u16*   tmpb  = (u16*)(w + (16u << 20));     // 4MB: phi-hidden, then Hm
  u16*   t2b   = Hb;                          // rho-hidden (Hb dead)
  u16*   Hm2b  = Hfb;                         // rho out (Hfb dead)
  u16*   g1b   = (u16*)(w + (8u << 20));      // over attF (dead)
  u16*   g2b   = (u16*)(w + (10u << 20));
  float* hgate = (float*)(w + (12u << 20));   // [N]
  u16*   wb    = (u16*)(w + (20u << 20));
  u16* phi_w1b = wb;
  u16* phi_w2b = wb + 65536;
  u16* att_wb  = wb + 2 * 65536;
  u16* rho_w1b = wb + 3 * 65536;
  u16* rho_w2b = wb + 4 * 65536;
  u16* g_w1b   = wb + 5 * 65536;
  u16* g_w2b   = wb + 5 * 65536 + 32768;
  int* sstart  = (int*)(w + (21u << 20));
  int* scount  = sstart + S_SEG;

  hipMemsetAsync(scount, 0, S_SEG * sizeof(int), stream);
  seg_offsets<<<(N_NODES + 255) / 256, 256, 0, stream>>>(batch, sstart, scount, N_NODES);

  CvtJobs jb;
  jb.src[0] = H;      jb.dst[0] = Hb;      jb.n4[0] = N_NODES * D / 4;
  jb.src[1] = phi_w1; jb.dst[1] = phi_w1b; jb.n4[1] = 65536 / 4;
  jb.src[2] = phi_w2; jb.dst[2] = phi_w2b; jb.n4[2] = 65536 / 4;
  jb.src[3] = att_w;  jb.dst[3] = att_wb;  jb.n4[3] = 65536 / 4;
  jb.src[4] = rho_w1; jb.dst[4] = rho_w1b; jb.n4[4] = 65536 / 4;
  jb.src[5] = rho_w2; jb.dst[5] = rho_w2b; jb.n4[5] = 65536 / 4;
  jb.src[6] = g_w1;   jb.dst[6] = g_w1b;   jb.n4[6] = 32768 / 4;
  jb.src[7] = g_w2;   jb.dst[7] = g_w2b;   jb.n4[7] = 16384 / 4;
  cvt_bf16<<<dim3(128, 8), 256, 0, stream>>>(jb);

  dim3 blk(256);
  dim3 gD(N_NODES / 64, D / 128);    // 128 x 2
  dim3 gH(N_NODES / 64, HID / 128);  // 128 x 1

  // phi MLP (bf16 out)
  gemm_mfma<1, 1><<<gD, blk, 0, stream>>>(Hb,   phi_w1b, phi_b1, tmpb, D, D);
  gemm_mfma<1, 1><<<gD, blk, 0, stream>>>(tmpb, phi_w2b, phi_b2, Hfb,  D, D);
  // att projection (f32 out, no act)
  gemm_mfma<0, 0><<<gD, blk, 0, stream>>>(Hfb, att_wb, att_b, attF, D, D);
  // segment attention -> Hm (bf16, into tmpb)
  seg_attention2<<<S_SEG, 512, 0, stream>>>(attF, Hfb, tmpb, sstart, scount);
  // rho MLP
  gemm_mfma<1, 1><<<gD, blk, 0, stream>>>(tmpb, rho_w1b, rho_b1, t2b,  D, D);
  gemm_mfma<1, 1><<<gD, blk, 0, stream>>>(t2b,  rho_w2b, rho_b2, Hm2b, D, D);
  // gate MLP
  gemm_mfma<1, 1><<<gH, blk, 0, stream>>>(Hm2b, g_w1b, g_b1, g1b, HID, D);
  gemm_mfma<1, 1><<<gH, blk, 0, stream>>>(g1b,  g_w2b, g_b2, g2b, HID, HID);
  gate3<<<(N_NODES + 255) / 256, 256, 0, stream>>>(g2b, g_w3, g_b3, hgate, N_NODES);
  // scatter softmax + pooling
  seg_pool<<<S_SEG, blk, 0, stream>>>(Hm2b, hgate, sstart, scount, out_hpool, out_scores);
}

// Round 3
// 114.593 us; speedup vs baseline: 3.2009x; 1.6865x over previous
//
#include <hip/hip_runtime.h>
#include <math.h>

#define N_NODES 8192
#define D 256
#define HID 128
#define S_SEG 256

typedef __attribute__((ext_vector_type(8))) short short8;
typedef __attribute__((ext_vector_type(4))) float f32x4;
typedef unsigned short u16;
typedef unsigned int u32;

__device__ __forceinline__ u16 f2bf(float f) {
  u32 u = __float_as_uint(f);
  u32 r = (u + 0x7fffu + ((u >> 16) & 1u)) >> 16;
  return (u16)r;
}
__device__ __forceinline__ float bf2f(u16 b) {
  return __uint_as_float(((u32)b) << 16);
}
__device__ __forceinline__ int4 pack8(float4 x, float4 y) {
  int4 v;
  v.x = (int)(((u32)f2bf(x.y) << 16) | f2bf(x.x));
  v.y = (int)(((u32)f2bf(x.w) << 16) | f2bf(x.z));
  v.z = (int)(((u32)f2bf(y.y) << 16) | f2bf(y.x));
  v.w = (int)(((u32)f2bf(y.w) << 16) | f2bf(y.z));
  return v;
}

// ------- segment metadata: counts, starts, packed-P prefix (one block) -------
__global__ __launch_bounds__(256) void seg_meta_all(
    const int* __restrict__ batch, int* __restrict__ sstart,
    int* __restrict__ scount, int* __restrict__ pbase) {
  __shared__ int cntS[S_SEG];
  __shared__ int startS[S_SEG];
  __shared__ int v[S_SEG];
  const int t = threadIdx.x;
  cntS[t] = 0;
  startS[t] = 0;
  __syncthreads();
  const int base = t * 32;
  int pb = (base == 0) ? -1 : batch[base - 1];
  for (int i = 0; i < 32; ++i) {
    int b = batch[base + i];
    atomicAdd(&cntS[b], 1);
    if (b != pb) startS[b] = base + i;
    pb = b;
  }
  __syncthreads();
  int cnt = cntS[t];
  int cp = (cnt + 15) & ~15;
  int sq = cp * cp;
  v[t] = sq;
  __syncthreads();
  for (int off = 1; off < S_SEG; off <<= 1) {
    int add = (t >= off) ? v[t - off] : 0;
    __syncthreads();
    v[t] += add;
    __syncthreads();
  }
  scount[t] = cnt;
  sstart[t] = startS[t];
  pbase[t] = v[t] - sq;  // exclusive prefix of cnt_pad^2
}

// ---------------- f32 -> bf16 converter (weights) ----------------
struct CvtJobs {
  const float* src[7];
  u16* dst[7];
  int n4[7];
};
__global__ void cvt_bf16(CvtJobs jb) {
  int e = blockIdx.y;
  const float* s = jb.src[e];
  u16* d = jb.dst[e];
  int n4 = jb.n4[e];
  for (int i = blockIdx.x * blockDim.x + threadIdx.x; i < n4;
       i += gridDim.x * blockDim.x) {
    float4 v = ((const float4*)s)[i];
    ushort4 o;
    o.x = f2bf(v.x); o.y = f2bf(v.y); o.z = f2bf(v.z); o.w = f2bf(v.w);
    ((ushort4*)d)[i] = o;
  }
}

// ---------- MFMA GEMM: C[N,M] = act(A[N,K] @ W[M,K]^T + bias[M]) ----------
// tile 64x64, BK=64, 4 waves (wave owns 16 cols). AF32: A is f32 (cvt in staging).
// OUT: 0=f32, 1=bf16, 2=bf16 hi->C, residual lo->C2 (for accurate QK^T).
template <int ACT, int OUT, int AF32>
__global__ __launch_bounds__(256) void gemm_mfma(
    const void* __restrict__ Av, const u16* __restrict__ W,
    const float* __restrict__ bias, void* __restrict__ Cv,
    void* __restrict__ C2v, int M, int K) {
  __shared__ __align__(16) u16 Asb[64 * 64];
  __shared__ __align__(16) u16 Bsb[64 * 64];
  const int tid = threadIdx.x;
  const int wave = tid >> 6;
  const int lane = tid & 63;
  const size_t row0 = (size_t)blockIdx.x * 64;
  const int col0 = blockIdx.y * 64;

  f32x4 acc[4];
#pragma unroll
  for (int m = 0; m < 4; ++m) acc[m] = (f32x4){0.f, 0.f, 0.f, 0.f};

  for (int k0 = 0; k0 < K; k0 += 64) {
    __syncthreads();
#pragma unroll
    for (int q = 0; q < 2; ++q) {
      int c = tid + q * 256;
      int r = c >> 3, sl = c & 7;
      int4 va;
      if (AF32) {
        const float* Af = (const float*)Av;
        const float4* p = (const float4*)&Af[(row0 + r) * (size_t)K + k0 + sl * 8];
        va = pack8(p[0], p[1]);
      } else {
        va = *(const int4*)&((const u16*)Av)[(row0 + r) * (size_t)K + k0 + sl * 8];
      }
      *(int4*)((char*)Asb + r * 128 + ((sl ^ (r & 7)) * 16)) = va;
      int4 wv = *(const int4*)&W[(size_t)(col0 + r) * K + k0 + sl * 8];
      *(int4*)((char*)Bsb + r * 128 + ((sl ^ (r & 7)) * 16)) = wv;
    }
    __syncthreads();
#pragma unroll
    for (int kh = 0; kh < 2; ++kh) {
      int sg = kh * 4 + (lane >> 4);
      int br = wave * 16 + (lane & 15);
      short8 bfr = *(const short8*)((const char*)Bsb + br * 128 + ((sg ^ (br & 7)) * 16));
#pragma unroll
      for (int m = 0; m < 4; ++m) {
        int r = m * 16 + (lane & 15);
        short8 af = *(const short8*)((const char*)Asb + r * 128 + ((sg ^ (r & 7)) * 16));
        acc[m] = __builtin_amdgcn_mfma_f32_16x16x32_bf16(af, bfr, acc[m], 0, 0, 0);
      }
    }
  }

  const int rb = (lane >> 4) * 4;
  const int col = col0 + wave * 16 + (lane & 15);
  const float b = bias[col];
#pragma unroll
  for (int m = 0; m < 4; ++m) {
#pragma unroll
    for (int r = 0; r < 4; ++r) {
      float v = acc[m][r] + b;
      if (ACT) v = (v >= 0.f) ? v : 0.01f * v;
      size_t row = row0 + m * 16 + rb + r;
      if (OUT == 0) {
        ((float*)Cv)[row * M + col] = v;
      } else if (OUT == 1) {
        ((u16*)Cv)[row * M + col] = f2bf(v);
      } else {
        u16 hi = f2bf(v);
        ((u16*)Cv)[row * M + col] = hi;
        ((u16*)C2v)[row * M + col] = f2bf(v - bf2f(hi));
      }
    }
  }
}

// -------- QK^T per segment: P[i,j] = att_i . att_j (hi/lo split MFMA) --------
// one block per segment, 4 waves; wave computes 16x16 tiles round-robin.
__global__ __launch_bounds__(256) void seg_qk(
    const u16* __restrict__ ahi, const u16* __restrict__ alo,
    float* __restrict__ P, const int* __restrict__ sstart,
    const int* __restrict__ scount, const int* __restrict__ pbase) {
  const int s = blockIdx.x;
  const int cnt = scount[s];
  if (cnt == 0) return;
  const int r0 = sstart[s];
  const int cp = (cnt + 15) & ~15;
  const int nt = cp >> 4;
  const int ntiles = nt * nt;
  float* Ps = P + pbase[s];
  const int wave = threadIdx.x >> 6, lane = threadIdx.x & 63;
  const int lrow = lane & 15, koff = (lane >> 4) * 8;

  for (int t = wave; t < ntiles; t += 4) {
    int ti = t / nt, tj = t - ti * nt;
    const u16* ab = ahi + (size_t)(r0 + ti * 16 + lrow) * D + koff;
    const u16* al = alo + (size_t)(r0 + ti * 16 + lrow) * D + koff;
    const u16* bb = ahi + (size_t)(r0 + tj * 16 + lrow) * D + koff;
    const u16* bl = alo + (size_t)(r0 + tj * 16 + lrow) * D + koff;
    f32x4 acc = (f32x4){0.f, 0.f, 0.f, 0.f};
#pragma unroll
    for (int k0 = 0; k0 < D; k0 += 32) {
      short8 ah = *(const short8*)(ab + k0);
      short8 alv = *(const short8*)(al + k0);
      short8 bh = *(const short8*)(bb + k0);
      short8 blv = *(const short8*)(bl + k0);
      acc = __builtin_amdgcn_mfma_f32_16x16x32_bf16(ah, bh, acc, 0, 0, 0);
      acc = __builtin_amdgcn_mfma_f32_16x16x32_bf16(ah, blv, acc, 0, 0, 0);
      acc = __builtin_amdgcn_mfma_f32_16x16x32_bf16(alv, bh, acc, 0, 0, 0);
    }
    int i0 = ti * 16 + (lane >> 4) * 4;
    int j = tj * 16 + lrow;
#pragma unroll
    for (int r = 0; r < 4; ++r) Ps[(size_t)(i0 + r) * cp + j] = acc[r];
  }
}

// -------- row softmax over packed P (one wave per node row) --------
__global__ __launch_bounds__(256) void row_softmax(
    float* __restrict__ P, const int* __restrict__ batch,
    const int* __restrict__ sstart, const int* __restrict__ scount,
    const int* __restrict__ pbase) {
  const int node = blockIdx.x * 4 + (threadIdx.x >> 6);
  const int lane = threadIdx.x & 63;
  const int s = batch[node];
  const int cnt = scount[s];
  const int r0 = sstart[s];
  const int cp = (cnt + 15) & ~15;
  float* prow = P + pbase[s] + (size_t)(node - r0) * cp;

  float m = -INFINITY;
  for (int j = lane; j < cnt; j += 64) m = fmaxf(m, prow[j]);
#pragma unroll
  for (int o = 32; o > 0; o >>= 1) m = fmaxf(m, __shfl_xor(m, o));
  float sum = 0.f;
  for (int j = lane; j < cnt; j += 64) sum += __expf(prow[j] - m);
#pragma unroll
  for (int o = 32; o > 0; o >>= 1) sum += __shfl_xor(sum, o);
  float inv = 1.f / sum;
  for (int j = lane; j < cp; j += 64)
    prow[j] = (j < cnt) ? __expf(prow[j] - m) * inv : 0.f;
}

// -------- PV: Hm[i,:] = sum_j P[i,j] * Hf[j,:]  (one wave per node row) -----
__global__ __launch_bounds__(256) void seg_pv(
    const float* __restrict__ P, const u16* __restrict__ Hf,
    u16* __restrict__ Hm, const int* __restrict__ batch,
    const int* __restrict__ sstart, const int* __restrict__ scount,
    const int* __restrict__ pbase) {
  const int node = blockIdx.x * 4 + (threadIdx.x >> 6);
  const int lane = threadIdx.x & 63;
  const int s = batch[node];
  const int cnt = scount[s];
  const int r0 = sstart[s];
  const int cp = (cnt + 15) & ~15;
  const float* prow = P + pbase[s] + (size_t)(node - r0) * cp;

  float a0 = 0.f, a1 = 0.f, a2 = 0.f, a3 = 0.f;
  int j = 0;
  for (; j + 1 < cnt; j += 2) {
    float w0 = prow[j], w1 = prow[j + 1];
    uint2 h0 = *(const uint2*)&Hf[(size_t)(r0 + j) * D + lane * 4];
    uint2 h1 = *(const uint2*)&Hf[(size_t)(r0 + j + 1) * D + lane * 4];
    a0 += w0 * __uint_as_float(h0.x << 16) + w1 * __uint_as_float(h1.x << 16);
    a1 += w0 * __uint_as_float(h0.x & 0xffff0000u) + w1 * __uint_as_float(h1.x & 0xffff0000u);
    a2 += w0 * __uint_as_float(h0.y << 16) + w1 * __uint_as_float(h1.y << 16);
    a3 += w0 * __uint_as_float(h0.y & 0xffff0000u) + w1 * __uint_as_float(h1.y & 0xffff0000u);
  }
  if (j < cnt) {
    float w0 = prow[j];
    uint2 h0 = *(const uint2*)&Hf[(size_t)(r0 + j) * D + lane * 4];
    a0 += w0 * __uint_as_float(h0.x << 16);
    a1 += w0 * __uint_as_float(h0.x & 0xffff0000u);
    a2 += w0 * __uint_as_float(h0.y << 16);
    a3 += w0 * __uint_as_float(h0.y & 0xffff0000u);
  }
  ushort4 o;
  o.x = f2bf(a0); o.y = f2bf(a1); o.z = f2bf(a2); o.w = f2bf(a3);
  *(ushort4*)&Hm[(size_t)node * D + lane * 4] = o;
}

// ---------------- final gate layer ----------------
__global__ void gate3(const u16* __restrict__ g2, const float* __restrict__ w3,
                      const float* __restrict__ b3, float* __restrict__ hgate,
                      int n) {
  int i = blockIdx.x * blockDim.x + threadIdx.x;
  if (i >= n) return;
  const uint4* a = (const uint4*)&g2[(size_t)i * HID];
  float acc = b3[0];
#pragma unroll 4
  for (int k = 0; k < HID / 8; ++k) {
    uint4 v = a[k];
    const float* wp = &w3[k * 8];
    acc += __uint_as_float(v.x << 16) * wp[0];
    acc += __uint_as_float(v.x & 0xffff0000u) * wp[1];
    acc += __uint_as_float(v.y << 16) * wp[2];
    acc += __uint_as_float(v.y & 0xffff0000u) * wp[3];
    acc += __uint_as_float(v.z << 16) * wp[4];
    acc += __uint_as_float(v.z & 0xffff0000u) * wp[5];
    acc += __uint_as_float(v.w << 16) * wp[6];
    acc += __uint_as_float(v.w & 0xffff0000u) * wp[7];
  }
  hgate[i] = acc;
}

// ------------- per-segment scatter softmax + weighted pooling -------------
__global__ __launch_bounds__(512) void seg_pool(
    const u16* __restrict__ Hm2, const float* __restrict__ hg,
    const int* __restrict__ sstart, const int* __restrict__ scount,
    float* __restrict__ hpool, float* __restrict__ scores) {
  __shared__ float red[512];
  __shared__ float part[512];
  const int s = blockIdx.x, t = threadIdx.x;
  const int cnt = scount[s];
  if (cnt == 0) {
    if (t < 256) hpool[(size_t)s * D + t] = 0.0f;
    return;
  }
  const int r0 = sstart[s];

  float pm = -INFINITY;
  for (int i = t; i < cnt; i += 512) pm = fmaxf(pm, hg[r0 + i]);
  red[t] = pm;
  __syncthreads();
  for (int o = 256; o > 0; o >>= 1) {
    if (t < o) red[t] = fmaxf(red[t], red[t + o]);
    __syncthreads();
  }
  float m = red[0];
  __syncthreads();
  float ps = 0.f;
  for (int i = t; i < cnt; i += 512) ps += __expf(hg[r0 + i] - m);
  red[t] = ps;
  __syncthreads();
  for (int o = 256; o > 0; o >>= 1) {
    if (t < o) red[t] += red[t + o];
    __syncthreads();
  }
  float inv = 1.f / red[0];

  for (int i = t; i < cnt; i += 512)
    scores[r0 + i] = __expf(hg[r0 + i] - m) * inv;

  const int h = t >> 8, d = t & 255;
  float acc = 0.f;
  for (int i = h; i < cnt; i += 2)
    acc += __expf(hg[r0 + i] - m) * inv * bf2f(Hm2[(size_t)(r0 + i) * D + d]);
  part[t] = acc;
  __syncthreads();
  if (t < 256) hpool[(size_t)s * D + t] = part[t] + part[t + 256];
}

// ---------------------------------------------------------------------
extern "C" void kernel_launch(void* const* d_in, const int* in_sizes, int n_in,
                              void* d_out, int out_size, void* d_ws, size_t ws_size,
                              hipStream_t stream) {
  const float* H      = (const float*)d_in[0];
  const int*   batch  = (const int*)d_in[1];
  const float* phi_w1 = (const float*)d_in[2];
  const float* phi_b1 = (const float*)d_in[3];
  const float* phi_w2 = (const float*)d_in[4];
  const float* phi_b2 = (const float*)d_in[5];
  const float* att_w  = (const float*)d_in[6];
  const float* att_b  = (const float*)d_in[7];
  const float* rho_w1 = (const float*)d_in[8];
  const float* rho_b1 = (const float*)d_in[9];
  const float* rho_w2 = (const float*)d_in[10];
  const float* rho_b2 = (const float*)d_in[11];
  const float* g_w1   = (const float*)d_in[12];
  const float* g_b1   = (const float*)d_in[13];
  const float* g_w2   = (const float*)d_in[14];
  const float* g_b2   = (const float*)d_in[15];
  const float* g_w3   = (const float*)d_in[16];
  const float* g_b3   = (const float*)d_in[17];

  float* out_hpool  = (float*)d_out;
  float* out_scores = (float*)d_out + (size_t)S_SEG * D;

  char* w = (char*)d_ws;
  const size_t MB = 1u << 20;
  u16*   wb     = (u16*)(w);               // weights bf16, <1MB
  u16*   tmp1   = (u16*)(w + 1 * MB);      // phi hidden -> Hm
  u16*   Hfb    = (u16*)(w + 5 * MB);      // Hf -> Hm2
  u16*   att_hi = (u16*)(w + 9 * MB);      // -> rho hidden
  u16*   att_lo = (u16*)(w + 13 * MB);     // -> g1
  float* P      = (float*)(w + 17 * MB);   // packed P, <=8MB (sum cnt_pad^2)
  float* hgate  = (float*)(w + 25 * MB);
  int*   sstart = (int*)(w + 25 * MB + 64 * 1024);
  int*   scount = sstart + S_SEG;
  int*   pbase  = scount + S_SEG;
  u16*   Hm     = tmp1;
  u16*   rhoh   = att_hi;
  u16*   Hm2    = Hfb;
  u16*   g1b    = att_lo;
  u16*   g2b    = (u16*)(w + 15 * MB);

  u16* phi_w1b = wb;
  u16* phi_w2b = wb + 65536;
  u16* att_wb  = wb + 2 * 65536;
  u16* rho_w1b = wb + 3 * 65536;
  u16* rho_w2b = wb + 4 * 65536;
  u16* g_w1b   = wb + 5 * 65536;
  u16* g_w2b   = wb + 5 * 65536 + 32768;

  seg_meta_all<<<1, 256, 0, stream>>>(batch, sstart, scount, pbase);

  CvtJobs jb;
  jb.src[0] = phi_w1; jb.dst[0] = phi_w1b; jb.n4[0] = 65536 / 4;
  jb.src[1] = phi_w2; jb.dst[1] = phi_w2b; jb.n4[1] = 65536 / 4;
  jb.src[2] = att_w;  jb.dst[2] = att_wb;  jb.n4[2] = 65536 / 4;
  jb.src[3] = rho_w1; jb.dst[3] = rho_w1b; jb.n4[3] = 65536 / 4;
  jb.src[4] = rho_w2; jb.dst[4] = rho_w2b; jb.n4[4] = 65536 / 4;
  jb.src[5] = g_w1;   jb.dst[5] = g_w1b;   jb.n4[5] = 32768 / 4;
  jb.src[6] = g_w2;   jb.dst[6] = g_w2b;   jb.n4[6] = 16384 / 4;
  cvt_bf16<<<dim3(64, 7), 256, 0, stream>>>(jb);

  dim3 blk(256);
  dim3 gDD(N_NODES / 64, D / 64);    // 128 x 4
  dim3 gDH(N_NODES / 64, HID / 64);  // 128 x 2

  // phi MLP (A f32 for first layer)
  gemm_mfma<1, 1, 1><<<gDD, blk, 0, stream>>>(H,    phi_w1b, phi_b1, tmp1, nullptr, D, D);
  gemm_mfma<1, 1, 0><<<gDD, blk, 0, stream>>>(tmp1, phi_w2b, phi_b2, Hfb,  nullptr, D, D);
  // att projection, split hi/lo output
  gemm_mfma<0, 2, 0><<<gDD, blk, 0, stream>>>(Hfb, att_wb, att_b, att_hi, att_lo, D, D);
  // attention
  seg_qk<<<S_SEG, blk, 0, stream>>>(att_hi, att_lo, P, sstart, scount, pbase);
  row_softmax<<<N_NODES / 4, blk, 0, stream>>>(P, batch, sstart, scount, pbase);
  seg_pv<<<N_NODES / 4, blk, 0, stream>>>(P, Hfb, Hm, batch, sstart, scount, pbase);
  // rho MLP
  gemm_mfma<1, 1, 0><<<gDD, blk, 0, stream>>>(Hm,   rho_w1b, rho_b1, rhoh, nullptr, D, D);
  gemm_mfma<1, 1, 0><<<gDD, blk, 0, stream>>>(rhoh, rho_w2b, rho_b2, Hm2,  nullptr, D, D);
  // gate MLP
  gemm_mfma<1, 1, 0><<<gDH, blk, 0, stream>>>(Hm2, g_w1b, g_b1, g1b, nullptr, HID, D);
  gemm_mfma<1, 1, 0><<<gDH, blk, 0, stream>>>(g1b, g_w2b, g_b2, g2b, nullptr, HID, HID);
  gate3<<<N_NODES / 256, 256, 0, stream>>>(g2b, g_w3, g_b3, hgate, N_NODES);
  // scatter softmax + pooling
  seg_pool<<<S_SEG, 512, 0, stream>>>(Hm2, hgate, sstart, scount, out_hpool, out_scores);
}

// Round 4
// 86.795 us; speedup vs baseline: 4.2261x; 1.3203x over previous
//
#include <hip/hip_runtime.h>
#include <math.h>

#define N_NODES 8192
#define D 256
#define HID 128
#define S_SEG 256
#define MAXC 112

typedef __attribute__((ext_vector_type(8))) short short8;
typedef __attribute__((ext_vector_type(4))) float f32x4;
typedef unsigned short u16;
typedef unsigned int u32;

__device__ __forceinline__ u16 f2bf(float f) {
  u32 u = __float_as_uint(f);
  u32 r = (u + 0x7fffu + ((u >> 16) & 1u)) >> 16;
  return (u16)r;
}
__device__ __forceinline__ float bf2f(u16 b) {
  return __uint_as_float(((u32)b) << 16);
}
__device__ __forceinline__ int4 pack8(float4 x, float4 y) {
  int4 v;
  v.x = (int)(((u32)f2bf(x.y) << 16) | f2bf(x.x));
  v.y = (int)(((u32)f2bf(x.w) << 16) | f2bf(x.z));
  v.z = (int)(((u32)f2bf(y.y) << 16) | f2bf(y.x));
  v.w = (int)(((u32)f2bf(y.w) << 16) | f2bf(y.z));
  return v;
}

// ---------------- prep: block 0 = segment meta; blocks 1..56 = weight cvt ----
struct CvtJobs {
  const float* src[7];
  u16* dst[7];
  int n4[7];
};
__global__ __launch_bounds__(256) void prep(const int* __restrict__ batch,
                                            int* __restrict__ sstart,
                                            int* __restrict__ scount, CvtJobs jb) {
  if (blockIdx.x == 0) {
    __shared__ int cntS[S_SEG];
    __shared__ int startS[S_SEG];
    const int t = threadIdx.x;
    cntS[t] = 0;
    startS[t] = 0;
    __syncthreads();
    const int base = t * 32;
    int pb = (base == 0) ? -1 : batch[base - 1];
    for (int i = 0; i < 32; ++i) {
      int b = batch[base + i];
      atomicAdd(&cntS[b], 1);
      if (b != pb) startS[b] = base + i;
      pb = b;
    }
    __syncthreads();
    scount[t] = cntS[t];
    sstart[t] = startS[t];
  } else {
    const int bid = blockIdx.x - 1;
    const int job = bid >> 3, chunk = bid & 7;
    const float* s = jb.src[job];
    u16* d = jb.dst[job];
    const int n4 = jb.n4[job];
    for (int i = chunk * 256 + threadIdx.x; i < n4; i += 2048) {
      float4 v = ((const float4*)s)[i];
      ushort4 o;
      o.x = f2bf(v.x); o.y = f2bf(v.y); o.z = f2bf(v.z); o.w = f2bf(v.w);
      ((ushort4*)d)[i] = o;
    }
  }
}

// ---- one MLP layer for a 32-row LDS-resident block ----
// out[32,M] = act(in[32,K] @ W[M,K]^T + bias). 512 thr = 8 waves; wave owns
// 16 cols per pass; NPASS = M/128; KST = K/32. A-frags held in VGPRs,
// B-frags streamed from global (L2-resident weights).
// MODE: 0 = LDS out only; 1 = LDS + global bf16; 2 = global hi/lo (no LDS).
template <int KST, int NPASS, int ACT, int MODE>
__device__ __forceinline__ void mlp_layer(
    const u16* ldsIn, u16* ldsOut, const u16* __restrict__ Wg,
    const float* __restrict__ bias, u16* __restrict__ gOut,
    u16* __restrict__ gOut2, int M, int K, int lane, int wave) {
  short8 af[2][KST];
#pragma unroll
  for (int m = 0; m < 2; ++m)
#pragma unroll
    for (int kk = 0; kk < KST; ++kk) {
      int r = m * 16 + (lane & 15);
      int sl = kk * 4 + (lane >> 4);
      af[m][kk] = *(const short8*)((const char*)ldsIn + r * 512 + ((sl ^ (r & 7)) * 16));
    }
#pragma unroll
  for (int p = 0; p < NPASS; ++p) {
    const int col = p * 128 + wave * 16 + (lane & 15);
    short8 bfr[KST];
#pragma unroll
    for (int kk = 0; kk < KST; ++kk)
      bfr[kk] = *(const short8*)&Wg[(size_t)col * K + kk * 32 + (lane >> 4) * 8];
    f32x4 acc0 = {0.f, 0.f, 0.f, 0.f}, acc1 = {0.f, 0.f, 0.f, 0.f};
#pragma unroll
    for (int kk = 0; kk < KST; ++kk) {
      acc0 = __builtin_amdgcn_mfma_f32_16x16x32_bf16(af[0][kk], bfr[kk], acc0, 0, 0, 0);
      acc1 = __builtin_amdgcn_mfma_f32_16x16x32_bf16(af[1][kk], bfr[kk], acc1, 0, 0, 0);
    }
    const float b = bias[col];
    const int rb = (lane >> 4) * 4;
#pragma unroll
    for (int m = 0; m < 2; ++m) {
      f32x4 a = m ? acc1 : acc0;
#pragma unroll
      for (int r = 0; r < 4; ++r) {
        float v = a[r] + b;
        if (ACT) v = (v >= 0.f) ? v : 0.01f * v;
        const int row = m * 16 + rb + r;
        if constexpr (MODE == 2) {
          u16 hi = f2bf(v);
          gOut[(size_t)row * M + col] = hi;
          gOut2[(size_t)row * M + col] = f2bf(v - bf2f(hi));
        } else {
          u16 hv = f2bf(v);
          *(u16*)((char*)ldsOut + row * 512 + (((col >> 3) ^ (row & 7)) * 16) +
                  (col & 7) * 2) = hv;
          if constexpr (MODE == 1) gOut[(size_t)row * M + col] = hv;
        }
      }
    }
  }
}

// ---- fusedA: H -> phi1 -> phi2 (Hf out) -> att (hi/lo out); 32 rows/block ----
__global__ __launch_bounds__(512, 2) void fusedA(
    const float* __restrict__ H, const u16* __restrict__ w1,
    const float* __restrict__ b1, const u16* __restrict__ w2,
    const float* __restrict__ b2, const u16* __restrict__ w3,
    const float* __restrict__ b3, u16* __restrict__ Hf,
    u16* __restrict__ ahi, u16* __restrict__ alo) {
  __shared__ __align__(16) u16 bufX[32 * 256];
  __shared__ __align__(16) u16 bufY[32 * 256];
  const int tid = threadIdx.x, wave = tid >> 6, lane = tid & 63;
  const size_t row0 = (size_t)blockIdx.x * 32;
  {
    int r = tid >> 4, part = tid & 15;
    const float4* src = (const float4*)&H[(row0 + r) * D + part * 16];
#pragma unroll
    for (int i = 0; i < 2; ++i) {
      int4 v = pack8(src[2 * i], src[2 * i + 1]);
      int sl = part * 2 + i;
      *(int4*)((char*)bufX + r * 512 + ((sl ^ (r & 7)) * 16)) = v;
    }
  }
  __syncthreads();
  mlp_layer<8, 2, 1, 0>(bufX, bufY, w1, b1, nullptr, nullptr, D, D, lane, wave);
  __syncthreads();
  mlp_layer<8, 2, 1, 1>(bufY, bufX, w2, b2, Hf + row0 * D, nullptr, D, D, lane, wave);
  __syncthreads();
  mlp_layer<8, 2, 0, 2>(bufX, nullptr, w3, b3, ahi + row0 * D, alo + row0 * D, D, D,
                        lane, wave);
}

// ---- fusedB: Hm -> rho1 -> rho2 (Hm2 out) -> g1 -> g2 -> gate3 (hgate) ----
__global__ __launch_bounds__(512, 2) void fusedB(
    const u16* __restrict__ Hm, const u16* __restrict__ rw1,
    const float* __restrict__ rb1, const u16* __restrict__ rw2,
    const float* __restrict__ rb2, const u16* __restrict__ gw1,
    const float* __restrict__ gb1, const u16* __restrict__ gw2,
    const float* __restrict__ gb2, const float* __restrict__ gw3,
    const float* __restrict__ gb3, u16* __restrict__ Hm2,
    float* __restrict__ hgate) {
  __shared__ __align__(16) u16 bufX[32 * 256];
  __shared__ __align__(16) u16 bufY[32 * 256];
  const int tid = threadIdx.x, wave = tid >> 6, lane = tid & 63;
  const size_t row0 = (size_t)blockIdx.x * 32;
  {
    int r = tid >> 4, part = tid & 15;
    const int4* src = (const int4*)&Hm[(row0 + r) * D + part * 16];
#pragma unroll
    for (int i = 0; i < 2; ++i) {
      int sl = part * 2 + i;
      *(int4*)((char*)bufX + r * 512 + ((sl ^ (r & 7)) * 16)) = src[i];
    }
  }
  __syncthreads();
  mlp_layer<8, 2, 1, 0>(bufX, bufY, rw1, rb1, nullptr, nullptr, D, D, lane, wave);
  __syncthreads();
  mlp_layer<8, 2, 1, 1>(bufY, bufX, rw2, rb2, Hm2 + row0 * D, nullptr, D, D, lane, wave);
  __syncthreads();
  mlp_layer<8, 1, 1, 0>(bufX, bufY, gw1, gb1, nullptr, nullptr, HID, D, lane, wave);
  __syncthreads();
  mlp_layer<4, 1, 1, 0>(bufY, bufX, gw2, gb2, nullptr, nullptr, HID, HID, lane, wave);
  __syncthreads();
  {
    int r = tid >> 4, part = tid & 15;
    int k0 = part * 8;
    int sl = k0 >> 3;
    short8 hv = *(const short8*)((const char*)bufX + r * 512 + ((sl ^ (r & 7)) * 16));
    float s = 0.f;
#pragma unroll
    for (int i = 0; i < 8; ++i) s += bf2f((u16)hv[i]) * gw3[k0 + i];
    s += __shfl_xor(s, 1);
    s += __shfl_xor(s, 2);
    s += __shfl_xor(s, 4);
    s += __shfl_xor(s, 8);
    if (part == 0) hgate[row0 + r] = s + gb3[0];
  }
}

// ---- fused per-segment attention: QK^T (hi/lo MFMA) + softmax + PV ----
__global__ __launch_bounds__(512) void seg_attn(
    const u16* __restrict__ ahi, const u16* __restrict__ alo,
    const u16* __restrict__ Hf, u16* __restrict__ Hm,
    const int* __restrict__ sstart, const int* __restrict__ scount) {
  __shared__ float P[MAXC][MAXC + 1];
  __shared__ float red[512];
  const int s = blockIdx.x, t = threadIdx.x;
  const int cnt = scount[s];
  if (cnt == 0) return;
  const int r0 = sstart[s];
  const int wave = t >> 6, lane = t & 63;

  if (cnt <= MAXC) {
    const int cp = (cnt + 15) & ~15;
    const int nt = cp >> 4;
    const int ntiles = nt * nt;
    const int lrow = lane & 15, koff = (lane >> 4) * 8;
    for (int tt = wave; tt < ntiles; tt += 8) {
      int ti = tt / nt, tj = tt - ti * nt;
      int ra = r0 + ti * 16 + lrow;
      if (ra > N_NODES - 1) ra = N_NODES - 1;
      int rb = r0 + tj * 16 + lrow;
      if (rb > N_NODES - 1) rb = N_NODES - 1;
      const u16* abp = ahi + (size_t)ra * D + koff;
      const u16* alp = alo + (size_t)ra * D + koff;
      const u16* bbp = ahi + (size_t)rb * D + koff;
      const u16* blp = alo + (size_t)rb * D + koff;
      f32x4 acc = {0.f, 0.f, 0.f, 0.f};
#pragma unroll
      for (int k0 = 0; k0 < D; k0 += 32) {
        short8 ah = *(const short8*)(abp + k0);
        short8 av = *(const short8*)(alp + k0);
        short8 bh = *(const short8*)(bbp + k0);
        short8 bv = *(const short8*)(blp + k0);
        acc = __builtin_amdgcn_mfma_f32_16x16x32_bf16(ah, bh, acc, 0, 0, 0);
        acc = __builtin_amdgcn_mfma_f32_16x16x32_bf16(ah, bv, acc, 0, 0, 0);
        acc = __builtin_amdgcn_mfma_f32_16x16x32_bf16(av, bh, acc, 0, 0, 0);
      }
      int i0 = ti * 16 + (lane >> 4) * 4;
      int j = tj * 16 + lrow;
#pragma unroll
      for (int r = 0; r < 4; ++r) P[i0 + r][j] = acc[r];
    }
    __syncthreads();
    for (int i = wave; i < cnt; i += 8) {
      float* row = P[i];
      float m = -INFINITY;
      for (int j = lane; j < cnt; j += 64) m = fmaxf(m, row[j]);
#pragma unroll
      for (int o = 32; o > 0; o >>= 1) m = fmaxf(m, __shfl_xor(m, o));
      float sum = 0.f;
      for (int j = lane; j < cnt; j += 64) sum += __expf(row[j] - m);
#pragma unroll
      for (int o = 32; o > 0; o >>= 1) sum += __shfl_xor(sum, o);
      float inv = 1.f / sum;
      for (int j = lane; j < cnt; j += 64) row[j] = __expf(row[j] - m) * inv;
    }
    __syncthreads();
    for (int i = wave; i < cnt; i += 8) {
      const float* Pi = P[i];
      float a0 = 0.f, a1 = 0.f, a2 = 0.f, a3 = 0.f;
      int j = 0;
      for (; j + 1 < cnt; j += 2) {
        float w0 = Pi[j], w1 = Pi[j + 1];
        uint2 h0 = *(const uint2*)&Hf[(size_t)(r0 + j) * D + lane * 4];
        uint2 h1 = *(const uint2*)&Hf[(size_t)(r0 + j + 1) * D + lane * 4];
        a0 += w0 * __uint_as_float(h0.x << 16) + w1 * __uint_as_float(h1.x << 16);
        a1 += w0 * __uint_as_float(h0.x & 0xffff0000u) + w1 * __uint_as_float(h1.x & 0xffff0000u);
        a2 += w0 * __uint_as_float(h0.y << 16) + w1 * __uint_as_float(h1.y << 16);
        a3 += w0 * __uint_as_float(h0.y & 0xffff0000u) + w1 * __uint_as_float(h1.y & 0xffff0000u);
      }
      if (j < cnt) {
        float w0 = Pi[j];
        uint2 h0 = *(const uint2*)&Hf[(size_t)(r0 + j) * D + lane * 4];
        a0 += w0 * __uint_as_float(h0.x << 16);
        a1 += w0 * __uint_as_float(h0.x & 0xffff0000u);
        a2 += w0 * __uint_as_float(h0.y << 16);
        a3 += w0 * __uint_as_float(h0.y & 0xffff0000u);
      }
      ushort4 o;
      o.x = f2bf(a0); o.y = f2bf(a1); o.z = f2bf(a2); o.w = f2bf(a3);
      *(ushort4*)&Hm[(size_t)(r0 + i) * D + lane * 4] = o;
    }
  } else {
    // fallback for cnt > MAXC (correct for any cnt <= N): row-serial two-pass
    float* Pf = &P[0][0];  // 12656 floats >= N_NODES? cnt <= 8192 fits
    for (int i = 0; i < cnt; ++i) {
      int ri = r0 + i;
      const u16* ai = ahi + (size_t)ri * D;
      const u16* li = alo + (size_t)ri * D;
      for (int j = t; j < cnt; j += 512) {
        const u16* aj = ahi + (size_t)(r0 + j) * D;
        const u16* lj = alo + (size_t)(r0 + j) * D;
        float acc = 0.f;
        for (int k = 0; k < D; ++k) {
          float x = bf2f(ai[k]) + bf2f(li[k]);
          float y = bf2f(aj[k]) + bf2f(lj[k]);
          acc += x * y;
        }
        Pf[j] = acc;
      }
      __syncthreads();
      float pm = -INFINITY;
      for (int j = t; j < cnt; j += 512) pm = fmaxf(pm, Pf[j]);
      red[t] = pm;
      __syncthreads();
      for (int o = 256; o > 0; o >>= 1) {
        if (t < o) red[t] = fmaxf(red[t], red[t + o]);
        __syncthreads();
      }
      float m = red[0];
      __syncthreads();
      float ps = 0.f;
      for (int j = t; j < cnt; j += 512) {
        float e = __expf(Pf[j] - m);
        Pf[j] = e;
        ps += e;
      }
      red[t] = ps;
      __syncthreads();
      for (int o = 256; o > 0; o >>= 1) {
        if (t < o) red[t] += red[t + o];
        __syncthreads();
      }
      float inv = 1.f / red[0];
      if (t < D) {
        float acc = 0.f;
        for (int j = 0; j < cnt; ++j)
          acc += Pf[j] * bf2f(Hf[(size_t)(r0 + j) * D + t]);
        Hm[(size_t)ri * D + t] = f2bf(acc * inv);
      }
      __syncthreads();
    }
  }
}

// ------------- per-segment scatter softmax + weighted pooling -------------
__global__ __launch_bounds__(512) void seg_pool(
    const u16* __restrict__ Hm2, const float* __restrict__ hg,
    const int* __restrict__ sstart, const int* __restrict__ scount,
    float* __restrict__ hpool, float* __restrict__ scores) {
  __shared__ float red[512];
  __shared__ float part[512];
  const int s = blockIdx.x, t = threadIdx.x;
  const int cnt = scount[s];
  if (cnt == 0) {
    if (t < 256) hpool[(size_t)s * D + t] = 0.0f;
    return;
  }
  const int r0 = sstart[s];

  float pm = -INFINITY;
  for (int i = t; i < cnt; i += 512) pm = fmaxf(pm, hg[r0 + i]);
  red[t] = pm;
  __syncthreads();
  for (int o = 256; o > 0; o >>= 1) {
    if (t < o) red[t] = fmaxf(red[t], red[t + o]);
    __syncthreads();
  }
  float m = red[0];
  __syncthreads();
  float ps = 0.f;
  for (int i = t; i < cnt; i += 512) ps += __expf(hg[r0 + i] - m);
  red[t] = ps;
  __syncthreads();
  for (int o = 256; o > 0; o >>= 1) {
    if (t < o) red[t] += red[t + o];
    __syncthreads();
  }
  float inv = 1.f / red[0];

  for (int i = t; i < cnt; i += 512)
    scores[r0 + i] = __expf(hg[r0 + i] - m) * inv;

  const int h = t >> 8, d = t & 255;
  float acc = 0.f;
  for (int i = h; i < cnt; i += 2)
    acc += __expf(hg[r0 + i] - m) * inv * bf2f(Hm2[(size_t)(r0 + i) * D + d]);
  part[t] = acc;
  __syncthreads();
  if (t < 256) hpool[(size_t)s * D + t] = part[t] + part[t + 256];
}

// ---------------------------------------------------------------------
extern "C" void kernel_launch(void* const* d_in, const int* in_sizes, int n_in,
                              void* d_out, int out_size, void* d_ws, size_t ws_size,
                              hipStream_t stream) {
  const float* H      = (const float*)d_in[0];
  const int*   batch  = (const int*)d_in[1];
  const float* phi_w1 = (const float*)d_in[2];
  const float* phi_b1 = (const float*)d_in[3];
  const float* phi_w2 = (const float*)d_in[4];
  const float* phi_b2 = (const float*)d_in[5];
  const float* att_w  = (const float*)d_in[6];
  const float* att_b  = (const float*)d_in[7];
  const float* rho_w1 = (const float*)d_in[8];
  const float* rho_b1 = (const float*)d_in[9];
  const float* rho_w2 = (const float*)d_in[10];
  const float* rho_b2 = (const float*)d_in[11];
  const float* g_w1   = (const float*)d_in[12];
  const float* g_b1   = (const float*)d_in[13];
  const float* g_w2   = (const float*)d_in[14];
  const float* g_b2   = (const float*)d_in[15];
  const float* g_w3   = (const float*)d_in[16];
  const float* g_b3   = (const float*)d_in[17];

  float* out_hpool  = (float*)d_out;
  float* out_scores = (float*)d_out + (size_t)S_SEG * D;

  char* w = (char*)d_ws;
  const size_t MB = 1u << 20;
  u16*   wb     = (u16*)(w);              // weights bf16 (<1MB)
  u16*   Hfb    = (u16*)(w + 1 * MB);     // 4MB
  u16*   att_hi = (u16*)(w + 5 * MB);     // 4MB
  u16*   att_lo = (u16*)(w + 9 * MB);     // 4MB
  u16*   Hm     = (u16*)(w + 13 * MB);    // 4MB
  u16*   Hm2    = (u16*)(w + 17 * MB);    // 4MB
  float* hgate  = (float*)(w + 21 * MB);  // 32KB
  int*   sstart = (int*)(w + 21 * MB + 64 * 1024);
  int*   scount = sstart + S_SEG;

  u16* phi_w1b = wb;
  u16* phi_w2b = wb + 65536;
  u16* att_wb  = wb + 2 * 65536;
  u16* rho_w1b = wb + 3 * 65536;
  u16* rho_w2b = wb + 4 * 65536;
  u16* g_w1b   = wb + 5 * 65536;
  u16* g_w2b   = wb + 5 * 65536 + 32768;

  CvtJobs jb;
  jb.src[0] = phi_w1; jb.dst[0] = phi_w1b; jb.n4[0] = 65536 / 4;
  jb.src[1] = phi_w2; jb.dst[1] = phi_w2b; jb.n4[1] = 65536 / 4;
  jb.src[2] = att_w;  jb.dst[2] = att_wb;  jb.n4[2] = 65536 / 4;
  jb.src[3] = rho_w1; jb.dst[3] = rho_w1b; jb.n4[3] = 65536 / 4;
  jb.src[4] = rho_w2; jb.dst[4] = rho_w2b; jb.n4[4] = 65536 / 4;
  jb.src[5] = g_w1;   jb.dst[5] = g_w1b;   jb.n4[5] = 32768 / 4;
  jb.src[6] = g_w2;   jb.dst[6] = g_w2b;   jb.n4[6] = 16384 / 4;

  prep<<<57, 256, 0, stream>>>(batch, sstart, scount, jb);

  fusedA<<<N_NODES / 32, 512, 0, stream>>>(H, phi_w1b, phi_b1, phi_w2b, phi_b2,
                                           att_wb, att_b, Hfb, att_hi, att_lo);

  seg_attn<<<S_SEG, 512, 0, stream>>>(att_hi, att_lo, Hfb, Hm, sstart, scount);

  fusedB<<<N_NODES / 32, 512, 0, stream>>>(Hm, rho_w1b, rho_b1, rho_w2b, rho_b2,
                                           g_w1b, g_b1, g_w2b, g_b2, g_w3, g_b3,
                                           Hm2, hgate);

  seg_pool<<<S_SEG, 512, 0, stream>>>(Hm2, hgate, sstart, scount, out_hpool,
                                      out_scores);
}

// Round 5
// 80.233 us; speedup vs baseline: 4.5717x; 1.0818x over previous
//
#include <hip/hip_runtime.h>
#include <math.h>

#define N_NODES 8192
#define D 256
#define HID 128
#define S_SEG 256
#define MAXC 96
#define PST (MAXC + 1)

typedef __attribute__((ext_vector_type(8))) short short8;
typedef __attribute__((ext_vector_type(4))) float f32x4;
typedef unsigned short u16;
typedef unsigned int u32;

__device__ __forceinline__ u16 f2bf(float f) {
  u32 u = __float_as_uint(f);
  u32 r = (u + 0x7fffu + ((u >> 16) & 1u)) >> 16;
  return (u16)r;
}
__device__ __forceinline__ float bf2f(u16 b) {
  return __uint_as_float(((u32)b) << 16);
}
__device__ __forceinline__ int4 pack8(float4 x, float4 y) {
  int4 v;
  v.x = (int)(((u32)f2bf(x.y) << 16) | f2bf(x.x));
  v.y = (int)(((u32)f2bf(x.w) << 16) | f2bf(x.z));
  v.z = (int)(((u32)f2bf(y.y) << 16) | f2bf(y.x));
  v.w = (int)(((u32)f2bf(y.w) << 16) | f2bf(y.z));
  return v;
}

// ---------------- prep: block 0 = segment meta; blocks 1..56 = weight cvt ----
struct CvtJobs {
  const float* src[7];
  u16* dst[7];
  int n4[7];
};
__global__ __launch_bounds__(256) void prep(const int* __restrict__ batch,
                                            int* __restrict__ sstart,
                                            int* __restrict__ scount, CvtJobs jb) {
  if (blockIdx.x == 0) {
    __shared__ int cntS[S_SEG];
    __shared__ int startS[S_SEG];
    const int t = threadIdx.x;
    cntS[t] = 0;
    startS[t] = 0;
    __syncthreads();
    const int base = t * 32;
    int pb = (base == 0) ? -1 : batch[base - 1];
    for (int i = 0; i < 32; ++i) {
      int b = batch[base + i];
      atomicAdd(&cntS[b], 1);
      if (b != pb) startS[b] = base + i;
      pb = b;
    }
    __syncthreads();
    scount[t] = cntS[t];
    sstart[t] = startS[t];
  } else {
    const int bid = blockIdx.x - 1;
    const int job = bid >> 3, chunk = bid & 7;
    const float* s = jb.src[job];
    u16* d = jb.dst[job];
    const int n4 = jb.n4[job];
    for (int i = chunk * 256 + threadIdx.x; i < n4; i += 2048) {
      float4 v = ((const float4*)s)[i];
      ushort4 o;
      o.x = f2bf(v.x); o.y = f2bf(v.y); o.z = f2bf(v.z); o.w = f2bf(v.w);
      ((ushort4*)d)[i] = o;
    }
  }
}

// ---- one MLP layer over a 32-row LDS tile ----
// out[rows,M'] = act(in[32,K] @ W^T + bias). 8 waves; wave = 16 cols/pass.
// ISTR/OSTR = LDS row strides in bytes. MODE: 0 LDS; 1 LDS+global bf16;
// 2 global hi/lo only. Writes guarded by `rows`.
template <int KST, int NPASS, int ACT, int ISTR, int OSTR, int MODE>
__device__ __forceinline__ void mlp_tile(
    const u16* ldsIn, u16* ldsOut, const u16* __restrict__ Wg,
    const float* __restrict__ bias, u16* __restrict__ gOut,
    u16* __restrict__ gOut2, int gM, int K, int rows, int lane, int wave) {
  short8 af[2][KST];
#pragma unroll
  for (int m = 0; m < 2; ++m)
#pragma unroll
    for (int kk = 0; kk < KST; ++kk) {
      int r = m * 16 + (lane & 15);
      int sl = kk * 4 + (lane >> 4);
      af[m][kk] =
          *(const short8*)((const char*)ldsIn + r * ISTR + ((sl ^ (r & 7)) * 16));
    }
#pragma unroll
  for (int p = 0; p < NPASS; ++p) {
    const int col = p * 128 + wave * 16 + (lane & 15);
    short8 bfr[KST];
#pragma unroll
    for (int kk = 0; kk < KST; ++kk)
      bfr[kk] = *(const short8*)&Wg[(size_t)col * K + kk * 32 + (lane >> 4) * 8];
    f32x4 acc0 = {0.f, 0.f, 0.f, 0.f}, acc1 = {0.f, 0.f, 0.f, 0.f};
#pragma unroll
    for (int kk = 0; kk < KST; ++kk) {
      acc0 = __builtin_amdgcn_mfma_f32_16x16x32_bf16(af[0][kk], bfr[kk], acc0, 0, 0, 0);
      acc1 = __builtin_amdgcn_mfma_f32_16x16x32_bf16(af[1][kk], bfr[kk], acc1, 0, 0, 0);
    }
    const float b = bias[col];
    const int rb = (lane >> 4) * 4;
#pragma unroll
    for (int m = 0; m < 2; ++m) {
      f32x4 a = m ? acc1 : acc0;
#pragma unroll
      for (int r = 0; r < 4; ++r) {
        const int row = m * 16 + rb + r;
        if (row < rows) {
          float v = a[r] + b;
          if (ACT) v = (v >= 0.f) ? v : 0.01f * v;
          if constexpr (MODE == 2) {
            u16 hi = f2bf(v);
            gOut[(size_t)row * gM + col] = hi;
            gOut2[(size_t)row * gM + col] = f2bf(v - bf2f(hi));
          } else {
            u16 hv = f2bf(v);
            *(u16*)((char*)ldsOut + row * OSTR + (((col >> 3) ^ (row & 7)) * 16) +
                    (col & 7) * 2) = hv;
            if constexpr (MODE == 1) gOut[(size_t)row * gM + col] = hv;
          }
        }
      }
    }
  }
}

// ---- fusedA: H -> phi1 -> phi2 (Hf out) -> att (hi/lo out); 32 rows/block ----
__global__ __launch_bounds__(512, 2) void fusedA(
    const float* __restrict__ H, const u16* __restrict__ w1,
    const float* __restrict__ b1, const u16* __restrict__ w2,
    const float* __restrict__ b2, const u16* __restrict__ w3,
    const float* __restrict__ b3, u16* __restrict__ Hf,
    u16* __restrict__ ahi, u16* __restrict__ alo) {
  __shared__ __align__(16) u16 bufX[32 * 256];
  __shared__ __align__(16) u16 bufY[32 * 256];
  const int tid = threadIdx.x, wave = tid >> 6, lane = tid & 63;
  const size_t row0 = (size_t)blockIdx.x * 32;
  {
    int r = tid >> 4, part = tid & 15;
    const float4* src = (const float4*)&H[(row0 + r) * D + part * 16];
#pragma unroll
    for (int i = 0; i < 2; ++i) {
      int4 v = pack8(src[2 * i], src[2 * i + 1]);
      int sl = part * 2 + i;
      *(int4*)((char*)bufX + r * 512 + ((sl ^ (r & 7)) * 16)) = v;
    }
  }
  __syncthreads();
  mlp_tile<8, 2, 1, 512, 512, 0>(bufX, bufY, w1, b1, nullptr, nullptr, 0, D, 32,
                                 lane, wave);
  __syncthreads();
  mlp_tile<8, 2, 1, 512, 512, 1>(bufY, bufX, w2, b2, Hf + row0 * D, nullptr, D, D,
                                 32, lane, wave);
  __syncthreads();
  mlp_tile<8, 2, 0, 512, 512, 2>(bufX, nullptr, w3, b3, ahi + row0 * D,
                                 alo + row0 * D, D, D, 32, lane, wave);
}

// ---- seg_tail: per segment, attention + rho MLP + gate MLP + pool ----
__global__ __launch_bounds__(512) void seg_tail(
    const u16* __restrict__ ahi, const u16* __restrict__ alo,
    const u16* __restrict__ Hf, const u16* __restrict__ rw1,
    const float* __restrict__ rb1, const u16* __restrict__ rw2,
    const float* __restrict__ rb2, const u16* __restrict__ gw1,
    const float* __restrict__ gb1, const u16* __restrict__ gw2,
    const float* __restrict__ gb2, const float* __restrict__ gw3,
    const float* __restrict__ gb3, const int* __restrict__ sstart,
    const int* __restrict__ scount, float* __restrict__ hpool,
    float* __restrict__ scores, u16* __restrict__ Hmg, u16* __restrict__ Hm2g,
    float* __restrict__ hgg) {
  __shared__ __align__(16) u16 bufX[MAXC * 256];  // 48KB: Hm, then Hm2
  __shared__ __align__(16) u16 bufY[MAXC * 256];  // 48KB: P / rho-hidden / g1,g2
  __shared__ float hgs[MAXC];
  __shared__ float red[512];
  __shared__ float part[512];
  const int s = blockIdx.x, t = threadIdx.x;
  const int cnt = scount[s];
  const int r0 = sstart[s];
  const int wave = t >> 6, lane = t & 63;

  if (cnt == 0) {
    if (t < 256) hpool[(size_t)s * D + t] = 0.0f;
    return;
  }

  if (cnt <= MAXC) {
    float* P = (float*)bufY;  // [MAXC][PST], 96*97*4 = 37248 <= 49152
    // ---- QK^T (hi/lo split MFMA) ----
    const int cp = (cnt + 15) & ~15;
    const int nt = cp >> 4;
    const int ntiles = nt * nt;
    const int lrow = lane & 15, koff = (lane >> 4) * 8;
    for (int tt = wave; tt < ntiles; tt += 8) {
      int ti = tt / nt, tj = tt - ti * nt;
      int ra = r0 + ti * 16 + lrow;
      if (ra > N_NODES - 1) ra = N_NODES - 1;
      int rb2_ = r0 + tj * 16 + lrow;
      if (rb2_ > N_NODES - 1) rb2_ = N_NODES - 1;
      const u16* abp = ahi + (size_t)ra * D + koff;
      const u16* alp = alo + (size_t)ra * D + koff;
      const u16* bbp = ahi + (size_t)rb2_ * D + koff;
      const u16* blp = alo + (size_t)rb2_ * D + koff;
      f32x4 acc = {0.f, 0.f, 0.f, 0.f};
#pragma unroll
      for (int k0 = 0; k0 < D; k0 += 32) {
        short8 ah = *(const short8*)(abp + k0);
        short8 av = *(const short8*)(alp + k0);
        short8 bh = *(const short8*)(bbp + k0);
        short8 bv = *(const short8*)(blp + k0);
        acc = __builtin_amdgcn_mfma_f32_16x16x32_bf16(ah, bh, acc, 0, 0, 0);
        acc = __builtin_amdgcn_mfma_f32_16x16x32_bf16(ah, bv, acc, 0, 0, 0);
        acc = __builtin_amdgcn_mfma_f32_16x16x32_bf16(av, bh, acc, 0, 0, 0);
      }
      int i0 = ti * 16 + (lane >> 4) * 4;
      int j = tj * 16 + lrow;
#pragma unroll
      for (int r = 0; r < 4; ++r) P[(i0 + r) * PST + j] = acc[r];
    }
    __syncthreads();
    // ---- row softmax (wave per row) ----
    for (int i = wave; i < cnt; i += 8) {
      float* row = P + i * PST;
      float m = -INFINITY;
      for (int j = lane; j < cnt; j += 64) m = fmaxf(m, row[j]);
#pragma unroll
      for (int o = 32; o > 0; o >>= 1) m = fmaxf(m, __shfl_xor(m, o));
      float sum = 0.f;
      for (int j = lane; j < cnt; j += 64) sum += __expf(row[j] - m);
#pragma unroll
      for (int o = 32; o > 0; o >>= 1) sum += __shfl_xor(sum, o);
      float inv = 1.f / sum;
      for (int j = lane; j < cnt; j += 64) row[j] = __expf(row[j] - m) * inv;
    }
    __syncthreads();
    // ---- PV -> bufX (swizzled bf16) ----
    for (int i = wave; i < cnt; i += 8) {
      const float* Pi = P + i * PST;
      float a0 = 0.f, a1 = 0.f, a2 = 0.f, a3 = 0.f;
      int j = 0;
      for (; j + 1 < cnt; j += 2) {
        float w0 = Pi[j], w1 = Pi[j + 1];
        uint2 h0 = *(const uint2*)&Hf[(size_t)(r0 + j) * D + lane * 4];
        uint2 h1 = *(const uint2*)&Hf[(size_t)(r0 + j + 1) * D + lane * 4];
        a0 += w0 * __uint_as_float(h0.x << 16) + w1 * __uint_as_float(h1.x << 16);
        a1 += w0 * __uint_as_float(h0.x & 0xffff0000u) + w1 * __uint_as_float(h1.x & 0xffff0000u);
        a2 += w0 * __uint_as_float(h0.y << 16) + w1 * __uint_as_float(h1.y << 16);
        a3 += w0 * __uint_as_float(h0.y & 0xffff0000u) + w1 * __uint_as_float(h1.y & 0xffff0000u);
      }
      if (j < cnt) {
        float w0 = Pi[j];
        uint2 h0 = *(const uint2*)&Hf[(size_t)(r0 + j) * D + lane * 4];
        a0 += w0 * __uint_as_float(h0.x << 16);
        a1 += w0 * __uint_as_float(h0.x & 0xffff0000u);
        a2 += w0 * __uint_as_float(h0.y << 16);
        a3 += w0 * __uint_as_float(h0.y & 0xffff0000u);
      }
      ushort4 o;
      o.x = f2bf(a0); o.y = f2bf(a1); o.z = f2bf(a2); o.w = f2bf(a3);
      const int c0 = lane * 4;
      *(ushort4*)((char*)bufX + i * 512 + (((c0 >> 3) ^ (i & 7)) * 16) +
                  (c0 & 7) * 2) = o;
    }
    __syncthreads();
    // ---- rho1 / rho2 / g1 / g2 on 32-row tiles (all LDS) ----
    const int nrt = (cnt + 31) >> 5;
    u16* g1buf = bufY;                                   // stride 256B
    u16* g2buf = (u16*)((char*)bufY + MAXC * 256);       // stride 256B
    for (int rt = 0; rt < nrt; ++rt) {
      int rows = cnt - rt * 32; rows = rows > 32 ? 32 : rows;
      mlp_tile<8, 2, 1, 512, 512, 0>(bufX + rt * 32 * 256, bufY + rt * 32 * 256,
                                     rw1, rb1, nullptr, nullptr, 0, D, rows, lane, wave);
    }
    __syncthreads();
    for (int rt = 0; rt < nrt; ++rt) {
      int rows = cnt - rt * 32; rows = rows > 32 ? 32 : rows;
      mlp_tile<8, 2, 1, 512, 512, 0>(bufY + rt * 32 * 256, bufX + rt * 32 * 256,
                                     rw2, rb2, nullptr, nullptr, 0, D, rows, lane, wave);
    }
    __syncthreads();
    for (int rt = 0; rt < nrt; ++rt) {
      int rows = cnt - rt * 32; rows = rows > 32 ? 32 : rows;
      mlp_tile<8, 1, 1, 512, 256, 0>(bufX + rt * 32 * 256, g1buf + rt * 32 * 128,
                                     gw1, gb1, nullptr, nullptr, 0, D, rows, lane, wave);
    }
    __syncthreads();
    for (int rt = 0; rt < nrt; ++rt) {
      int rows = cnt - rt * 32; rows = rows > 32 ? 32 : rows;
      mlp_tile<4, 1, 1, 256, 256, 0>(g1buf + rt * 32 * 128, g2buf + rt * 32 * 128,
                                     gw2, gb2, nullptr, nullptr, 0, HID, rows, lane, wave);
    }
    __syncthreads();
    // ---- gate3 -> hgs ----
    {
      const int part16 = t & 15;
      for (int i = t >> 4; i < cnt; i += 32) {
        short8 hv = *(const short8*)((const char*)g2buf + i * 256 +
                                     ((part16 ^ (i & 7)) * 16));
        float sacc = 0.f;
#pragma unroll
        for (int q = 0; q < 8; ++q)
          sacc += bf2f((u16)hv[q]) * gw3[part16 * 8 + q];
        sacc += __shfl_xor(sacc, 1);
        sacc += __shfl_xor(sacc, 2);
        sacc += __shfl_xor(sacc, 4);
        sacc += __shfl_xor(sacc, 8);
        if (part16 == 0) hgs[i] = sacc + gb3[0];
      }
    }
    __syncthreads();
    // ---- segment softmax + pool ----
    float pm = (t < cnt) ? hgs[t] : -INFINITY;
    red[t] = pm;
    __syncthreads();
    for (int o = 256; o > 0; o >>= 1) {
      if (t < o) red[t] = fmaxf(red[t], red[t + o]);
      __syncthreads();
    }
    float m = red[0];
    __syncthreads();
    red[t] = (t < cnt) ? __expf(hgs[t] - m) : 0.f;
    __syncthreads();
    for (int o = 256; o > 0; o >>= 1) {
      if (t < o) red[t] += red[t + o];
      __syncthreads();
    }
    float inv = 1.f / red[0];
    if (t < cnt) scores[r0 + t] = __expf(hgs[t] - m) * inv;
    const int h = t >> 8, d = t & 255;
    float acc = 0.f;
    for (int i = h; i < cnt; i += 2) {
      float wgt = __expf(hgs[i] - m) * inv;
      acc += wgt * bf2f(*(const u16*)((const char*)bufX + i * 512 +
                                      (((d >> 3) ^ (i & 7)) * 16) + (d & 7) * 2));
    }
    part[t] = acc;
    __syncthreads();
    if (t < 256) hpool[(size_t)s * D + t] = part[t] + part[t + 256];
  } else {
    // ================= rare fallback: any cnt =================
    float* Pf = (float*)bufY;  // 12288 floats >= cnt (<= 8192)
    for (int i = 0; i < cnt; ++i) {
      int ri = r0 + i;
      const u16* ai = ahi + (size_t)ri * D;
      const u16* li = alo + (size_t)ri * D;
      for (int j = t; j < cnt; j += 512) {
        const u16* aj = ahi + (size_t)(r0 + j) * D;
        const u16* lj = alo + (size_t)(r0 + j) * D;
        float acc = 0.f;
        for (int k = 0; k < D; ++k)
          acc += (bf2f(ai[k]) + bf2f(li[k])) * (bf2f(aj[k]) + bf2f(lj[k]));
        Pf[j] = acc;
      }
      __syncthreads();
      float pm = -INFINITY;
      for (int j = t; j < cnt; j += 512) pm = fmaxf(pm, Pf[j]);
      red[t] = pm;
      __syncthreads();
      for (int o = 256; o > 0; o >>= 1) {
        if (t < o) red[t] = fmaxf(red[t], red[t + o]);
        __syncthreads();
      }
      float m = red[0];
      __syncthreads();
      float ps = 0.f;
      for (int j = t; j < cnt; j += 512) {
        float e = __expf(Pf[j] - m);
        Pf[j] = e;
        ps += e;
      }
      red[t] = ps;
      __syncthreads();
      for (int o = 256; o > 0; o >>= 1) {
        if (t < o) red[t] += red[t + o];
        __syncthreads();
      }
      float inv = 1.f / red[0];
      if (t < D) {
        float acc = 0.f;
        for (int j = 0; j < cnt; ++j)
          acc += Pf[j] * bf2f(Hf[(size_t)(r0 + j) * D + t]);
        Hmg[(size_t)ri * D + t] = f2bf(acc * inv);
      }
      __syncthreads();
    }
    // MLP tail in 32-row tiles via global scratch
    u16* g1buf = bufY;
    u16* g2buf = (u16*)((char*)bufY + 32 * 256);
    const int nrt = (cnt + 31) >> 5;
    for (int rt = 0; rt < nrt; ++rt) {
      int rows = cnt - rt * 32; rows = rows > 32 ? 32 : rows;
      {
        int r = t >> 4, part16 = t & 15;
        if (r < rows) {
          const int4* src =
              (const int4*)&Hmg[(size_t)(r0 + rt * 32 + r) * D + part16 * 16];
#pragma unroll
          for (int i = 0; i < 2; ++i) {
            int sl = part16 * 2 + i;
            *(int4*)((char*)bufX + r * 512 + ((sl ^ (r & 7)) * 16)) = src[i];
          }
        }
      }
      __syncthreads();
      mlp_tile<8, 2, 1, 512, 512, 0>(bufX, bufX + 32 * 256, rw1, rb1, nullptr,
                                     nullptr, 0, D, rows, lane, wave);
      __syncthreads();
      mlp_tile<8, 2, 1, 512, 512, 1>(bufX + 32 * 256, bufX, rw2, rb2,
                                     Hm2g + (size_t)(r0 + rt * 32) * D, nullptr,
                                     D, D, rows, lane, wave);
      __syncthreads();
      mlp_tile<8, 1, 1, 512, 256, 0>(bufX, g1buf, gw1, gb1, nullptr, nullptr, 0,
                                     D, rows, lane, wave);
      __syncthreads();
      mlp_tile<4, 1, 1, 256, 256, 0>(g1buf, g2buf, gw2, gb2, nullptr, nullptr, 0,
                                     HID, rows, lane, wave);
      __syncthreads();
      {
        const int part16 = t & 15;
        for (int i = t >> 4; i < rows; i += 32) {
          short8 hv = *(const short8*)((const char*)g2buf + i * 256 +
                                       ((part16 ^ (i & 7)) * 16));
          float sacc = 0.f;
#pragma unroll
          for (int q = 0; q < 8; ++q)
            sacc += bf2f((u16)hv[q]) * gw3[part16 * 8 + q];
          sacc += __shfl_xor(sacc, 1);
          sacc += __shfl_xor(sacc, 2);
          sacc += __shfl_xor(sacc, 4);
          sacc += __shfl_xor(sacc, 8);
          if (part16 == 0) hgg[r0 + rt * 32 + i] = sacc + gb3[0];
        }
      }
      __syncthreads();
    }
    // segment softmax + pool from global scratch
    float pm = -INFINITY;
    for (int i = t; i < cnt; i += 512) pm = fmaxf(pm, hgg[r0 + i]);
    red[t] = pm;
    __syncthreads();
    for (int o = 256; o > 0; o >>= 1) {
      if (t < o) red[t] = fmaxf(red[t], red[t + o]);
      __syncthreads();
    }
    float m = red[0];
    __syncthreads();
    float ps = 0.f;
    for (int i = t; i < cnt; i += 512) ps += __expf(hgg[r0 + i] - m);
    red[t] = ps;
    __syncthreads();
    for (int o = 256; o > 0; o >>= 1) {
      if (t < o) red[t] += red[t + o];
      __syncthreads();
    }
    float inv = 1.f / red[0];
    for (int i = t; i < cnt; i += 512)
      scores[r0 + i] = __expf(hgg[r0 + i] - m) * inv;
    const int h = t >> 8, d = t & 255;
    float acc = 0.f;
    for (int i = h; i < cnt; i += 2)
      acc += __expf(hgg[r0 + i] - m) * inv * bf2f(Hm2g[(size_t)(r0 + i) * D + d]);
    part[t] = acc;
    __syncthreads();
    if (t < 256) hpool[(size_t)s * D + t] = part[t] + part[t + 256];
  }
}

// ---------------------------------------------------------------------
extern "C" void kernel_launch(void* const* d_in, const int* in_sizes, int n_in,
                              void* d_out, int out_size, void* d_ws, size_t ws_size,
                              hipStream_t stream) {
  const float* H      = (const float*)d_in[0];
  const int*   batch  = (const int*)d_in[1];
  const float* phi_w1 = (const float*)d_in[2];
  const float* phi_b1 = (const float*)d_in[3];
  const float* phi_w2 = (const float*)d_in[4];
  const float* phi_b2 = (const float*)d_in[5];
  const float* att_w  = (const float*)d_in[6];
  const float* att_b  = (const float*)d_in[7];
  const float* rho_w1 = (const float*)d_in[8];
  const float* rho_b1 = (const float*)d_in[9];
  const float* rho_w2 = (const float*)d_in[10];
  const float* rho_b2 = (const float*)d_in[11];
  const float* g_w1   = (const float*)d_in[12];
  const float* g_b1   = (const float*)d_in[13];
  const float* g_w2   = (const float*)d_in[14];
  const float* g_b2   = (const float*)d_in[15];
  const float* g_w3   = (const float*)d_in[16];
  const float* g_b3   = (const float*)d_in[17];

  float* out_hpool  = (float*)d_out;
  float* out_scores = (float*)d_out + (size_t)S_SEG * D;

  char* w = (char*)d_ws;
  const size_t MB = 1u << 20;
  u16*   wb     = (u16*)(w);              // weights bf16 (<1MB)
  u16*   Hfb    = (u16*)(w + 1 * MB);     // 4MB
  u16*   att_hi = (u16*)(w + 5 * MB);     // 4MB
  u16*   att_lo = (u16*)(w + 9 * MB);     // 4MB
  u16*   Hmg    = (u16*)(w + 13 * MB);    // fallback scratch
  u16*   Hm2g   = (u16*)(w + 17 * MB);    // fallback scratch
  float* hgg    = (float*)(w + 21 * MB);  // fallback scratch
  int*   sstart = (int*)(w + 21 * MB + 64 * 1024);
  int*   scount = sstart + S_SEG;

  u16* phi_w1b = wb;
  u16* phi_w2b = wb + 65536;
  u16* att_wb  = wb + 2 * 65536;
  u16* rho_w1b = wb + 3 * 65536;
  u16* rho_w2b = wb + 4 * 65536;
  u16* g_w1b   = wb + 5 * 65536;
  u16* g_w2b   = wb + 5 * 65536 + 32768;

  CvtJobs jb;
  jb.src[0] = phi_w1; jb.dst[0] = phi_w1b; jb.n4[0] = 65536 / 4;
  jb.src[1] = phi_w2; jb.dst[1] = phi_w2b; jb.n4[1] = 65536 / 4;
  jb.src[2] = att_w;  jb.dst[2] = att_wb;  jb.n4[2] = 65536 / 4;
  jb.src[3] = rho_w1; jb.dst[3] = rho_w1b; jb.n4[3] = 65536 / 4;
  jb.src[4] = rho_w2; jb.dst[4] = rho_w2b; jb.n4[4] = 65536 / 4;
  jb.src[5] = g_w1;   jb.dst[5] = g_w1b;   jb.n4[5] = 32768 / 4;
  jb.src[6] = g_w2;   jb.dst[6] = g_w2b;   jb.n4[6] = 16384 / 4;

  prep<<<57, 256, 0, stream>>>(batch, sstart, scount, jb);

  fusedA<<<N_NODES / 32, 512, 0, stream>>>(H, phi_w1b, phi_b1, phi_w2b, phi_b2,
                                           att_wb, att_b, Hfb, att_hi, att_lo);

  seg_tail<<<S_SEG, 512, 0, stream>>>(att_hi, att_lo, Hfb, rho_w1b, rho_b1,
                                      rho_w2b, rho_b2, g_w1b, g_b1, g_w2b, g_b2,
                                      g_w3, g_b3, sstart, scount, out_hpool,
                                      out_scores, Hmg, Hm2g, hgg);
}

// Round 6
// 74.103 us; speedup vs baseline: 4.9499x; 1.0827x over previous
//
#include <hip/hip_runtime.h>
#include <math.h>

#define N_NODES 8192
#define D 256
#define HID 128
#define S_SEG 256
#define MAXC 64
#define PST 65

typedef __attribute__((ext_vector_type(8))) short short8;
typedef __attribute__((ext_vector_type(4))) float f32x4;
typedef unsigned short u16;
typedef unsigned int u32;

__device__ __forceinline__ u16 f2bf(float f) {
  u32 u = __float_as_uint(f);
  u32 r = (u + 0x7fffu + ((u >> 16) & 1u)) >> 16;
  return (u16)r;
}
__device__ __forceinline__ float bf2f(u16 b) {
  return __uint_as_float(((u32)b) << 16);
}
__device__ __forceinline__ int4 pack8(float4 x, float4 y) {
  int4 v;
  v.x = (int)(((u32)f2bf(x.y) << 16) | f2bf(x.x));
  v.y = (int)(((u32)f2bf(x.w) << 16) | f2bf(x.z));
  v.z = (int)(((u32)f2bf(y.y) << 16) | f2bf(y.x));
  v.w = (int)(((u32)f2bf(y.w) << 16) | f2bf(y.z));
  return v;
}

// ---------------- prep: block 0 = segment meta; blocks 1..56 = weight cvt ----
struct CvtJobs {
  const float* src[7];
  u16* dst[7];
  int n4[7];
};
__global__ __launch_bounds__(256) void prep(const int* __restrict__ batch,
                                            int* __restrict__ sstart,
                                            int* __restrict__ scount, CvtJobs jb) {
  if (blockIdx.x == 0) {
    __shared__ int cntS[S_SEG];
    __shared__ int startS[S_SEG];
    const int t = threadIdx.x;
    cntS[t] = 0;
    startS[t] = 0;
    __syncthreads();
    const int base = t * 32;
    int pb = (base == 0) ? -1 : batch[base - 1];
    for (int i = 0; i < 32; ++i) {
      int b = batch[base + i];
      atomicAdd(&cntS[b], 1);
      if (b != pb) startS[b] = base + i;
      pb = b;
    }
    __syncthreads();
    scount[t] = cntS[t];
    sstart[t] = startS[t];
  } else {
    const int bid = blockIdx.x - 1;
    const int job = bid >> 3, chunk = bid & 7;
    const float* s = jb.src[job];
    u16* d = jb.dst[job];
    const int n4 = jb.n4[job];
    for (int i = chunk * 256 + threadIdx.x; i < n4; i += 2048) {
      float4 v = ((const float4*)s)[i];
      ushort4 o;
      o.x = f2bf(v.x); o.y = f2bf(v.y); o.z = f2bf(v.z); o.w = f2bf(v.w);
      ((ushort4*)d)[i] = o;
    }
  }
}

// ---- one MLP layer over an LDS tile, 16 waves (1024 threads) ----
// out[rows,M] = act(in[rows,K] @ W^T + bias). Work = (row_tile, col_group)
// pairs round-robin over 16 waves. ISTR/OSTR LDS row strides (bytes).
// MODE: 0 LDS out; 1 LDS + global bf16; 2 global hi/lo; 3 LDS hi/lo.
template <int KST, int ACT, int ISTR, int OSTR, int MODE>
__device__ __forceinline__ void mlp16(
    const u16* ldsIn, u16* ldsOut, u16* ldsOut2, const u16* __restrict__ Wg,
    const float* __restrict__ bias, u16* __restrict__ gOut,
    u16* __restrict__ gOut2, int M, int K, int rows, int lane, int wave) {
  const int MG = M >> 4;
  const int npairs = ((rows + 31) >> 5) * MG;
  for (int p = wave; p < npairs; p += 16) {
    const int rt = p / MG, cg = p - rt * MG;
    short8 af[2][KST];
#pragma unroll
    for (int m = 0; m < 2; ++m)
#pragma unroll
      for (int kk = 0; kk < KST; ++kk) {
        const int r = rt * 32 + m * 16 + (lane & 15);
        const int sl = kk * 4 + (lane >> 4);
        af[m][kk] = *(const short8*)((const char*)ldsIn + r * ISTR +
                                     ((sl ^ (r & 7)) * 16));
      }
    const int col = cg * 16 + (lane & 15);
    short8 bfr[KST];
#pragma unroll
    for (int kk = 0; kk < KST; ++kk)
      bfr[kk] = *(const short8*)&Wg[(size_t)col * K + kk * 32 + (lane >> 4) * 8];
    f32x4 acc0 = {0.f, 0.f, 0.f, 0.f}, acc1 = {0.f, 0.f, 0.f, 0.f};
#pragma unroll
    for (int kk = 0; kk < KST; ++kk) {
      acc0 = __builtin_amdgcn_mfma_f32_16x16x32_bf16(af[0][kk], bfr[kk], acc0, 0, 0, 0);
      acc1 = __builtin_amdgcn_mfma_f32_16x16x32_bf16(af[1][kk], bfr[kk], acc1, 0, 0, 0);
    }
    const float b = bias[col];
    const int rb = (lane >> 4) * 4;
#pragma unroll
    for (int m = 0; m < 2; ++m) {
      f32x4 a = m ? acc1 : acc0;
#pragma unroll
      for (int r4 = 0; r4 < 4; ++r4) {
        const int row = rt * 32 + m * 16 + rb + r4;
        if (row < rows) {
          float v = a[r4] + b;
          if (ACT) v = (v >= 0.f) ? v : 0.01f * v;
          if constexpr (MODE == 2) {
            u16 hi = f2bf(v);
            gOut[(size_t)row * M + col] = hi;
            gOut2[(size_t)row * M + col] = f2bf(v - bf2f(hi));
          } else if constexpr (MODE == 3) {
            const int byo =
                row * OSTR + (((col >> 3) ^ (row & 7)) * 16) + (col & 7) * 2;
            u16 hi = f2bf(v);
            *(u16*)((char*)ldsOut + byo) = hi;
            *(u16*)((char*)ldsOut2 + byo) = f2bf(v - bf2f(hi));
          } else {
            u16 hv = f2bf(v);
            *(u16*)((char*)ldsOut + row * OSTR + (((col >> 3) ^ (row & 7)) * 16) +
                    (col & 7) * 2) = hv;
            if constexpr (MODE == 1) gOut[(size_t)row * M + col] = hv;
          }
        }
      }
    }
  }
}

// ---- seg_all: the whole network per segment in one block ----
__global__ __launch_bounds__(1024) void seg_all(
    const float* __restrict__ H, const u16* __restrict__ pw1,
    const float* __restrict__ pb1, const u16* __restrict__ pw2,
    const float* __restrict__ pb2, const u16* __restrict__ aw,
    const float* __restrict__ ab, const u16* __restrict__ rw1,
    const float* __restrict__ rb1, const u16* __restrict__ rw2,
    const float* __restrict__ rb2, const u16* __restrict__ gw1,
    const float* __restrict__ gb1, const u16* __restrict__ gw2,
    const float* __restrict__ gb2, const float* __restrict__ gw3,
    const float* __restrict__ gb3, const int* __restrict__ sstart,
    const int* __restrict__ scount, float* __restrict__ hpool,
    float* __restrict__ scores, u16* __restrict__ Hfg, u16* __restrict__ aHg,
    u16* __restrict__ aLg, u16* __restrict__ Hmg, u16* __restrict__ Hm2g,
    float* __restrict__ hgg) {
  __shared__ __align__(16) u16 bufX[MAXC * 256];  // 32KB
  __shared__ __align__(16) u16 bufY[MAXC * 256];  // 32KB (P aliases)
  __shared__ __align__(16) u16 attH[MAXC * 256];  // 32KB
  __shared__ __align__(16) u16 attL[MAXC * 256];  // 32KB
  __shared__ float hgs[MAXC];
  __shared__ float red[1024];
  __shared__ float part[1024];
  const int s = blockIdx.x, t = threadIdx.x;
  const int cnt = scount[s];
  const int r0 = sstart[s];
  const int wave = t >> 6, lane = t & 63;

  if (cnt == 0) {
    if (t < 256) hpool[(size_t)s * D + t] = 0.f;
    return;
  }

  if (cnt <= MAXC) {
    // ---- stage H (f32 -> bf16 swizzled) ----
    {
      const int r = t >> 4, p16 = t & 15;
      if (r < cnt) {
        const float4* src = (const float4*)&H[(size_t)(r0 + r) * D + p16 * 16];
#pragma unroll
        for (int i = 0; i < 2; ++i) {
          int4 v = pack8(src[2 * i], src[2 * i + 1]);
          const int sl = p16 * 2 + i;
          *(int4*)((char*)bufX + r * 512 + ((sl ^ (r & 7)) * 16)) = v;
        }
      }
    }
    __syncthreads();
    mlp16<8, 1, 512, 512, 0>(bufX, bufY, nullptr, pw1, pb1, nullptr, nullptr, D, D, cnt, lane, wave);
    __syncthreads();
    mlp16<8, 1, 512, 512, 0>(bufY, bufX, nullptr, pw2, pb2, nullptr, nullptr, D, D, cnt, lane, wave);
    __syncthreads();  // bufX = Hf
    mlp16<8, 0, 512, 512, 3>(bufX, attH, attL, aw, ab, nullptr, nullptr, D, D, cnt, lane, wave);
    __syncthreads();
    // ---- QK^T (hi/lo split MFMA, LDS operands) ----
    float* P = (float*)bufY;
    const int cp = (cnt + 15) & ~15;
    const int nt = cp >> 4;
    const int lrow = lane & 15;
    for (int tt = wave; tt < nt * nt; tt += 16) {
      const int ti = tt / nt, tj = tt - ti * nt;
      const int ra = ti * 16 + lrow, rb2 = tj * 16 + lrow;
      f32x4 acc = {0.f, 0.f, 0.f, 0.f};
#pragma unroll
      for (int k0 = 0; k0 < D; k0 += 32) {
        const int sg = (k0 >> 3) + (lane >> 4);
        short8 ah = *(const short8*)((const char*)attH + ra * 512 + ((sg ^ (ra & 7)) * 16));
        short8 av = *(const short8*)((const char*)attL + ra * 512 + ((sg ^ (ra & 7)) * 16));
        short8 bh = *(const short8*)((const char*)attH + rb2 * 512 + ((sg ^ (rb2 & 7)) * 16));
        short8 bv = *(const short8*)((const char*)attL + rb2 * 512 + ((sg ^ (rb2 & 7)) * 16));
        acc = __builtin_amdgcn_mfma_f32_16x16x32_bf16(ah, bh, acc, 0, 0, 0);
        acc = __builtin_amdgcn_mfma_f32_16x16x32_bf16(ah, bv, acc, 0, 0, 0);
        acc = __builtin_amdgcn_mfma_f32_16x16x32_bf16(av, bh, acc, 0, 0, 0);
      }
      const int i0 = ti * 16 + (lane >> 4) * 4, j = tj * 16 + lrow;
#pragma unroll
      for (int r = 0; r < 4; ++r) P[(i0 + r) * PST + j] = acc[r];
    }
    __syncthreads();
    // ---- row softmax: lane = j (cnt <= 64) ----
    for (int i = wave; i < cnt; i += 16) {
      float* row = P + i * PST;
      float v = (lane < cnt) ? row[lane] : -INFINITY;
      float m = v;
#pragma unroll
      for (int o = 32; o > 0; o >>= 1) m = fmaxf(m, __shfl_xor(m, o));
      float e = (lane < cnt) ? __expf(v - m) : 0.f;
      float sum = e;
#pragma unroll
      for (int o = 32; o > 0; o >>= 1) sum += __shfl_xor(sum, o);
      if (lane < cnt) row[lane] = e / sum;
    }
    __syncthreads();
    // ---- PV -> attH (Hm, swizzled); Hf read from bufX LDS ----
    for (int i = wave; i < cnt; i += 16) {
      const float* Pi = P + i * PST;
      float a0 = 0.f, a1 = 0.f, a2 = 0.f, a3 = 0.f;
      for (int j = 0; j < cnt; ++j) {
        const float wj = Pi[j];
        const ushort4 hv = *(const ushort4*)((const char*)bufX + j * 512 +
                             (((lane >> 1) ^ (j & 7)) * 16) + (lane & 1) * 8);
        a0 += wj * bf2f(hv.x);
        a1 += wj * bf2f(hv.y);
        a2 += wj * bf2f(hv.z);
        a3 += wj * bf2f(hv.w);
      }
      ushort4 o;
      o.x = f2bf(a0); o.y = f2bf(a1); o.z = f2bf(a2); o.w = f2bf(a3);
      *(ushort4*)((char*)attH + i * 512 + (((lane >> 1) ^ (i & 7)) * 16) +
                  (lane & 1) * 8) = o;
    }
    __syncthreads();
    mlp16<8, 1, 512, 512, 0>(attH, attL, nullptr, rw1, rb1, nullptr, nullptr, D, D, cnt, lane, wave);
    __syncthreads();
    mlp16<8, 1, 512, 512, 0>(attL, bufX, nullptr, rw2, rb2, nullptr, nullptr, D, D, cnt, lane, wave);
    __syncthreads();  // bufX = Hm2
    mlp16<8, 1, 512, 256, 0>(bufX, bufY, nullptr, gw1, gb1, nullptr, nullptr, HID, D, cnt, lane, wave);
    __syncthreads();
    mlp16<4, 1, 256, 256, 0>(bufY, attH, nullptr, gw2, gb2, nullptr, nullptr, HID, HID, cnt, lane, wave);
    __syncthreads();  // attH (stride 256) = g2
    // ---- gate3 -> hgs ----
    {
      const int i = t >> 4, p16 = t & 15;
      if (i < cnt) {
        short8 hv = *(const short8*)((const char*)attH + i * 256 + ((p16 ^ (i & 7)) * 16));
        float sacc = 0.f;
#pragma unroll
        for (int q = 0; q < 8; ++q) sacc += bf2f((u16)hv[q]) * gw3[p16 * 8 + q];
        sacc += __shfl_xor(sacc, 1);
        sacc += __shfl_xor(sacc, 2);
        sacc += __shfl_xor(sacc, 4);
        sacc += __shfl_xor(sacc, 8);
        if (p16 == 0) hgs[i] = sacc + gb3[0];
      }
    }
    __syncthreads();
    // ---- segment softmax (single wave; cnt <= 64) ----
    if (t < 64) {
      float v = (t < cnt) ? hgs[t] : -INFINITY;
      float m = v;
#pragma unroll
      for (int o = 32; o > 0; o >>= 1) m = fmaxf(m, __shfl_xor(m, o));
      float e = (t < cnt) ? __expf(v - m) : 0.f;
      float sum = e;
#pragma unroll
      for (int o = 32; o > 0; o >>= 1) sum += __shfl_xor(sum, o);
      if (t < cnt) {
        const float sc = e / sum;
        hgs[t] = sc;
        scores[r0 + t] = sc;
      }
    }
    __syncthreads();
    // ---- pool from bufX (Hm2) ----
    {
      const int h = t >> 8, d = t & 255;
      float acc = 0.f;
      for (int i = h; i < cnt; i += 4)
        acc += hgs[i] * bf2f(*(const u16*)((const char*)bufX + i * 512 +
                              (((d >> 3) ^ (i & 7)) * 16) + (d & 7) * 2));
      part[t] = acc;
    }
    __syncthreads();
    if (t < 256)
      hpool[(size_t)s * D + t] =
          part[t] + part[t + 256] + part[t + 512] + part[t + 768];
  } else {
    // ============ fallback (cnt > 64, practically never taken) ============
    // Phase 1: phi + att in 64-row chunks -> global scratch
    for (int c0 = 0; c0 < cnt; c0 += 64) {
      const int rows = (cnt - c0) > 64 ? 64 : (cnt - c0);
      {
        const int r = t >> 4, p16 = t & 15;
        if (r < rows) {
          const float4* src = (const float4*)&H[(size_t)(r0 + c0 + r) * D + p16 * 16];
#pragma unroll
          for (int i = 0; i < 2; ++i) {
            int4 v = pack8(src[2 * i], src[2 * i + 1]);
            const int sl = p16 * 2 + i;
            *(int4*)((char*)bufX + r * 512 + ((sl ^ (r & 7)) * 16)) = v;
          }
        }
      }
      __syncthreads();
      mlp16<8, 1, 512, 512, 0>(bufX, bufY, nullptr, pw1, pb1, nullptr, nullptr, D, D, rows, lane, wave);
      __syncthreads();
      mlp16<8, 1, 512, 512, 1>(bufY, bufX, nullptr, pw2, pb2, Hfg + (size_t)(r0 + c0) * D, nullptr, D, D, rows, lane, wave);
      __syncthreads();
      mlp16<8, 0, 512, 512, 2>(bufX, nullptr, nullptr, aw, ab, aHg + (size_t)(r0 + c0) * D, aLg + (size_t)(r0 + c0) * D, D, D, rows, lane, wave);
      __syncthreads();
    }
    // Phase 2: attention, row-serial
    float* Pf = (float*)bufY;  // 8192 floats >= cnt
    for (int i = 0; i < cnt; ++i) {
      const u16* ai = aHg + (size_t)(r0 + i) * D;
      const u16* li = aLg + (size_t)(r0 + i) * D;
      for (int j = t; j < cnt; j += 1024) {
        const u16* aj = aHg + (size_t)(r0 + j) * D;
        const u16* lj = aLg + (size_t)(r0 + j) * D;
        float acc = 0.f;
        for (int k = 0; k < D; ++k)
          acc += (bf2f(ai[k]) + bf2f(li[k])) * (bf2f(aj[k]) + bf2f(lj[k]));
        Pf[j] = acc;
      }
      __syncthreads();
      float pm = -INFINITY;
      for (int j = t; j < cnt; j += 1024) pm = fmaxf(pm, Pf[j]);
      red[t] = pm;
      __syncthreads();
      for (int o = 512; o > 0; o >>= 1) {
        if (t < o) red[t] = fmaxf(red[t], red[t + o]);
        __syncthreads();
      }
      const float m = red[0];
      __syncthreads();
      float ps = 0.f;
      for (int j = t; j < cnt; j += 1024) {
        const float e = __expf(Pf[j] - m);
        Pf[j] = e;
        ps += e;
      }
      red[t] = ps;
      __syncthreads();
      for (int o = 512; o > 0; o >>= 1) {
        if (t < o) red[t] += red[t + o];
        __syncthreads();
      }
      const float inv = 1.f / red[0];
      if (t < D) {
        float acc = 0.f;
        for (int j = 0; j < cnt; ++j)
          acc += Pf[j] * bf2f(Hfg[(size_t)(r0 + j) * D + t]);
        Hmg[(size_t)(r0 + i) * D + t] = f2bf(acc * inv);
      }
      __syncthreads();
    }
    // Phase 3: rho + gate in 64-row chunks
    for (int c0 = 0; c0 < cnt; c0 += 64) {
      const int rows = (cnt - c0) > 64 ? 64 : (cnt - c0);
      {
        const int r = t >> 4, p16 = t & 15;
        if (r < rows) {
          const int4* src = (const int4*)&Hmg[(size_t)(r0 + c0 + r) * D + p16 * 16];
#pragma unroll
          for (int i = 0; i < 2; ++i) {
            const int sl = p16 * 2 + i;
            *(int4*)((char*)bufX + r * 512 + ((sl ^ (r & 7)) * 16)) = src[i];
          }
        }
      }
      __syncthreads();
      mlp16<8, 1, 512, 512, 0>(bufX, bufY, nullptr, rw1, rb1, nullptr, nullptr, D, D, rows, lane, wave);
      __syncthreads();
      mlp16<8, 1, 512, 512, 1>(bufY, bufX, nullptr, rw2, rb2, Hm2g + (size_t)(r0 + c0) * D, nullptr, D, D, rows, lane, wave);
      __syncthreads();
      mlp16<8, 1, 512, 256, 0>(bufX, bufY, nullptr, gw1, gb1, nullptr, nullptr, HID, D, rows, lane, wave);
      __syncthreads();
      mlp16<4, 1, 256, 256, 0>(bufY, attH, nullptr, gw2, gb2, nullptr, nullptr, HID, HID, rows, lane, wave);
      __syncthreads();
      {
        const int i = t >> 4, p16 = t & 15;
        if (i < rows) {
          short8 hv = *(const short8*)((const char*)attH + i * 256 + ((p16 ^ (i & 7)) * 16));
          float sacc = 0.f;
#pragma unroll
          for (int q = 0; q < 8; ++q) sacc += bf2f((u16)hv[q]) * gw3[p16 * 8 + q];
          sacc += __shfl_xor(sacc, 1);
          sacc += __shfl_xor(sacc, 2);
          sacc += __shfl_xor(sacc, 4);
          sacc += __shfl_xor(sacc, 8);
          if (p16 == 0) hgg[r0 + c0 + i] = sacc + gb3[0];
        }
      }
      __syncthreads();
    }
    // Phase 4: segment softmax + pool from global
    float pm = -INFINITY;
    for (int i = t; i < cnt; i += 1024) pm = fmaxf(pm, hgg[r0 + i]);
    red[t] = pm;
    __syncthreads();
    for (int o = 512; o > 0; o >>= 1) {
      if (t < o) red[t] = fmaxf(red[t], red[t + o]);
      __syncthreads();
    }
    const float m = red[0];
    __syncthreads();
    float ps = 0.f;
    for (int i = t; i < cnt; i += 1024) ps += __expf(hgg[r0 + i] - m);
    red[t] = ps;
    __syncthreads();
    for (int o = 512; o > 0; o >>= 1) {
      if (t < o) red[t] += red[t + o];
      __syncthreads();
    }
    const float inv = 1.f / red[0];
    for (int i = t; i < cnt; i += 1024)
      scores[r0 + i] = __expf(hgg[r0 + i] - m) * inv;
    const int h = t >> 8, d = t & 255;
    float acc = 0.f;
    for (int i = h; i < cnt; i += 4)
      acc += __expf(hgg[r0 + i] - m) * inv * bf2f(Hm2g[(size_t)(r0 + i) * D + d]);
    part[t] = acc;
    __syncthreads();
    if (t < 256)
      hpool[(size_t)s * D + t] =
          part[t] + part[t + 256] + part[t + 512] + part[t + 768];
  }
}

// ---------------------------------------------------------------------
extern "C" void kernel_launch(void* const* d_in, const int* in_sizes, int n_in,
                              void* d_out, int out_size, void* d_ws, size_t ws_size,
                              hipStream_t stream) {
  const float* H      = (const float*)d_in[0];
  const int*   batch  = (const int*)d_in[1];
  const float* phi_w1 = (const float*)d_in[2];
  const float* phi_b1 = (const float*)d_in[3];
  const float* phi_w2 = (const float*)d_in[4];
  const float* phi_b2 = (const float*)d_in[5];
  const float* att_w  = (const float*)d_in[6];
  const float* att_b  = (const float*)d_in[7];
  const float* rho_w1 = (const float*)d_in[8];
  const float* rho_b1 = (const float*)d_in[9];
  const float* rho_w2 = (const float*)d_in[10];
  const float* rho_b2 = (const float*)d_in[11];
  const float* g_w1   = (const float*)d_in[12];
  const float* g_b1   = (const float*)d_in[13];
  const float* g_w2   = (const float*)d_in[14];
  const float* g_b2   = (const float*)d_in[15];
  const float* g_w3   = (const float*)d_in[16];
  const float* g_b3   = (const float*)d_in[17];

  float* out_hpool  = (float*)d_out;
  float* out_scores = (float*)d_out + (size_t)S_SEG * D;

  char* w = (char*)d_ws;
  const size_t MB = 1u << 20;
  u16*   wb     = (u16*)(w);              // weights bf16 (<1MB)
  u16*   Hfg    = (u16*)(w + 1 * MB);     // fallback scratch 4MB
  u16*   aHg    = (u16*)(w + 5 * MB);     // 4MB
  u16*   aLg    = (u16*)(w + 9 * MB);     // 4MB
  u16*   Hmg    = (u16*)(w + 13 * MB);    // 4MB
  u16*   Hm2g   = (u16*)(w + 17 * MB);    // 4MB
  float* hgg    = (float*)(w + 21 * MB);  // 32KB
  int*   sstart = (int*)(w + 21 * MB + 64 * 1024);
  int*   scount = sstart + S_SEG;

  u16* phi_w1b = wb;
  u16* phi_w2b = wb + 65536;
  u16* att_wb  = wb + 2 * 65536;
  u16* rho_w1b = wb + 3 * 65536;
  u16* rho_w2b = wb + 4 * 65536;
  u16* g_w1b   = wb + 5 * 65536;
  u16* g_w2b   = wb + 5 * 65536 + 32768;

  CvtJobs jb;
  jb.src[0] = phi_w1; jb.dst[0] = phi_w1b; jb.n4[0] = 65536 / 4;
  jb.src[1] = phi_w2; jb.dst[1] = phi_w2b; jb.n4[1] = 65536 / 4;
  jb.src[2] = att_w;  jb.dst[2] = att_wb;  jb.n4[2] = 65536 / 4;
  jb.src[3] = rho_w1; jb.dst[3] = rho_w1b; jb.n4[3] = 65536 / 4;
  jb.src[4] = rho_w2; jb.dst[4] = rho_w2b; jb.n4[4] = 65536 / 4;
  jb.src[5] = g_w1;   jb.dst[5] = g_w1b;   jb.n4[5] = 32768 / 4;
  jb.src[6] = g_w2;   jb.dst[6] = g_w2b;   jb.n4[6] = 16384 / 4;

  prep<<<57, 256, 0, stream>>>(batch, sstart, scount, jb);

  seg_all<<<S_SEG, 1024, 0, stream>>>(
      H, phi_w1b, phi_b1, phi_w2b, phi_b2, att_wb, att_b, rho_w1b, rho_b1,
      rho_w2b, rho_b2, g_w1b, g_b1, g_w2b, g_b2, g_w3, g_b3, sstart, scount,
      out_hpool, out_scores, Hfg, aHg, aLg, Hmg, Hm2g, hgg);
}

// Round 7
// 74.014 us; speedup vs baseline: 4.9558x; 1.0012x over previous
//
#include <hip/hip_runtime.h>
#include <math.h>

#define N_NODES 8192
#define D 256
#define HID 128
#define S_SEG 256
#define MAXC 64
#define PST 65

typedef __attribute__((ext_vector_type(8))) short short8;
typedef __attribute__((ext_vector_type(4))) float f32x4;
typedef unsigned short u16;
typedef unsigned int u32;

__device__ __forceinline__ u16 f2bf(float f) {
  u32 u = __float_as_uint(f);
  u32 r = (u + 0x7fffu + ((u >> 16) & 1u)) >> 16;
  return (u16)r;
}
__device__ __forceinline__ float bf2f(u16 b) {
  return __uint_as_float(((u32)b) << 16);
}
__device__ __forceinline__ int4 pack8(float4 x, float4 y) {
  int4 v;
  v.x = (int)(((u32)f2bf(x.y) << 16) | f2bf(x.x));
  v.y = (int)(((u32)f2bf(x.w) << 16) | f2bf(x.z));
  v.z = (int)(((u32)f2bf(y.y) << 16) | f2bf(y.x));
  v.w = (int)(((u32)f2bf(y.w) << 16) | f2bf(y.z));
  return v;
}

// ---------------- prep: block 0 = segment meta; blocks 1..56 = weight cvt ----
struct CvtJobs {
  const float* src[7];
  u16* dst[7];
  int n4[7];
};
__global__ __launch_bounds__(256) void prep(const int* __restrict__ batch,
                                            int* __restrict__ sstart,
                                            int* __restrict__ scount, CvtJobs jb) {
  if (blockIdx.x == 0) {
    __shared__ int cntS[S_SEG];
    __shared__ int startS[S_SEG];
    const int t = threadIdx.x;
    cntS[t] = 0;
    startS[t] = 0;
    __syncthreads();
    const int base = t * 32;
    int pb = (base == 0) ? -1 : batch[base - 1];
    for (int i = 0; i < 32; ++i) {
      int b = batch[base + i];
      atomicAdd(&cntS[b], 1);
      if (b != pb) startS[b] = base + i;
      pb = b;
    }
    __syncthreads();
    scount[t] = cntS[t];
    sstart[t] = startS[t];
  } else {
    const int bid = blockIdx.x - 1;
    const int job = bid >> 3, chunk = bid & 7;
    const float* s = jb.src[job];
    u16* d = jb.dst[job];
    const int n4 = jb.n4[job];
    for (int i = chunk * 256 + threadIdx.x; i < n4; i += 2048) {
      float4 v = ((const float4*)s)[i];
      ushort4 o;
      o.x = f2bf(v.x); o.y = f2bf(v.y); o.z = f2bf(v.z); o.w = f2bf(v.w);
      ((ushort4*)d)[i] = o;
    }
  }
}

// ---- one MLP layer over an LDS tile, 16 waves (1024 threads) ----
// out[rows,M] = act(in[rows,K] @ W^T + bias). Work = (row_tile, col_group)
// pairs round-robin over 16 waves. ISTR/OSTR LDS row strides (bytes).
// MODE: 0 LDS out; 1 LDS + global bf16; 2 global hi/lo; 3 LDS hi/lo.
template <int KST, int ACT, int ISTR, int OSTR, int MODE>
__device__ __forceinline__ void mlp16(
    const u16* ldsIn, u16* ldsOut, u16* ldsOut2, const u16* __restrict__ Wg,
    const float* __restrict__ bias, u16* __restrict__ gOut,
    u16* __restrict__ gOut2, int M, int K, int rows, int lane, int wave) {
  const int MG = M >> 4;
  const int npairs = ((rows + 31) >> 5) * MG;
  for (int p = wave; p < npairs; p += 16) {
    const int rt = p / MG, cg = p - rt * MG;
    short8 af[2][KST];
#pragma unroll
    for (int m = 0; m < 2; ++m)
#pragma unroll
      for (int kk = 0; kk < KST; ++kk) {
        const int r = rt * 32 + m * 16 + (lane & 15);
        const int sl = kk * 4 + (lane >> 4);
        af[m][kk] = *(const short8*)((const char*)ldsIn + r * ISTR +
                                     ((sl ^ (r & 7)) * 16));
      }
    const int col = cg * 16 + (lane & 15);
    short8 bfr[KST];
#pragma unroll
    for (int kk = 0; kk < KST; ++kk)
      bfr[kk] = *(const short8*)&Wg[(size_t)col * K + kk * 32 + (lane >> 4) * 8];
    f32x4 acc0 = {0.f, 0.f, 0.f, 0.f}, acc1 = {0.f, 0.f, 0.f, 0.f};
#pragma unroll
    for (int kk = 0; kk < KST; ++kk) {
      acc0 = __builtin_amdgcn_mfma_f32_16x16x32_bf16(af[0][kk], bfr[kk], acc0, 0, 0, 0);
      acc1 = __builtin_amdgcn_mfma_f32_16x16x32_bf16(af[1][kk], bfr[kk], acc1, 0, 0, 0);
    }
    const float b = bias[col];
    const int rb = (lane >> 4) * 4;
#pragma unroll
    for (int m = 0; m < 2; ++m) {
      f32x4 a = m ? acc1 : acc0;
#pragma unroll
      for (int r4 = 0; r4 < 4; ++r4) {
        const int row = rt * 32 + m * 16 + rb + r4;
        if (row < rows) {
          float v = a[r4] + b;
          if (ACT) v = (v >= 0.f) ? v : 0.01f * v;
          if constexpr (MODE == 2) {
            u16 hi = f2bf(v);
            gOut[(size_t)row * M + col] = hi;
            gOut2[(size_t)row * M + col] = f2bf(v - bf2f(hi));
          } else if constexpr (MODE == 3) {
            const int byo =
                row * OSTR + (((col >> 3) ^ (row & 7)) * 16) + (col & 7) * 2;
            u16 hi = f2bf(v);
            *(u16*)((char*)ldsOut + byo) = hi;
            *(u16*)((char*)ldsOut2 + byo) = f2bf(v - bf2f(hi));
          } else {
            u16 hv = f2bf(v);
            *(u16*)((char*)ldsOut + row * OSTR + (((col >> 3) ^ (row & 7)) * 16) +
                    (col & 7) * 2) = hv;
            if constexpr (MODE == 1) gOut[(size_t)row * M + col] = hv;
          }
        }
      }
    }
  }
}

// ---- seg_all: the whole network per segment in one block ----
__global__ __launch_bounds__(1024) void seg_all(
    const float* __restrict__ H, const u16* __restrict__ pw1,
    const float* __restrict__ pb1, const u16* __restrict__ pw2,
    const float* __restrict__ pb2, const u16* __restrict__ aw,
    const float* __restrict__ ab, const u16* __restrict__ rw1,
    const float* __restrict__ rb1, const u16* __restrict__ rw2,
    const float* __restrict__ rb2, const u16* __restrict__ gw1,
    const float* __restrict__ gb1, const u16* __restrict__ gw2,
    const float* __restrict__ gb2, const float* __restrict__ gw3,
    const float* __restrict__ gb3, const int* __restrict__ sstart,
    const int* __restrict__ scount, float* __restrict__ hpool,
    float* __restrict__ scores, u16* __restrict__ Hfg, u16* __restrict__ aHg,
    u16* __restrict__ aLg, u16* __restrict__ Hmg, u16* __restrict__ Hm2g,
    float* __restrict__ hgg) {
  __shared__ __align__(16) u16 bufX[MAXC * 256];  // 32KB
  __shared__ __align__(16) u16 bufY[MAXC * 256];  // 32KB (P aliases)
  __shared__ __align__(16) u16 attH[MAXC * 256];  // 32KB
  __shared__ __align__(16) u16 attL[MAXC * 256];  // 32KB
  __shared__ float hgs[MAXC];
  __shared__ float red[1024];
  __shared__ float part[1024];
  const int s = blockIdx.x, t = threadIdx.x;
  const int cnt = scount[s];
  const int r0 = sstart[s];
  const int wave = t >> 6, lane = t & 63;

  if (cnt == 0) {
    if (t < 256) hpool[(size_t)s * D + t] = 0.f;
    return;
  }

  if (cnt <= MAXC) {
    // ---- stage H (f32 -> bf16 swizzled) ----
    {
      const int r = t >> 4, p16 = t & 15;
      if (r < cnt) {
        const float4* src = (const float4*)&H[(size_t)(r0 + r) * D + p16 * 16];
#pragma unroll
        for (int i = 0; i < 2; ++i) {
          int4 v = pack8(src[2 * i], src[2 * i + 1]);
          const int sl = p16 * 2 + i;
          *(int4*)((char*)bufX + r * 512 + ((sl ^ (r & 7)) * 16)) = v;
        }
      }
    }
    __syncthreads();
    mlp16<8, 1, 512, 512, 0>(bufX, bufY, nullptr, pw1, pb1, nullptr, nullptr, D, D, cnt, lane, wave);
    __syncthreads();
    mlp16<8, 1, 512, 512, 0>(bufY, bufX, nullptr, pw2, pb2, nullptr, nullptr, D, D, cnt, lane, wave);
    __syncthreads();  // bufX = Hf
    mlp16<8, 0, 512, 512, 3>(bufX, attH, attL, aw, ab, nullptr, nullptr, D, D, cnt, lane, wave);
    __syncthreads();
    // ---- QK^T (hi/lo split MFMA, LDS operands) ----
    float* P = (float*)bufY;
    const int cp = (cnt + 15) & ~15;
    const int nt = cp >> 4;
    const int lrow = lane & 15;
    for (int tt = wave; tt < nt * nt; tt += 16) {
      const int ti = tt / nt, tj = tt - ti * nt;
      const int ra = ti * 16 + lrow, rb2 = tj * 16 + lrow;
      f32x4 acc = {0.f, 0.f, 0.f, 0.f};
#pragma unroll
      for (int k0 = 0; k0 < D; k0 += 32) {
        const int sg = (k0 >> 3) + (lane >> 4);
        short8 ah = *(const short8*)((const char*)attH + ra * 512 + ((sg ^ (ra & 7)) * 16));
        short8 av = *(const short8*)((const char*)attL + ra * 512 + ((sg ^ (ra & 7)) * 16));
        short8 bh = *(const short8*)((const char*)attH + rb2 * 512 + ((sg ^ (rb2 & 7)) * 16));
        short8 bv = *(const short8*)((const char*)attL + rb2 * 512 + ((sg ^ (rb2 & 7)) * 16));
        acc = __builtin_amdgcn_mfma_f32_16x16x32_bf16(ah, bh, acc, 0, 0, 0);
        acc = __builtin_amdgcn_mfma_f32_16x16x32_bf16(ah, bv, acc, 0, 0, 0);
        acc = __builtin_amdgcn_mfma_f32_16x16x32_bf16(av, bh, acc, 0, 0, 0);
      }
      const int i0 = ti * 16 + (lane >> 4) * 4, j = tj * 16 + lrow;
#pragma unroll
      for (int r = 0; r < 4; ++r) P[(i0 + r) * PST + j] = acc[r];
    }
    __syncthreads();
    // ---- row softmax: lane = j (cnt <= 64) ----
    for (int i = wave; i < cnt; i += 16) {
      float* row = P + i * PST;
      float v = (lane < cnt) ? row[lane] : -INFINITY;
      float m = v;
#pragma unroll
      for (int o = 32; o > 0; o >>= 1) m = fmaxf(m, __shfl_xor(m, o));
      float e = (lane < cnt) ? __expf(v - m) : 0.f;
      float sum = e;
#pragma unroll
      for (int o = 32; o > 0; o >>= 1) sum += __shfl_xor(sum, o);
      if (lane < cnt) row[lane] = e / sum;
    }
    __syncthreads();
    // ---- PV -> attH (Hm, swizzled); Hf read from bufX LDS ----
    for (int i = wave; i < cnt; i += 16) {
      const float* Pi = P + i * PST;
      float a0 = 0.f, a1 = 0.f, a2 = 0.f, a3 = 0.f;
      for (int j = 0; j < cnt; ++j) {
        const float wj = Pi[j];
        const ushort4 hv = *(const ushort4*)((const char*)bufX + j * 512 +
                             (((lane >> 1) ^ (j & 7)) * 16) + (lane & 1) * 8);
        a0 += wj * bf2f(hv.x);
        a1 += wj * bf2f(hv.y);
        a2 += wj * bf2f(hv.z);
        a3 += wj * bf2f(hv.w);
      }
      ushort4 o;
      o.x = f2bf(a0); o.y = f2bf(a1); o.z = f2bf(a2); o.w = f2bf(a3);
      *(ushort4*)((char*)attH + i * 512 + (((lane >> 1) ^ (i & 7)) * 16) +
                  (lane & 1) * 8) = o;
    }
    __syncthreads();
    mlp16<8, 1, 512, 512, 0>(attH, attL, nullptr, rw1, rb1, nullptr, nullptr, D, D, cnt, lane, wave);
    __syncthreads();
    mlp16<8, 1, 512, 512, 0>(attL, bufX, nullptr, rw2, rb2, nullptr, nullptr, D, D, cnt, lane, wave);
    __syncthreads();  // bufX = Hm2
    mlp16<8, 1, 512, 256, 0>(bufX, bufY, nullptr, gw1, gb1, nullptr, nullptr, HID, D, cnt, lane, wave);
    __syncthreads();
    mlp16<4, 1, 256, 256, 0>(bufY, attH, nullptr, gw2, gb2, nullptr, nullptr, HID, HID, cnt, lane, wave);
    __syncthreads();  // attH (stride 256) = g2
    // ---- gate3 -> hgs ----
    {
      const int i = t >> 4, p16 = t & 15;
      if (i < cnt) {
        short8 hv = *(const short8*)((const char*)attH + i * 256 + ((p16 ^ (i & 7)) * 16));
        float sacc = 0.f;
#pragma unroll
        for (int q = 0; q < 8; ++q) sacc += bf2f((u16)hv[q]) * gw3[p16 * 8 + q];
        sacc += __shfl_xor(sacc, 1);
        sacc += __shfl_xor(sacc, 2);
        sacc += __shfl_xor(sacc, 4);
        sacc += __shfl_xor(sacc, 8);
        if (p16 == 0) hgs[i] = sacc + gb3[0];
      }
    }
    __syncthreads();
    // ---- segment softmax (single wave; cnt <= 64) ----
    if (t < 64) {
      float v = (t < cnt) ? hgs[t] : -INFINITY;
      float m = v;
#pragma unroll
      for (int o = 32; o > 0; o >>= 1) m = fmaxf(m, __shfl_xor(m, o));
      float e = (t < cnt) ? __expf(v - m) : 0.f;
      float sum = e;
#pragma unroll
      for (int o = 32; o > 0; o >>= 1) sum += __shfl_xor(sum, o);
      if (t < cnt) {
        const float sc = e / sum;
        hgs[t] = sc;
        scores[r0 + t] = sc;
      }
    }
    __syncthreads();
    // ---- pool from bufX (Hm2) ----
    {
      const int h = t >> 8, d = t & 255;
      float acc = 0.f;
      for (int i = h; i < cnt; i += 4)
        acc += hgs[i] * bf2f(*(const u16*)((const char*)bufX + i * 512 +
                              (((d >> 3) ^ (i & 7)) * 16) + (d & 7) * 2));
      part[t] = acc;
    }
    __syncthreads();
    if (t < 256)
      hpool[(size_t)s * D + t] =
          part[t] + part[t + 256] + part[t + 512] + part[t + 768];
  } else {
    // ============ fallback (cnt > 64, practically never taken) ============
    // Phase 1: phi + att in 64-row chunks -> global scratch
    for (int c0 = 0; c0 < cnt; c0 += 64) {
      const int rows = (cnt - c0) > 64 ? 64 : (cnt - c0);
      {
        const int r = t >> 4, p16 = t & 15;
        if (r < rows) {
          const float4* src = (const float4*)&H[(size_t)(r0 + c0 + r) * D + p16 * 16];
#pragma unroll
          for (int i = 0; i < 2; ++i) {
            int4 v = pack8(src[2 * i], src[2 * i + 1]);
            const int sl = p16 * 2 + i;
            *(int4*)((char*)bufX + r * 512 + ((sl ^ (r & 7)) * 16)) = v;
          }
        }
      }
      __syncthreads();
      mlp16<8, 1, 512, 512, 0>(bufX, bufY, nullptr, pw1, pb1, nullptr, nullptr, D, D, rows, lane, wave);
      __syncthreads();
      mlp16<8, 1, 512, 512, 1>(bufY, bufX, nullptr, pw2, pb2, Hfg + (size_t)(r0 + c0) * D, nullptr, D, D, rows, lane, wave);
      __syncthreads();
      mlp16<8, 0, 512, 512, 2>(bufX, nullptr, nullptr, aw, ab, aHg + (size_t)(r0 + c0) * D, aLg + (size_t)(r0 + c0) * D, D, D, rows, lane, wave);
      __syncthreads();
    }
    // Phase 2: attention, row-serial
    float* Pf = (float*)bufY;  // 8192 floats >= cnt
    for (int i = 0; i < cnt; ++i) {
      const u16* ai = aHg + (size_t)(r0 + i) * D;
      const u16* li = aLg + (size_t)(r0 + i) * D;
      for (int j = t; j < cnt; j += 1024) {
        const u16* aj = aHg + (size_t)(r0 + j) * D;
        const u16* lj = aLg + (size_t)(r0 + j) * D;
        float acc = 0.f;
        for (int k = 0; k < D; ++k)
          acc += (bf2f(ai[k]) + bf2f(li[k])) * (bf2f(aj[k]) + bf2f(lj[k]));
        Pf[j] = acc;
      }
      __syncthreads();
      float pm = -INFINITY;
      for (int j = t; j < cnt; j += 1024) pm = fmaxf(pm, Pf[j]);
      red[t] = pm;
      __syncthreads();
      for (int o = 512; o > 0; o >>= 1) {
        if (t < o) red[t] = fmaxf(red[t], red[t + o]);
        __syncthreads();
      }
      const float m = red[0];
      __syncthreads();
      float ps = 0.f;
      for (int j = t; j < cnt; j += 1024) {
        const float e = __expf(Pf[j] - m);
        Pf[j] = e;
        ps += e;
      }
      red[t] = ps;
      __syncthreads();
      for (int o = 512; o > 0; o >>= 1) {
        if (t < o) red[t] += red[t + o];
        __syncthreads();
      }
      const float inv = 1.f / red[0];
      if (t < D) {
        float acc = 0.f;
        for (int j = 0; j < cnt; ++j)
          acc += Pf[j] * bf2f(Hfg[(size_t)(r0 + j) * D + t]);
        Hmg[(size_t)(r0 + i) * D + t] = f2bf(acc * inv);
      }
      __syncthreads();
    }
    // Phase 3: rho + gate in 64-row chunks
    for (int c0 = 0; c0 < cnt; c0 += 64) {
      const int rows = (cnt - c0) > 64 ? 64 : (cnt - c0);
      {
        const int r = t >> 4, p16 = t & 15;
        if (r < rows) {
          const int4* src = (const int4*)&Hmg[(size_t)(r0 + c0 + r) * D + p16 * 16];
#pragma unroll
          for (int i = 0; i < 2; ++i) {
            const int sl = p16 * 2 + i;
            *(int4*)((char*)bufX + r * 512 + ((sl ^ (r & 7)) * 16)) = src[i];
          }
        }
      }
      __syncthreads();
      mlp16<8, 1, 512, 512, 0>(bufX, bufY, nullptr, rw1, rb1, nullptr, nullptr, D, D, rows, lane, wave);
      __syncthreads();
      mlp16<8, 1, 512, 512, 1>(bufY, bufX, nullptr, rw2, rb2, Hm2g + (size_t)(r0 + c0) * D, nullptr, D, D, rows, lane, wave);
      __syncthreads();
      mlp16<8, 1, 512, 256, 0>(bufX, bufY, nullptr, gw1, gb1, nullptr, nullptr, HID, D, rows, lane, wave);
      __syncthreads();
      mlp16<4, 1, 256, 256, 0>(bufY, attH, nullptr, gw2, gb2, nullptr, nullptr, HID, HID, rows, lane, wave);
      __syncthreads();
      {
        const int i = t >> 4, p16 = t & 15;
        if (i < rows) {
          short8 hv = *(const short8*)((const char*)attH + i * 256 + ((p16 ^ (i & 7)) * 16));
          float sacc = 0.f;
#pragma unroll
          for (int q = 0; q < 8; ++q) sacc += bf2f((u16)hv[q]) * gw3[p16 * 8 + q];
          sacc += __shfl_xor(sacc, 1);
          sacc += __shfl_xor(sacc, 2);
          sacc += __shfl_xor(sacc, 4);
          sacc += __shfl_xor(sacc, 8);
          if (p16 == 0) hgg[r0 + c0 + i] = sacc + gb3[0];
        }
      }
      __syncthreads();
    }
    // Phase 4: segment softmax + pool from global
    float pm = -INFINITY;
    for (int i = t; i < cnt; i += 1024) pm = fmaxf(pm, hgg[r0 + i]);
    red[t] = pm;
    __syncthreads();
    for (int o = 512; o > 0; o >>= 1) {
      if (t < o) red[t] = fmaxf(red[t], red[t + o]);
      __syncthreads();
    }
    const float m = red[0];
    __syncthreads();
    float ps = 0.f;
    for (int i = t; i < cnt; i += 1024) ps += __expf(hgg[r0 + i] - m);
    red[t] = ps;
    __syncthreads();
    for (int o = 512; o > 0; o >>= 1) {
      if (t < o) red[t] += red[t + o];
      __syncthreads();
    }
    const float inv = 1.f / red[0];
    for (int i = t; i < cnt; i += 1024)
      scores[r0 + i] = __expf(hgg[r0 + i] - m) * inv;
    const int h = t >> 8, d = t & 255;
    float acc = 0.f;
    for (int i = h; i < cnt; i += 4)
      acc += __expf(hgg[r0 + i] - m) * inv * bf2f(Hm2g[(size_t)(r0 + i) * D + d]);
    part[t] = acc;
    __syncthreads();
    if (t < 256)
      hpool[(size_t)s * D + t] =
          part[t] + part[t + 256] + part[t + 512] + part[t + 768];
  }
}

// ---------------------------------------------------------------------
extern "C" void kernel_launch(void* const* d_in, const int* in_sizes, int n_in,
                              void* d_out, int out_size, void* d_ws, size_t ws_size,
                              hipStream_t stream) {
  const float* H      = (const float*)d_in[0];
  const int*   batch  = (const int*)d_in[1];
  const float* phi_w1 = (const float*)d_in[2];
  const float* phi_b1 = (const float*)d_in[3];
  const float* phi_w2 = (const float*)d_in[4];
  const float* phi_b2 = (const float*)d_in[5];
  const float* att_w  = (const float*)d_in[6];
  const float* att_b  = (const float*)d_in[7];
  const float* rho_w1 = (const float*)d_in[8];
  const float* rho_b1 = (const float*)d_in[9];
  const float* rho_w2 = (const float*)d_in[10];
  const float* rho_b2 = (const float*)d_in[11];
  const float* g_w1   = (const float*)d_in[12];
  const float* g_b1   = (const float*)d_in[13];
  const float* g_w2   = (const float*)d_in[14];
  const float* g_b2   = (const float*)d_in[15];
  const float* g_w3   = (const float*)d_in[16];
  const float* g_b3   = (const float*)d_in[17];

  float* out_hpool  = (float*)d_out;
  float* out_scores = (float*)d_out + (size_t)S_SEG * D;

  char* w = (char*)d_ws;
  const size_t MB = 1u << 20;
  u16*   wb     = (u16*)(w);              // weights bf16 (<1MB)
  u16*   Hfg    = (u16*)(w + 1 * MB);     // fallback scratch 4MB
  u16*   aHg    = (u16*)(w + 5 * MB);     // 4MB
  u16*   aLg    = (u16*)(w + 9 * MB);     // 4MB
  u16*   Hmg    = (u16*)(w + 13 * MB);    // 4MB
  u16*   Hm2g   = (u16*)(w + 17 * MB);    // 4MB
  float* hgg    = (float*)(w + 21 * MB);  // 32KB
  int*   sstart = (int*)(w + 21 * MB + 64 * 1024);
  int*   scount = sstart + S_SEG;

  u16* phi_w1b = wb;
  u16* phi_w2b = wb + 65536;
  u16* att_wb  = wb + 2 * 65536;
  u16* rho_w1b = wb + 3 * 65536;
  u16* rho_w2b = wb + 4 * 65536;
  u16* g_w1b   = wb + 5 * 65536;
  u16* g_w2b   = wb + 5 * 65536 + 32768;

  CvtJobs jb;
  jb.src[0] = phi_w1; jb.dst[0] = phi_w1b; jb.n4[0] = 65536 / 4;
  jb.src[1] = phi_w2; jb.dst[1] = phi_w2b; jb.n4[1] = 65536 / 4;
  jb.src[2] = att_w;  jb.dst[2] = att_wb;  jb.n4[2] = 65536 / 4;
  jb.src[3] = rho_w1; jb.dst[3] = rho_w1b; jb.n4[3] = 65536 / 4;
  jb.src[4] = rho_w2; jb.dst[4] = rho_w2b; jb.n4[4] = 65536 / 4;
  jb.src[5] = g_w1;   jb.dst[5] = g_w1b;   jb.n4[5] = 32768 / 4;
  jb.src[6] = g_w2;   jb.dst[6] = g_w2b;   jb.n4[6] = 16384 / 4;

  prep<<<57, 256, 0, stream>>>(batch, sstart, scount, jb);

  seg_all<<<S_SEG, 1024, 0, stream>>>(
      H, phi_w1b, phi_b1, phi_w2b, phi_b2, att_wb, att_b, rho_w1b, rho_b1,
      rho_w2b, rho_b2, g_w1b, g_b1, g_w2b, g_b2, g_w3, g_b3, sstart, scount,
      out_hpool, out_scores, Hfg, aHg, aLg, Hmg, Hm2g, hgg);
}

// Round 8
// 73.892 us; speedup vs baseline: 4.9640x; 1.0017x over previous
//
#include <hip/hip_runtime.h>
#include <math.h>

#define N_NODES 8192
#define D 256
#define HID 128
#define S_SEG 256
#define MAXC 64
#define PST 65

typedef __attribute__((ext_vector_type(8))) short short8;
typedef __attribute__((ext_vector_type(4))) float f32x4;
typedef unsigned short u16;
typedef unsigned int u32;

__device__ __forceinline__ u16 f2bf(float f) {
  u32 u = __float_as_uint(f);
  u32 r = (u + 0x7fffu + ((u >> 16) & 1u)) >> 16;
  return (u16)r;
}
__device__ __forceinline__ float bf2f(u16 b) {
  return __uint_as_float(((u32)b) << 16);
}
__device__ __forceinline__ int4 pack8(float4 x, float4 y) {
  int4 v;
  v.x = (int)(((u32)f2bf(x.y) << 16) | f2bf(x.x));
  v.y = (int)(((u32)f2bf(x.w) << 16) | f2bf(x.z));
  v.z = (int)(((u32)f2bf(y.y) << 16) | f2bf(y.x));
  v.w = (int)(((u32)f2bf(y.w) << 16) | f2bf(y.z));
  return v;
}

// ---------------- prep: block 0 = segment meta; blocks 1..56 = weight cvt ----
struct CvtJobs {
  const float* src[7];
  u16* dst[7];
  int n4[7];
};
__global__ __launch_bounds__(256) void prep(const int* __restrict__ batch,
                                            int* __restrict__ sstart,
                                            int* __restrict__ scount, CvtJobs jb) {
  if (blockIdx.x == 0) {
    __shared__ int cntS[S_SEG];
    __shared__ int startS[S_SEG];
    const int t = threadIdx.x;
    cntS[t] = 0;
    startS[t] = 0;
    __syncthreads();
    const int base = t * 32;
    int pb = (base == 0) ? -1 : batch[base - 1];
    for (int i = 0; i < 32; ++i) {
      int b = batch[base + i];
      atomicAdd(&cntS[b], 1);
      if (b != pb) startS[b] = base + i;
      pb = b;
    }
    __syncthreads();
    scount[t] = cntS[t];
    sstart[t] = startS[t];
  } else {
    const int bid = blockIdx.x - 1;
    const int job = bid >> 3, chunk = bid & 7;
    const float* s = jb.src[job];
    u16* d = jb.dst[job];
    const int n4 = jb.n4[job];
    for (int i = chunk * 256 + threadIdx.x; i < n4; i += 2048) {
      float4 v = ((const float4*)s)[i];
      ushort4 o;
      o.x = f2bf(v.x); o.y = f2bf(v.y); o.z = f2bf(v.z); o.w = f2bf(v.w);
      ((ushort4*)d)[i] = o;
    }
  }
}

// ---- one MLP layer over an LDS tile, 16 waves (1024 threads) ----
// out[rows,M] = act(in[rows,K] @ W^T + bias). Work = (row_tile, col_group)
// pairs round-robin over 16 waves. ISTR/OSTR LDS row strides (bytes).
// MODE: 0 LDS out; 1 LDS + global bf16; 2 global hi/lo; 3 LDS hi/lo.
template <int KST, int ACT, int ISTR, int OSTR, int MODE>
__device__ __forceinline__ void mlp16(
    const u16* ldsIn, u16* ldsOut, u16* ldsOut2, const u16* __restrict__ Wg,
    const float* __restrict__ bias, u16* __restrict__ gOut,
    u16* __restrict__ gOut2, int M, int K, int rows, int lane, int wave) {
  const int MG = M >> 4;
  const int npairs = ((rows + 31) >> 5) * MG;
  for (int p = wave; p < npairs; p += 16) {
    const int rt = p / MG, cg = p - rt * MG;
    short8 af[2][KST];
#pragma unroll
    for (int m = 0; m < 2; ++m)
#pragma unroll
      for (int kk = 0; kk < KST; ++kk) {
        const int r = rt * 32 + m * 16 + (lane & 15);
        const int sl = kk * 4 + (lane >> 4);
        af[m][kk] = *(const short8*)((const char*)ldsIn + r * ISTR +
                                     ((sl ^ (r & 7)) * 16));
      }
    const int col = cg * 16 + (lane & 15);
    short8 bfr[KST];
#pragma unroll
    for (int kk = 0; kk < KST; ++kk)
      bfr[kk] = *(const short8*)&Wg[(size_t)col * K + kk * 32 + (lane >> 4) * 8];
    f32x4 acc0 = {0.f, 0.f, 0.f, 0.f}, acc1 = {0.f, 0.f, 0.f, 0.f};
#pragma unroll
    for (int kk = 0; kk < KST; ++kk) {
      acc0 = __builtin_amdgcn_mfma_f32_16x16x32_bf16(af[0][kk], bfr[kk], acc0, 0, 0, 0);
      acc1 = __builtin_amdgcn_mfma_f32_16x16x32_bf16(af[1][kk], bfr[kk], acc1, 0, 0, 0);
    }
    const float b = bias[col];
    const int rb = (lane >> 4) * 4;
#pragma unroll
    for (int m = 0; m < 2; ++m) {
      f32x4 a = m ? acc1 : acc0;
#pragma unroll
      for (int r4 = 0; r4 < 4; ++r4) {
        const int row = rt * 32 + m * 16 + rb + r4;
        if (row < rows) {
          float v = a[r4] + b;
          if (ACT) v = (v >= 0.f) ? v : 0.01f * v;
          if constexpr (MODE == 2) {
            u16 hi = f2bf(v);
            gOut[(size_t)row * M + col] = hi;
            gOut2[(size_t)row * M + col] = f2bf(v - bf2f(hi));
          } else if constexpr (MODE == 3) {
            const int byo =
                row * OSTR + (((col >> 3) ^ (row & 7)) * 16) + (col & 7) * 2;
            u16 hi = f2bf(v);
            *(u16*)((char*)ldsOut + byo) = hi;
            *(u16*)((char*)ldsOut2 + byo) = f2bf(v - bf2f(hi));
          } else {
            u16 hv = f2bf(v);
            *(u16*)((char*)ldsOut + row * OSTR + (((col >> 3) ^ (row & 7)) * 16) +
                    (col & 7) * 2) = hv;
            if constexpr (MODE == 1) gOut[(size_t)row * M + col] = hv;
          }
        }
      }
    }
  }
}

// ---- seg_all: the whole network per segment in one block ----
__global__ __launch_bounds__(1024) void seg_all(
    const float* __restrict__ H, const u16* __restrict__ pw1,
    const float* __restrict__ pb1, const u16* __restrict__ pw2,
    const float* __restrict__ pb2, const u16* __restrict__ aw,
    const float* __restrict__ ab, const u16* __restrict__ rw1,
    const float* __restrict__ rb1, const u16* __restrict__ rw2,
    const float* __restrict__ rb2, const u16* __restrict__ gw1,
    const float* __restrict__ gb1, const u16* __restrict__ gw2,
    const float* __restrict__ gb2, const float* __restrict__ gw3,
    const float* __restrict__ gb3, const int* __restrict__ sstart,
    const int* __restrict__ scount, float* __restrict__ hpool,
    float* __restrict__ scores, u16* __restrict__ Hfg, u16* __restrict__ aHg,
    u16* __restrict__ aLg, u16* __restrict__ Hmg, u16* __restrict__ Hm2g,
    float* __restrict__ hgg) {
  __shared__ __align__(16) u16 bufX[MAXC * 256];  // 32KB
  __shared__ __align__(16) u16 bufY[MAXC * 256];  // 32KB (P aliases)
  __shared__ __align__(16) u16 attH[MAXC * 256];  // 32KB
  __shared__ __align__(16) u16 attL[MAXC * 256];  // 32KB
  __shared__ float hgs[MAXC];
  __shared__ float red[1024];
  __shared__ float part[1024];
  const int s = blockIdx.x, t = threadIdx.x;
  const int cnt = scount[s];
  const int r0 = sstart[s];
  const int wave = t >> 6, lane = t & 63;

  if (cnt == 0) {
    if (t < 256) hpool[(size_t)s * D + t] = 0.f;
    return;
  }

  if (cnt <= MAXC) {
    // ---- stage H (f32 -> bf16 swizzled) ----
    {
      const int r = t >> 4, p16 = t & 15;
      if (r < cnt) {
        const float4* src = (const float4*)&H[(size_t)(r0 + r) * D + p16 * 16];
#pragma unroll
        for (int i = 0; i < 2; ++i) {
          int4 v = pack8(src[2 * i], src[2 * i + 1]);
          const int sl = p16 * 2 + i;
          *(int4*)((char*)bufX + r * 512 + ((sl ^ (r & 7)) * 16)) = v;
        }
      }
    }
    __syncthreads();
    mlp16<8, 1, 512, 512, 0>(bufX, bufY, nullptr, pw1, pb1, nullptr, nullptr, D, D, cnt, lane, wave);
    __syncthreads();
    mlp16<8, 1, 512, 512, 0>(bufY, bufX, nullptr, pw2, pb2, nullptr, nullptr, D, D, cnt, lane, wave);
    __syncthreads();  // bufX = Hf
    mlp16<8, 0, 512, 512, 3>(bufX, attH, attL, aw, ab, nullptr, nullptr, D, D, cnt, lane, wave);
    __syncthreads();
    // ---- QK^T (hi/lo split MFMA, LDS operands) ----
    float* P = (float*)bufY;
    const int cp = (cnt + 15) & ~15;
    const int nt = cp >> 4;
    const int lrow = lane & 15;
    for (int tt = wave; tt < nt * nt; tt += 16) {
      const int ti = tt / nt, tj = tt - ti * nt;
      const int ra = ti * 16 + lrow, rb2 = tj * 16 + lrow;
      f32x4 acc = {0.f, 0.f, 0.f, 0.f};
#pragma unroll
      for (int k0 = 0; k0 < D; k0 += 32) {
        const int sg = (k0 >> 3) + (lane >> 4);
        short8 ah = *(const short8*)((const char*)attH + ra * 512 + ((sg ^ (ra & 7)) * 16));
        short8 av = *(const short8*)((const char*)attL + ra * 512 + ((sg ^ (ra & 7)) * 16));
        short8 bh = *(const short8*)((const char*)attH + rb2 * 512 + ((sg ^ (rb2 & 7)) * 16));
        short8 bv = *(const short8*)((const char*)attL + rb2 * 512 + ((sg ^ (rb2 & 7)) * 16));
        acc = __builtin_amdgcn_mfma_f32_16x16x32_bf16(ah, bh, acc, 0, 0, 0);
        acc = __builtin_amdgcn_mfma_f32_16x16x32_bf16(ah, bv, acc, 0, 0, 0);
        acc = __builtin_amdgcn_mfma_f32_16x16x32_bf16(av, bh, acc, 0, 0, 0);
      }
      const int i0 = ti * 16 + (lane >> 4) * 4, j = tj * 16 + lrow;
#pragma unroll
      for (int r = 0; r < 4; ++r) P[(i0 + r) * PST + j] = acc[r];
    }
    __syncthreads();
    // ---- row softmax: lane = j (cnt <= 64) ----
    for (int i = wave; i < cnt; i += 16) {
      float* row = P + i * PST;
      float v = (lane < cnt) ? row[lane] : -INFINITY;
      float m = v;
#pragma unroll
      for (int o = 32; o > 0; o >>= 1) m = fmaxf(m, __shfl_xor(m, o));
      float e = (lane < cnt) ? __expf(v - m) : 0.f;
      float sum = e;
#pragma unroll
      for (int o = 32; o > 0; o >>= 1) sum += __shfl_xor(sum, o);
      if (lane < cnt) row[lane] = e / sum;
    }
    __syncthreads();
    // ---- PV -> attH (Hm, swizzled); Hf read from bufX LDS ----
    for (int i = wave; i < cnt; i += 16) {
      const float* Pi = P + i * PST;
      float a0 = 0.f, a1 = 0.f, a2 = 0.f, a3 = 0.f;
      for (int j = 0; j < cnt; ++j) {
        const float wj = Pi[j];
        const ushort4 hv = *(const ushort4*)((const char*)bufX + j * 512 +
                             (((lane >> 1) ^ (j & 7)) * 16) + (lane & 1) * 8);
        a0 += wj * bf2f(hv.x);
        a1 += wj * bf2f(hv.y);
        a2 += wj * bf2f(hv.z);
        a3 += wj * bf2f(hv.w);
      }
      ushort4 o;
      o.x = f2bf(a0); o.y = f2bf(a1); o.z = f2bf(a2); o.w = f2bf(a3);
      *(ushort4*)((char*)attH + i * 512 + (((lane >> 1) ^ (i & 7)) * 16) +
                  (lane & 1) * 8) = o;
    }
    __syncthreads();
    mlp16<8, 1, 512, 512, 0>(attH, attL, nullptr, rw1, rb1, nullptr, nullptr, D, D, cnt, lane, wave);
    __syncthreads();
    mlp16<8, 1, 512, 512, 0>(attL, bufX, nullptr, rw2, rb2, nullptr, nullptr, D, D, cnt, lane, wave);
    __syncthreads();  // bufX = Hm2
    mlp16<8, 1, 512, 256, 0>(bufX, bufY, nullptr, gw1, gb1, nullptr, nullptr, HID, D, cnt, lane, wave);
    __syncthreads();
    mlp16<4, 1, 256, 256, 0>(bufY, attH, nullptr, gw2, gb2, nullptr, nullptr, HID, HID, cnt, lane, wave);
    __syncthreads();  // attH (stride 256) = g2
    // ---- gate3 -> hgs ----
    {
      const int i = t >> 4, p16 = t & 15;
      if (i < cnt) {
        short8 hv = *(const short8*)((const char*)attH + i * 256 + ((p16 ^ (i & 7)) * 16));
        float sacc = 0.f;
#pragma unroll
        for (int q = 0; q < 8; ++q) sacc += bf2f((u16)hv[q]) * gw3[p16 * 8 + q];
        sacc += __shfl_xor(sacc, 1);
        sacc += __shfl_xor(sacc, 2);
        sacc += __shfl_xor(sacc, 4);
        sacc += __shfl_xor(sacc, 8);
        if (p16 == 0) hgs[i] = sacc + gb3[0];
      }
    }
    __syncthreads();
    // ---- segment softmax (single wave; cnt <= 64) ----
    if (t < 64) {
      float v = (t < cnt) ? hgs[t] : -INFINITY;
      float m = v;
#pragma unroll
      for (int o = 32; o > 0; o >>= 1) m = fmaxf(m, __shfl_xor(m, o));
      float e = (t < cnt) ? __expf(v - m) : 0.f;
      float sum = e;
#pragma unroll
      for (int o = 32; o > 0; o >>= 1) sum += __shfl_xor(sum, o);
      if (t < cnt) {
        const float sc = e / sum;
        hgs[t] = sc;
        scores[r0 + t] = sc;
      }
    }
    __syncthreads();
    // ---- pool from bufX (Hm2) ----
    {
      const int h = t >> 8, d = t & 255;
      float acc = 0.f;
      for (int i = h; i < cnt; i += 4)
        acc += hgs[i] * bf2f(*(const u16*)((const char*)bufX + i * 512 +
                              (((d >> 3) ^ (i & 7)) * 16) + (d & 7) * 2));
      part[t] = acc;
    }
    __syncthreads();
    if (t < 256)
      hpool[(size_t)s * D + t] =
          part[t] + part[t + 256] + part[t + 512] + part[t + 768];
  } else {
    // ============ fallback (cnt > 64, practically never taken) ============
    // Phase 1: phi + att in 64-row chunks -> global scratch
    for (int c0 = 0; c0 < cnt; c0 += 64) {
      const int rows = (cnt - c0) > 64 ? 64 : (cnt - c0);
      {
        const int r = t >> 4, p16 = t & 15;
        if (r < rows) {
          const float4* src = (const float4*)&H[(size_t)(r0 + c0 + r) * D + p16 * 16];
#pragma unroll
          for (int i = 0; i < 2; ++i) {
            int4 v = pack8(src[2 * i], src[2 * i + 1]);
            const int sl = p16 * 2 + i;
            *(int4*)((char*)bufX + r * 512 + ((sl ^ (r & 7)) * 16)) = v;
          }
        }
      }
      __syncthreads();
      mlp16<8, 1, 512, 512, 0>(bufX, bufY, nullptr, pw1, pb1, nullptr, nullptr, D, D, rows, lane, wave);
      __syncthreads();
      mlp16<8, 1, 512, 512, 1>(bufY, bufX, nullptr, pw2, pb2, Hfg + (size_t)(r0 + c0) * D, nullptr, D, D, rows, lane, wave);
      __syncthreads();
      mlp16<8, 0, 512, 512, 2>(bufX, nullptr, nullptr, aw, ab, aHg + (size_t)(r0 + c0) * D, aLg + (size_t)(r0 + c0) * D, D, D, rows, lane, wave);
      __syncthreads();
    }
    // Phase 2: attention, row-serial
    float* Pf = (float*)bufY;  // 8192 floats >= cnt
    for (int i = 0; i < cnt; ++i) {
      const u16* ai = aHg + (size_t)(r0 + i) * D;
      const u16* li = aLg + (size_t)(r0 + i) * D;
      for (int j = t; j < cnt; j += 1024) {
        const u16* aj = aHg + (size_t)(r0 + j) * D;
        const u16* lj = aLg + (size_t)(r0 + j) * D;
        float acc = 0.f;
        for (int k = 0; k < D; ++k)
          acc += (bf2f(ai[k]) + bf2f(li[k])) * (bf2f(aj[k]) + bf2f(lj[k]));
        Pf[j] = acc;
      }
      __syncthreads();
      float pm = -INFINITY;
      for (int j = t; j < cnt; j += 1024) pm = fmaxf(pm, Pf[j]);
      red[t] = pm;
      __syncthreads();
      for (int o = 512; o > 0; o >>= 1) {
        if (t < o) red[t] = fmaxf(red[t], red[t + o]);
        __syncthreads();
      }
      const float m = red[0];
      __syncthreads();
      float ps = 0.f;
      for (int j = t; j < cnt; j += 1024) {
        const float e = __expf(Pf[j] - m);
        Pf[j] = e;
        ps += e;
      }
      red[t] = ps;
      __syncthreads();
      for (int o = 512; o > 0; o >>= 1) {
        if (t < o) red[t] += red[t + o];
        __syncthreads();
      }
      const float inv = 1.f / red[0];
      if (t < D) {
        float acc = 0.f;
        for (int j = 0; j < cnt; ++j)
          acc += Pf[j] * bf2f(Hfg[(size_t)(r0 + j) * D + t]);
        Hmg[(size_t)(r0 + i) * D + t] = f2bf(acc * inv);
      }
      __syncthreads();
    }
    // Phase 3: rho + gate in 64-row chunks
    for (int c0 = 0; c0 < cnt; c0 += 64) {
      const int rows = (cnt - c0) > 64 ? 64 : (cnt - c0);
      {
        const int r = t >> 4, p16 = t & 15;
        if (r < rows) {
          const int4* src = (const int4*)&Hmg[(size_t)(r0 + c0 + r) * D + p16 * 16];
#pragma unroll
          for (int i = 0; i < 2; ++i) {
            const int sl = p16 * 2 + i;
            *(int4*)((char*)bufX + r * 512 + ((sl ^ (r & 7)) * 16)) = src[i];
          }
        }
      }
      __syncthreads();
      mlp16<8, 1, 512, 512, 0>(bufX, bufY, nullptr, rw1, rb1, nullptr, nullptr, D, D, rows, lane, wave);
      __syncthreads();
      mlp16<8, 1, 512, 512, 1>(bufY, bufX, nullptr, rw2, rb2, Hm2g + (size_t)(r0 + c0) * D, nullptr, D, D, rows, lane, wave);
      __syncthreads();
      mlp16<8, 1, 512, 256, 0>(bufX, bufY, nullptr, gw1, gb1, nullptr, nullptr, HID, D, rows, lane, wave);
      __syncthreads();
      mlp16<4, 1, 256, 256, 0>(bufY, attH, nullptr, gw2, gb2, nullptr, nullptr, HID, HID, rows, lane, wave);
      __syncthreads();
      {
        const int i = t >> 4, p16 = t & 15;
        if (i < rows) {
          short8 hv = *(const short8*)((const char*)attH + i * 256 + ((p16 ^ (i & 7)) * 16));
          float sacc = 0.f;
#pragma unroll
          for (int q = 0; q < 8; ++q) sacc += bf2f((u16)hv[q]) * gw3[p16 * 8 + q];
          sacc += __shfl_xor(sacc, 1);
          sacc += __shfl_xor(sacc, 2);
          sacc += __shfl_xor(sacc, 4);
          sacc += __shfl_xor(sacc, 8);
          if (p16 == 0) hgg[r0 + c0 + i] = sacc + gb3[0];
        }
      }
      __syncthreads();
    }
    // Phase 4: segment softmax + pool from global
    float pm = -INFINITY;
    for (int i = t; i < cnt; i += 1024) pm = fmaxf(pm, hgg[r0 + i]);
    red[t] = pm;
    __syncthreads();
    for (int o = 512; o > 0; o >>= 1) {
      if (t < o) red[t] = fmaxf(red[t], red[t + o]);
      __syncthreads();
    }
    const float m = red[0];
    __syncthreads();
    float ps = 0.f;
    for (int i = t; i < cnt; i += 1024) ps += __expf(hgg[r0 + i] - m);
    red[t] = ps;
    __syncthreads();
    for (int o = 512; o > 0; o >>= 1) {
      if (t < o) red[t] += red[t + o];
      __syncthreads();
    }
    const float inv = 1.f / red[0];
    for (int i = t; i < cnt; i += 1024)
      scores[r0 + i] = __expf(hgg[r0 + i] - m) * inv;
    const int h = t >> 8, d = t & 255;
    float acc = 0.f;
    for (int i = h; i < cnt; i += 4)
      acc += __expf(hgg[r0 + i] - m) * inv * bf2f(Hm2g[(size_t)(r0 + i) * D + d]);
    part[t] = acc;
    __syncthreads();
    if (t < 256)
      hpool[(size_t)s * D + t] =
          part[t] + part[t + 256] + part[t + 512] + part[t + 768];
  }
}

// ---------------------------------------------------------------------
extern "C" void kernel_launch(void* const* d_in, const int* in_sizes, int n_in,
                              void* d_out, int out_size, void* d_ws, size_t ws_size,
                              hipStream_t stream) {
  const float* H      = (const float*)d_in[0];
  const int*   batch  = (const int*)d_in[1];
  const float* phi_w1 = (const float*)d_in[2];
  const float* phi_b1 = (const float*)d_in[3];
  const float* phi_w2 = (const float*)d_in[4];
  const float* phi_b2 = (const float*)d_in[5];
  const float* att_w  = (const float*)d_in[6];
  const float* att_b  = (const float*)d_in[7];
  const float* rho_w1 = (const float*)d_in[8];
  const float* rho_b1 = (const float*)d_in[9];
  const float* rho_w2 = (const float*)d_in[10];
  const float* rho_b2 = (const float*)d_in[11];
  const float* g_w1   = (const float*)d_in[12];
  const float* g_b1   = (const float*)d_in[13];
  const float* g_w2   = (const float*)d_in[14];
  const float* g_b2   = (const float*)d_in[15];
  const float* g_w3   = (const float*)d_in[16];
  const float* g_b3   = (const float*)d_in[17];

  float* out_hpool  = (float*)d_out;
  float* out_scores = (float*)d_out + (size_t)S_SEG * D;

  char* w = (char*)d_ws;
  const size_t MB = 1u << 20;
  u16*   wb     = (u16*)(w);              // weights bf16 (<1MB)
  u16*   Hfg    = (u16*)(w + 1 * MB);     // fallback scratch 4MB
  u16*   aHg    = (u16*)(w + 5 * MB);     // 4MB
  u16*   aLg    = (u16*)(w + 9 * MB);     // 4MB
  u16*   Hmg    = (u16*)(w + 13 * MB);    // 4MB
  u16*   Hm2g   = (u16*)(w + 17 * MB);    // 4MB
  float* hgg    = (float*)(w + 21 * MB);  // 32KB
  int*   sstart = (int*)(w + 21 * MB + 64 * 1024);
  int*   scount = sstart + S_SEG;

  u16* phi_w1b = wb;
  u16* phi_w2b = wb + 65536;
  u16* att_wb  = wb + 2 * 65536;
  u16* rho_w1b = wb + 3 * 65536;
  u16* rho_w2b = wb + 4 * 65536;
  u16* g_w1b   = wb + 5 * 65536;
  u16* g_w2b   = wb + 5 * 65536 + 32768;

  CvtJobs jb;
  jb.src[0] = phi_w1; jb.dst[0] = phi_w1b; jb.n4[0] = 65536 / 4;
  jb.src[1] = phi_w2; jb.dst[1] = phi_w2b; jb.n4[1] = 65536 / 4;
  jb.src[2] = att_w;  jb.dst[2] = att_wb;  jb.n4[2] = 65536 / 4;
  jb.src[3] = rho_w1; jb.dst[3] = rho_w1b; jb.n4[3] = 65536 / 4;
  jb.src[4] = rho_w2; jb.dst[4] = rho_w2b; jb.n4[4] = 65536 / 4;
  jb.src[5] = g_w1;   jb.dst[5] = g_w1b;   jb.n4[5] = 32768 / 4;
  jb.src[6] = g_w2;   jb.dst[6] = g_w2b;   jb.n4[6] = 16384 / 4;

  prep<<<57, 256, 0, stream>>>(batch, sstart, scount, jb);

  seg_all<<<S_SEG, 1024, 0, stream>>>(
      H, phi_w1b, phi_b1, phi_w2b, phi_b2, att_wb, att_b, rho_w1b, rho_b1,
      rho_w2b, rho_b2, g_w1b, g_b1, g_w2b, g_b2, g_w3, g_b3, sstart, scount,
      out_hpool, out_scores, Hfg, aHg, aLg, Hmg, Hm2g, hgg);
}

// Round 9
// 73.829 us; speedup vs baseline: 4.9683x; 1.0009x over previous
//
#include <hip/hip_runtime.h>
#include <math.h>

#define N_NODES 8192
#define D 256
#define HID 128
#define S_SEG 256
#define MAXC 64
#define PST 65

typedef __attribute__((ext_vector_type(8))) short short8;
typedef __attribute__((ext_vector_type(4))) float f32x4;
typedef unsigned short u16;
typedef unsigned int u32;

__device__ __forceinline__ u16 f2bf(float f) {
  u32 u = __float_as_uint(f);
  u32 r = (u + 0x7fffu + ((u >> 16) & 1u)) >> 16;
  return (u16)r;
}
__device__ __forceinline__ float bf2f(u16 b) {
  return __uint_as_float(((u32)b) << 16);
}
__device__ __forceinline__ int4 pack8(float4 x, float4 y) {
  int4 v;
  v.x = (int)(((u32)f2bf(x.y) << 16) | f2bf(x.x));
  v.y = (int)(((u32)f2bf(x.w) << 16) | f2bf(x.z));
  v.z = (int)(((u32)f2bf(y.y) << 16) | f2bf(y.x));
  v.w = (int)(((u32)f2bf(y.w) << 16) | f2bf(y.z));
  return v;
}

// ---------------- prep: block 0 = segment meta; blocks 1..56 = weight cvt ----
struct CvtJobs {
  const float* src[7];
  u16* dst[7];
  int n4[7];
};
__global__ __launch_bounds__(256) void prep(const int* __restrict__ batch,
                                            int* __restrict__ sstart,
                                            int* __restrict__ scount, CvtJobs jb) {
  if (blockIdx.x == 0) {
    __shared__ int cntS[S_SEG];
    __shared__ int startS[S_SEG];
    const int t = threadIdx.x;
    cntS[t] = 0;
    startS[t] = 0;
    __syncthreads();
    const int base = t * 32;
    int pb = (base == 0) ? -1 : batch[base - 1];
    for (int i = 0; i < 32; ++i) {
      int b = batch[base + i];
      atomicAdd(&cntS[b], 1);
      if (b != pb) startS[b] = base + i;
      pb = b;
    }
    __syncthreads();
    scount[t] = cntS[t];
    sstart[t] = startS[t];
  } else {
    const int bid = blockIdx.x - 1;
    const int job = bid >> 3, chunk = bid & 7;
    const float* s = jb.src[job];
    u16* d = jb.dst[job];
    const int n4 = jb.n4[job];
    for (int i = chunk * 256 + threadIdx.x; i < n4; i += 2048) {
      float4 v = ((const float4*)s)[i];
      ushort4 o;
      o.x = f2bf(v.x); o.y = f2bf(v.y); o.z = f2bf(v.z); o.w = f2bf(v.w);
      ((ushort4*)d)[i] = o;
    }
  }
}

// ---- one MLP layer over an LDS tile, 16 waves (1024 threads) ----
// out[rows,M] = act(in[rows,K] @ W^T + bias). Work = (row_tile, col_group)
// pairs round-robin over 16 waves. ISTR/OSTR LDS row strides (bytes).
// MODE: 0 LDS out; 1 LDS + global bf16; 2 global hi/lo; 3 LDS hi/lo.
template <int KST, int ACT, int ISTR, int OSTR, int MODE>
__device__ __forceinline__ void mlp16(
    const u16* ldsIn, u16* ldsOut, u16* ldsOut2, const u16* __restrict__ Wg,
    const float* __restrict__ bias, u16* __restrict__ gOut,
    u16* __restrict__ gOut2, int M, int K, int rows, int lane, int wave) {
  const int MG = M >> 4;
  const int npairs = ((rows + 31) >> 5) * MG;
  for (int p = wave; p < npairs; p += 16) {
    const int rt = p / MG, cg = p - rt * MG;
    short8 af[2][KST];
#pragma unroll
    for (int m = 0; m < 2; ++m)
#pragma unroll
      for (int kk = 0; kk < KST; ++kk) {
        const int r = rt * 32 + m * 16 + (lane & 15);
        const int sl = kk * 4 + (lane >> 4);
        af[m][kk] = *(const short8*)((const char*)ldsIn + r * ISTR +
                                     ((sl ^ (r & 7)) * 16));
      }
    const int col = cg * 16 + (lane & 15);
    short8 bfr[KST];
#pragma unroll
    for (int kk = 0; kk < KST; ++kk)
      bfr[kk] = *(const short8*)&Wg[(size_t)col * K + kk * 32 + (lane >> 4) * 8];
    f32x4 acc0 = {0.f, 0.f, 0.f, 0.f}, acc1 = {0.f, 0.f, 0.f, 0.f};
#pragma unroll
    for (int kk = 0; kk < KST; ++kk) {
      acc0 = __builtin_amdgcn_mfma_f32_16x16x32_bf16(af[0][kk], bfr[kk], acc0, 0, 0, 0);
      acc1 = __builtin_amdgcn_mfma_f32_16x16x32_bf16(af[1][kk], bfr[kk], acc1, 0, 0, 0);
    }
    const float b = bias[col];
    const int rb = (lane >> 4) * 4;
#pragma unroll
    for (int m = 0; m < 2; ++m) {
      f32x4 a = m ? acc1 : acc0;
#pragma unroll
      for (int r4 = 0; r4 < 4; ++r4) {
        const int row = rt * 32 + m * 16 + rb + r4;
        if (row < rows) {
          float v = a[r4] + b;
          if (ACT) v = (v >= 0.f) ? v : 0.01f * v;
          if constexpr (MODE == 2) {
            u16 hi = f2bf(v);
            gOut[(size_t)row * M + col] = hi;
            gOut2[(size_t)row * M + col] = f2bf(v - bf2f(hi));
          } else if constexpr (MODE == 3) {
            const int byo =
                row * OSTR + (((col >> 3) ^ (row & 7)) * 16) + (col & 7) * 2;
            u16 hi = f2bf(v);
            *(u16*)((char*)ldsOut + byo) = hi;
            *(u16*)((char*)ldsOut2 + byo) = f2bf(v - bf2f(hi));
          } else {
            u16 hv = f2bf(v);
            *(u16*)((char*)ldsOut + row * OSTR + (((col >> 3) ^ (row & 7)) * 16) +
                    (col & 7) * 2) = hv;
            if constexpr (MODE == 1) gOut[(size_t)row * M + col] = hv;
          }
        }
      }
    }
  }
}

// ---- seg_all: the whole network per segment in one block ----
__global__ __launch_bounds__(1024) void seg_all(
    const float* __restrict__ H, const u16* __restrict__ pw1,
    const float* __restrict__ pb1, const u16* __restrict__ pw2,
    const float* __restrict__ pb2, const u16* __restrict__ aw,
    const float* __restrict__ ab, const u16* __restrict__ rw1,
    const float* __restrict__ rb1, const u16* __restrict__ rw2,
    const float* __restrict__ rb2, const u16* __restrict__ gw1,
    const float* __restrict__ gb1, const u16* __restrict__ gw2,
    const float* __restrict__ gb2, const float* __restrict__ gw3,
    const float* __restrict__ gb3, const int* __restrict__ sstart,
    const int* __restrict__ scount, float* __restrict__ hpool,
    float* __restrict__ scores, u16* __restrict__ Hfg, u16* __restrict__ aHg,
    u16* __restrict__ aLg, u16* __restrict__ Hmg, u16* __restrict__ Hm2g,
    float* __restrict__ hgg) {
  __shared__ __align__(16) u16 bufX[MAXC * 256];  // 32KB
  __shared__ __align__(16) u16 bufY[MAXC * 256];  // 32KB (P aliases)
  __shared__ __align__(16) u16 attH[MAXC * 256];  // 32KB
  __shared__ __align__(16) u16 attL[MAXC * 256];  // 32KB
  __shared__ float hgs[MAXC];
  __shared__ float red[1024];
  __shared__ float part[1024];
  const int s = blockIdx.x, t = threadIdx.x;
  const int cnt = scount[s];
  const int r0 = sstart[s];
  const int wave = t >> 6, lane = t & 63;

  if (cnt == 0) {
    if (t < 256) hpool[(size_t)s * D + t] = 0.f;
    return;
  }

  if (cnt <= MAXC) {
    // ---- stage H (f32 -> bf16 swizzled) ----
    {
      const int r = t >> 4, p16 = t & 15;
      if (r < cnt) {
        const float4* src = (const float4*)&H[(size_t)(r0 + r) * D + p16 * 16];
#pragma unroll
        for (int i = 0; i < 2; ++i) {
          int4 v = pack8(src[2 * i], src[2 * i + 1]);
          const int sl = p16 * 2 + i;
          *(int4*)((char*)bufX + r * 512 + ((sl ^ (r & 7)) * 16)) = v;
        }
      }
    }
    __syncthreads();
    mlp16<8, 1, 512, 512, 0>(bufX, bufY, nullptr, pw1, pb1, nullptr, nullptr, D, D, cnt, lane, wave);
    __syncthreads();
    mlp16<8, 1, 512, 512, 0>(bufY, bufX, nullptr, pw2, pb2, nullptr, nullptr, D, D, cnt, lane, wave);
    __syncthreads();  // bufX = Hf
    mlp16<8, 0, 512, 512, 3>(bufX, attH, attL, aw, ab, nullptr, nullptr, D, D, cnt, lane, wave);
    __syncthreads();
    // ---- QK^T (hi/lo split MFMA, LDS operands) ----
    float* P = (float*)bufY;
    const int cp = (cnt + 15) & ~15;
    const int nt = cp >> 4;
    const int lrow = lane & 15;
    for (int tt = wave; tt < nt * nt; tt += 16) {
      const int ti = tt / nt, tj = tt - ti * nt;
      const int ra = ti * 16 + lrow, rb2 = tj * 16 + lrow;
      f32x4 acc = {0.f, 0.f, 0.f, 0.f};
#pragma unroll
      for (int k0 = 0; k0 < D; k0 += 32) {
        const int sg = (k0 >> 3) + (lane >> 4);
        short8 ah = *(const short8*)((const char*)attH + ra * 512 + ((sg ^ (ra & 7)) * 16));
        short8 av = *(const short8*)((const char*)attL + ra * 512 + ((sg ^ (ra & 7)) * 16));
        short8 bh = *(const short8*)((const char*)attH + rb2 * 512 + ((sg ^ (rb2 & 7)) * 16));
        short8 bv = *(const short8*)((const char*)attL + rb2 * 512 + ((sg ^ (rb2 & 7)) * 16));
        acc = __builtin_amdgcn_mfma_f32_16x16x32_bf16(ah, bh, acc, 0, 0, 0);
        acc = __builtin_amdgcn_mfma_f32_16x16x32_bf16(ah, bv, acc, 0, 0, 0);
        acc = __builtin_amdgcn_mfma_f32_16x16x32_bf16(av, bh, acc, 0, 0, 0);
      }
      const int i0 = ti * 16 + (lane >> 4) * 4, j = tj * 16 + lrow;
#pragma unroll
      for (int r = 0; r < 4; ++r) P[(i0 + r) * PST + j] = acc[r];
    }
    __syncthreads();
    // ---- row softmax: lane = j (cnt <= 64) ----
    for (int i = wave; i < cnt; i += 16) {
      float* row = P + i * PST;
      float v = (lane < cnt) ? row[lane] : -INFINITY;
      float m = v;
#pragma unroll
      for (int o = 32; o > 0; o >>= 1) m = fmaxf(m, __shfl_xor(m, o));
      float e = (lane < cnt) ? __expf(v - m) : 0.f;
      float sum = e;
#pragma unroll
      for (int o = 32; o > 0; o >>= 1) sum += __shfl_xor(sum, o);
      if (lane < cnt) row[lane] = e / sum;
    }
    __syncthreads();
    // ---- PV -> attH (Hm, swizzled); Hf read from bufX LDS ----
    for (int i = wave; i < cnt; i += 16) {
      const float* Pi = P + i * PST;
      float a0 = 0.f, a1 = 0.f, a2 = 0.f, a3 = 0.f;
      for (int j = 0; j < cnt; ++j) {
        const float wj = Pi[j];
        const ushort4 hv = *(const ushort4*)((const char*)bufX + j * 512 +
                             (((lane >> 1) ^ (j & 7)) * 16) + (lane & 1) * 8);
        a0 += wj * bf2f(hv.x);
        a1 += wj * bf2f(hv.y);
        a2 += wj * bf2f(hv.z);
        a3 += wj * bf2f(hv.w);
      }
      ushort4 o;
      o.x = f2bf(a0); o.y = f2bf(a1); o.z = f2bf(a2); o.w = f2bf(a3);
      *(ushort4*)((char*)attH + i * 512 + (((lane >> 1) ^ (i & 7)) * 16) +
                  (lane & 1) * 8) = o;
    }
    __syncthreads();
    mlp16<8, 1, 512, 512, 0>(attH, attL, nullptr, rw1, rb1, nullptr, nullptr, D, D, cnt, lane, wave);
    __syncthreads();
    mlp16<8, 1, 512, 512, 0>(attL, bufX, nullptr, rw2, rb2, nullptr, nullptr, D, D, cnt, lane, wave);
    __syncthreads();  // bufX = Hm2
    mlp16<8, 1, 512, 256, 0>(bufX, bufY, nullptr, gw1, gb1, nullptr, nullptr, HID, D, cnt, lane, wave);
    __syncthreads();
    mlp16<4, 1, 256, 256, 0>(bufY, attH, nullptr, gw2, gb2, nullptr, nullptr, HID, HID, cnt, lane, wave);
    __syncthreads();  // attH (stride 256) = g2
    // ---- gate3 -> hgs ----
    {
      const int i = t >> 4, p16 = t & 15;
      if (i < cnt) {
        short8 hv = *(const short8*)((const char*)attH + i * 256 + ((p16 ^ (i & 7)) * 16));
        float sacc = 0.f;
#pragma unroll
        for (int q = 0; q < 8; ++q) sacc += bf2f((u16)hv[q]) * gw3[p16 * 8 + q];
        sacc += __shfl_xor(sacc, 1);
        sacc += __shfl_xor(sacc, 2);
        sacc += __shfl_xor(sacc, 4);
        sacc += __shfl_xor(sacc, 8);
        if (p16 == 0) hgs[i] = sacc + gb3[0];
      }
    }
    __syncthreads();
    // ---- segment softmax (single wave; cnt <= 64) ----
    if (t < 64) {
      float v = (t < cnt) ? hgs[t] : -INFINITY;
      float m = v;
#pragma unroll
      for (int o = 32; o > 0; o >>= 1) m = fmaxf(m, __shfl_xor(m, o));
      float e = (t < cnt) ? __expf(v - m) : 0.f;
      float sum = e;
#pragma unroll
      for (int o = 32; o > 0; o >>= 1) sum += __shfl_xor(sum, o);
      if (t < cnt) {
        const float sc = e / sum;
        hgs[t] = sc;
        scores[r0 + t] = sc;
      }
    }
    __syncthreads();
    // ---- pool from bufX (Hm2) ----
    {
      const int h = t >> 8, d = t & 255;
      float acc = 0.f;
      for (int i = h; i < cnt; i += 4)
        acc += hgs[i] * bf2f(*(const u16*)((const char*)bufX + i * 512 +
                              (((d >> 3) ^ (i & 7)) * 16) + (d & 7) * 2));
      part[t] = acc;
    }
    __syncthreads();
    if (t < 256)
      hpool[(size_t)s * D + t] =
          part[t] + part[t + 256] + part[t + 512] + part[t + 768];
  } else {
    // ============ fallback (cnt > 64, practically never taken) ============
    // Phase 1: phi + att in 64-row chunks -> global scratch
    for (int c0 = 0; c0 < cnt; c0 += 64) {
      const int rows = (cnt - c0) > 64 ? 64 : (cnt - c0);
      {
        const int r = t >> 4, p16 = t & 15;
        if (r < rows) {
          const float4* src = (const float4*)&H[(size_t)(r0 + c0 + r) * D + p16 * 16];
#pragma unroll
          for (int i = 0; i < 2; ++i) {
            int4 v = pack8(src[2 * i], src[2 * i + 1]);
            const int sl = p16 * 2 + i;
            *(int4*)((char*)bufX + r * 512 + ((sl ^ (r & 7)) * 16)) = v;
          }
        }
      }
      __syncthreads();
      mlp16<8, 1, 512, 512, 0>(bufX, bufY, nullptr, pw1, pb1, nullptr, nullptr, D, D, rows, lane, wave);
      __syncthreads();
      mlp16<8, 1, 512, 512, 1>(bufY, bufX, nullptr, pw2, pb2, Hfg + (size_t)(r0 + c0) * D, nullptr, D, D, rows, lane, wave);
      __syncthreads();
      mlp16<8, 0, 512, 512, 2>(bufX, nullptr, nullptr, aw, ab, aHg + (size_t)(r0 + c0) * D, aLg + (size_t)(r0 + c0) * D, D, D, rows, lane, wave);
      __syncthreads();
    }
    // Phase 2: attention, row-serial
    float* Pf = (float*)bufY;  // 8192 floats >= cnt
    for (int i = 0; i < cnt; ++i) {
      const u16* ai = aHg + (size_t)(r0 + i) * D;
      const u16* li = aLg + (size_t)(r0 + i) * D;
      for (int j = t; j < cnt; j += 1024) {
        const u16* aj = aHg + (size_t)(r0 + j) * D;
        const u16* lj = aLg + (size_t)(r0 + j) * D;
        float acc = 0.f;
        for (int k = 0; k < D; ++k)
          acc += (bf2f(ai[k]) + bf2f(li[k])) * (bf2f(aj[k]) + bf2f(lj[k]));
        Pf[j] = acc;
      }
      __syncthreads();
      float pm = -INFINITY;
      for (int j = t; j < cnt; j += 1024) pm = fmaxf(pm, Pf[j]);
      red[t] = pm;
      __syncthreads();
      for (int o = 512; o > 0; o >>= 1) {
        if (t < o) red[t] = fmaxf(red[t], red[t + o]);
        __syncthreads();
      }
      const float m = red[0];
      __syncthreads();
      float ps = 0.f;
      for (int j = t; j < cnt; j += 1024) {
        const float e = __expf(Pf[j] - m);
        Pf[j] = e;
        ps += e;
      }
      red[t] = ps;
      __syncthreads();
      for (int o = 512; o > 0; o >>= 1) {
        if (t < o) red[t] += red[t + o];
        __syncthreads();
      }
      const float inv = 1.f / red[0];
      if (t < D) {
        float acc = 0.f;
        for (int j = 0; j < cnt; ++j)
          acc += Pf[j] * bf2f(Hfg[(size_t)(r0 + j) * D + t]);
        Hmg[(size_t)(r0 + i) * D + t] = f2bf(acc * inv);
      }
      __syncthreads();
    }
    // Phase 3: rho + gate in 64-row chunks
    for (int c0 = 0; c0 < cnt; c0 += 64) {
      const int rows = (cnt - c0) > 64 ? 64 : (cnt - c0);
      {
        const int r = t >> 4, p16 = t & 15;
        if (r < rows) {
          const int4* src = (const int4*)&Hmg[(size_t)(r0 + c0 + r) * D + p16 * 16];
#pragma unroll
          for (int i = 0; i < 2; ++i) {
            const int sl = p16 * 2 + i;
            *(int4*)((char*)bufX + r * 512 + ((sl ^ (r & 7)) * 16)) = src[i];
          }
        }
      }
      __syncthreads();
      mlp16<8, 1, 512, 512, 0>(bufX, bufY, nullptr, rw1, rb1, nullptr, nullptr, D, D, rows, lane, wave);
      __syncthreads();
      mlp16<8, 1, 512, 512, 1>(bufY, bufX, nullptr, rw2, rb2, Hm2g + (size_t)(r0 + c0) * D, nullptr, D, D, rows, lane, wave);
      __syncthreads();
      mlp16<8, 1, 512, 256, 0>(bufX, bufY, nullptr, gw1, gb1, nullptr, nullptr, HID, D, rows, lane, wave);
      __syncthreads();
      mlp16<4, 1, 256, 256, 0>(bufY, attH, nullptr, gw2, gb2, nullptr, nullptr, HID, HID, rows, lane, wave);
      __syncthreads();
      {
        const int i = t >> 4, p16 = t & 15;
        if (i < rows) {
          short8 hv = *(const short8*)((const char*)attH + i * 256 + ((p16 ^ (i & 7)) * 16));
          float sacc = 0.f;
#pragma unroll
          for (int q = 0; q < 8; ++q) sacc += bf2f((u16)hv[q]) * gw3[p16 * 8 + q];
          sacc += __shfl_xor(sacc, 1);
          sacc += __shfl_xor(sacc, 2);
          sacc += __shfl_xor(sacc, 4);
          sacc += __shfl_xor(sacc, 8);
          if (p16 == 0) hgg[r0 + c0 + i] = sacc + gb3[0];
        }
      }
      __syncthreads();
    }
    // Phase 4: segment softmax + pool from global
    float pm = -INFINITY;
    for (int i = t; i < cnt; i += 1024) pm = fmaxf(pm, hgg[r0 + i]);
    red[t] = pm;
    __syncthreads();
    for (int o = 512; o > 0; o >>= 1) {
      if (t < o) red[t] = fmaxf(red[t], red[t + o]);
      __syncthreads();
    }
    const float m = red[0];
    __syncthreads();
    float ps = 0.f;
    for (int i = t; i < cnt; i += 1024) ps += __expf(hgg[r0 + i] - m);
    red[t] = ps;
    __syncthreads();
    for (int o = 512; o > 0; o >>= 1) {
      if (t < o) red[t] += red[t + o];
      __syncthreads();
    }
    const float inv = 1.f / red[0];
    for (int i = t; i < cnt; i += 1024)
      scores[r0 + i] = __expf(hgg[r0 + i] - m) * inv;
    const int h = t >> 8, d = t & 255;
    float acc = 0.f;
    for (int i = h; i < cnt; i += 4)
      acc += __expf(hgg[r0 + i] - m) * inv * bf2f(Hm2g[(size_t)(r0 + i) * D + d]);
    part[t] = acc;
    __syncthreads();
    if (t < 256)
      hpool[(size_t)s * D + t] =
          part[t] + part[t + 256] + part[t + 512] + part[t + 768];
  }
}

// ---------------------------------------------------------------------
extern "C" void kernel_launch(void* const* d_in, const int* in_sizes, int n_in,
                              void* d_out, int out_size, void* d_ws, size_t ws_size,
                              hipStream_t stream) {
  const float* H      = (const float*)d_in[0];
  const int*   batch  = (const int*)d_in[1];
  const float* phi_w1 = (const float*)d_in[2];
  const float* phi_b1 = (const float*)d_in[3];
  const float* phi_w2 = (const float*)d_in[4];
  const float* phi_b2 = (const float*)d_in[5];
  const float* att_w  = (const float*)d_in[6];
  const float* att_b  = (const float*)d_in[7];
  const float* rho_w1 = (const float*)d_in[8];
  const float* rho_b1 = (const float*)d_in[9];
  const float* rho_w2 = (const float*)d_in[10];
  const float* rho_b2 = (const float*)d_in[11];
  const float* g_w1   = (const float*)d_in[12];
  const float* g_b1   = (const float*)d_in[13];
  const float* g_w2   = (const float*)d_in[14];
  const float* g_b2   = (const float*)d_in[15];
  const float* g_w3   = (const float*)d_in[16];
  const float* g_b3   = (const float*)d_in[17];

  float* out_hpool  = (float*)d_out;
  float* out_scores = (float*)d_out + (size_t)S_SEG * D;

  char* w = (char*)d_ws;
  const size_t MB = 1u << 20;
  u16*   wb     = (u16*)(w);              // weights bf16 (<1MB)
  u16*   Hfg    = (u16*)(w + 1 * MB);     // fallback scratch 4MB
  u16*   aHg    = (u16*)(w + 5 * MB);     // 4MB
  u16*   aLg    = (u16*)(w + 9 * MB);     // 4MB
  u16*   Hmg    = (u16*)(w + 13 * MB);    // 4MB
  u16*   Hm2g   = (u16*)(w + 17 * MB);    // 4MB
  float* hgg    = (float*)(w + 21 * MB);  // 32KB
  int*   sstart = (int*)(w + 21 * MB + 64 * 1024);
  int*   scount = sstart + S_SEG;

  u16* phi_w1b = wb;
  u16* phi_w2b = wb + 65536;
  u16* att_wb  = wb + 2 * 65536;
  u16* rho_w1b = wb + 3 * 65536;
  u16* rho_w2b = wb + 4 * 65536;
  u16* g_w1b   = wb + 5 * 65536;
  u16* g_w2b   = wb + 5 * 65536 + 32768;

  CvtJobs jb;
  jb.src[0] = phi_w1; jb.dst[0] = phi_w1b; jb.n4[0] = 65536 / 4;
  jb.src[1] = phi_w2; jb.dst[1] = phi_w2b; jb.n4[1] = 65536 / 4;
  jb.src[2] = att_w;  jb.dst[2] = att_wb;  jb.n4[2] = 65536 / 4;
  jb.src[3] = rho_w1; jb.dst[3] = rho_w1b; jb.n4[3] = 65536 / 4;
  jb.src[4] = rho_w2; jb.dst[4] = rho_w2b; jb.n4[4] = 65536 / 4;
  jb.src[5] = g_w1;   jb.dst[5] = g_w1b;   jb.n4[5] = 32768 / 4;
  jb.src[6] = g_w2;   jb.dst[6] = g_w2b;   jb.n4[6] = 16384 / 4;

  prep<<<57, 256, 0, stream>>>(batch, sstart, scount, jb);

  seg_all<<<S_SEG, 1024, 0, stream>>>(
      H, phi_w1b, phi_b1, phi_w2b, phi_b2, att_wb, att_b, rho_w1b, rho_b1,
      rho_w2b, rho_b2, g_w1b, g_b1, g_w2b, g_b2, g_w3, g_b3, sstart, scount,
      out_hpool, out_scores, Hfg, aHg, aLg, Hmg, Hm2g, hgg);
}